// Round 1
// 622.430 us; speedup vs baseline: 1.3660x; 1.3660x over previous
//
#include <hip/hip_runtime.h>
#include <hip/hip_bf16.h>
#include <math.h>

#define D_DIM   1024
#define P_DIM   128
#define B_ROWS  4096
#define NBANK   8192
#define C_CLS   1000
#define EPS_BN  1e-5f
#define SCALE_S 0.1f
#define MTOT    20480   // 4096 + 8192 + 8192 batched pre_project rows
#define AVSPLIT 8       // A@h2v split-K chunks

typedef __bf16 bf16x8 __attribute__((ext_vector_type(8)));
typedef float  f32x4  __attribute__((ext_vector_type(4)));
typedef __hip_bfloat16 bf;

__device__ __forceinline__ void load_lds16(const void* gp, void* lp) {
    __builtin_amdgcn_global_load_lds(
        (__attribute__((address_space(1))) void*)gp,
        (__attribute__((address_space(3))) void*)lp, 16, 0, 0);
}

// ---------------------------------------------------------------------------
// bf16 MFMA GEMM: C[M,N] = A[M,K] @ B[N,K]^T (row-major bf16), 128x128 tile.
// A row stride = K; B row stride = ldb. kchunks>1 -> split-K via blockIdx.z.
// epi: 1 +bias,BN,ReLU -> bf16 | 3 fp32 +bias + addsrc[(gm&(ldc-1))*N+gn] |
//      4 fp32 *exp(*lsp), cols<ldc | 5 bf16 (+bias[n], +biasm[m]) |
//      6 bf16 partial at Cb + z*M*N | 7 bf16 exp(SCALE_S*(val + bias[n]))
// bf16 epis (1,5,6,7) store via per-wave LDS staging -> dwordx4 coalesced.
// ---------------------------------------------------------------------------
__global__ __launch_bounds__(256)
void gemm_bf16(const bf* __restrict__ A, const bf* __restrict__ B,
               int M, int N, int K, int ldb, int kchunks, int fx, int fy, int epi,
               float* __restrict__ Cf, bf* __restrict__ Cb,
               const float* __restrict__ bias, const float* __restrict__ biasm,
               const float* __restrict__ bng, const float* __restrict__ bnb,
               const float* __restrict__ bnm, const float* __restrict__ bnv,
               const float* __restrict__ addsrc, const float* __restrict__ lsp,
               int ldc)
{
    __shared__ __align__(16) short ldsS[8192];   // 16 KB
    short* lsA = ldsS;          // [128][32]
    short* lsB = ldsS + 4096;   // [128][32]

    const int tid  = threadIdx.x;
    const int wave = tid >> 6;
    const int lane = tid & 63;
    const int wm   = wave >> 1;
    const int wn   = wave & 1;
    const int r16  = lane & 15;
    const int quad = lane >> 4;

    // XCD-aware tile remap
    const int gx = gridDim.x, gy = gridDim.y;
    const int l   = blockIdx.y * gx + blockIdx.x;
    const int xcd = l & 7;
    const int i0  = l >> 3;
    const int sx  = gx / fx, sy = gy / fy;
    const int bx  = (xcd % fx) * sx + (i0 % sx);
    const int by  = (xcd / fx) * sy + (i0 / sx);
    const int bm0 = by * 128;
    const int bn0 = bx * 128;

    const int kper = K / kchunks;
    const int kbeg = blockIdx.z * kper;
    const int kend = kbeg + kper;

    f32x4 acc[4][4];
#pragma unroll
    for (int i = 0; i < 4; ++i)
#pragma unroll
        for (int j = 0; j < 4; ++j) acc[i][j] = (f32x4){0.f, 0.f, 0.f, 0.f};

    for (int k0 = kbeg; k0 < kend; k0 += 32) {
#pragma unroll
        for (int i = 0; i < 2; ++i) {
            const int s   = i * 256 + tid;
            const int row = s >> 2;
            const int cc  = (s & 3) * 8;
            const int lofs = (i * 256 + wave * 64) * 16;
            load_lds16(A + (size_t)(bm0 + row) * K + k0 + cc, (char*)lsA + lofs);
            load_lds16(B + (size_t)(bn0 + row) * ldb + k0 + cc, (char*)lsB + lofs);
        }
        __syncthreads();

        bf16x8 af[4], bfr[4];
#pragma unroll
        for (int i = 0; i < 4; ++i)
            af[i] = *(const bf16x8*)(lsA + (wm * 64 + i * 16 + r16) * 32 + quad * 8);
#pragma unroll
        for (int j = 0; j < 4; ++j)
            bfr[j] = *(const bf16x8*)(lsB + (wn * 64 + j * 16 + r16) * 32 + quad * 8);
#pragma unroll
        for (int i = 0; i < 4; ++i)
#pragma unroll
            for (int j = 0; j < 4; ++j)
                acc[i][j] = __builtin_amdgcn_mfma_f32_16x16x32_bf16(
                    af[i], bfr[j], acc[i][j], 0, 0, 0);
        __syncthreads();
    }
    // after final barrier all LDS fragment reads are complete -> safe to reuse

    if (epi == 3 || epi == 4) {
        const float lsv = (epi == 4) ? expf(*lsp) : 1.0f;
#pragma unroll
        for (int i = 0; i < 4; ++i) {
            const int gmb = bm0 + wm * 64 + i * 16 + quad * 4;
#pragma unroll
            for (int j = 0; j < 4; ++j) {
                const int gn = bn0 + wn * 64 + j * 16 + r16;
#pragma unroll
                for (int r = 0; r < 4; ++r) {
                    const int gm = gmb + r;
                    float val = acc[i][j][r];
                    if (epi == 3) {
                        Cf[(size_t)gm * N + gn] =
                            val + bias[gn] + addsrc[(size_t)(gm & (ldc - 1)) * N + gn];
                    } else {
                        if (gn < ldc) Cf[(size_t)gm * ldc + gn] = val * lsv;
                    }
                }
            }
        }
        return;
    }

    // bf16 LDS-staged store path (epi 1, 5, 6, 7)
    bf* dst = Cb + (epi == 6 ? (size_t)blockIdx.z * M * N : 0);
    bf* my  = (bf*)(ldsS + wave * 2048);   // 4 KB per wave: [32][64] bf16

#pragma unroll
    for (int half = 0; half < 2; ++half) {
#pragma unroll
        for (int i2 = 0; i2 < 2; ++i2) {
            const int i = half * 2 + i2;
            const int gmb = bm0 + wm * 64 + i * 16 + quad * 4;
#pragma unroll
            for (int j = 0; j < 4; ++j) {
                const int gn = bn0 + wn * 64 + j * 16 + r16;
#pragma unroll
                for (int r = 0; r < 4; ++r) {
                    float val = acc[i][j][r];
                    if (epi == 1) {
                        val += bias[gn];
                        val = (val - bnm[gn]) * rsqrtf(bnv[gn] + EPS_BN) * bng[gn] + bnb[gn];
                        val = fmaxf(val, 0.f);
                    } else if (epi == 7) {
                        val = __expf(SCALE_S * (val + (bias ? bias[gn] : 0.f)));
                    } else {
                        if (bias)  val += bias[gn];
                        if (biasm) val += biasm[gmb + r];
                    }
                    my[(i2 * 16 + quad * 4 + r) * 64 + j * 16 + r16] =
                        __float2bfloat16(val);
                }
            }
        }
#pragma unroll
        for (int it = 0; it < 4; ++it) {
            const int chunk = it * 64 + lane;
            const int lrow  = chunk >> 3;
            const int lcol  = (chunk & 7) * 8;
            const int grow  = bm0 + wm * 64 + half * 32 + lrow;
            const int gcol  = bn0 + wn * 64 + lcol;
            int4 v = *(const int4*)(my + lrow * 64 + lcol);
            *(int4*)(dst + (size_t)grow * N + gcol) = v;
        }
    }
}

// per-row sum of bf16 matrix [nrows, NBANK] -> fp32 rowsum
__global__ __launch_bounds__(256)
void rowsum_k(const bf* __restrict__ S, float* __restrict__ rs)
{
    __shared__ float red[8];
    const int tid = threadIdx.x;
    const bf* p = S + (size_t)blockIdx.x * NBANK;
    float s = 0.f;
    for (int i = tid * 8; i < NBANK; i += 2048) {
        union { int4 v; bf h[8]; } u;
        u.v = *(const int4*)(p + i);
#pragma unroll
        for (int e = 0; e < 8; ++e) s += __bfloat162float(u.h[e]);
    }
    for (int o = 32; o > 0; o >>= 1) s += __shfl_down(s, o, 64);
    if ((tid & 63) == 0) red[tid >> 6] = s;
    __syncthreads();
    if (tid == 0) {
        float t = 0.f;
        for (int w = 0; w < 4; ++w) t += red[w];
        rs[blockIdx.x] = t;
    }
}

// sum nparts bf16 partials (stride psz), divide by rowsum[i>>shift] -> bf16
__global__ __launch_bounds__(256)
void reduce_parts(const bf* __restrict__ parts, size_t psz, int nparts,
                  const float* __restrict__ rowsum, int shift,
                  bf* __restrict__ out, int n)
{
    int i = (blockIdx.x * 256 + threadIdx.x) * 8;
    if (i + 8 > n) return;
    const float inv = 1.0f / rowsum[i >> shift];
    float s[8] = {};
    for (int z = 0; z < nparts; ++z) {
        union { int4 v; bf h[8]; } u;
        u.v = *(const int4*)(parts + (size_t)z * psz + i);
#pragma unroll
        for (int e = 0; e < 8; ++e) s[e] += __bfloat162float(u.h[e]);
    }
    union { int4 v; bf h[8]; } o;
#pragma unroll
    for (int e = 0; e < 8; ++e) o.h[e] = __float2bfloat16(s[e] * inv);
    *(int4*)(out + i) = o.v;
}

// dual row L2-normalize: Fsum[r] = Gs[r]/||Gs[r]|| + Gt[r]/||Gt[r]||
__global__ __launch_bounds__(256)
void rownorm2(const float* __restrict__ G, float* __restrict__ Fsum)
{
    __shared__ float red[16];
    const int tid = threadIdx.x;
    const float* ps = G + (size_t)blockIdx.x * D_DIM;
    const float* pt = ps + (size_t)B_ROWS * D_DIM;
    float sa = 0.f, sb = 0.f;
    for (int i = tid; i < D_DIM; i += 256) {
        float a = ps[i], b = pt[i];
        sa = fmaf(a, a, sa); sb = fmaf(b, b, sb);
    }
    for (int s = 32; s > 0; s >>= 1) {
        sa += __shfl_down(sa, s, 64);
        sb += __shfl_down(sb, s, 64);
    }
    if ((tid & 63) == 0) { red[tid >> 6] = sa; red[8 + (tid >> 6)] = sb; }
    __syncthreads();
    if (tid == 0) {
        float ta = 0.f, tb = 0.f;
        for (int w = 0; w < 4; ++w) { ta += red[w]; tb += red[8 + w]; }
        red[4] = rsqrtf(ta); red[12] = rsqrtf(tb);
    }
    __syncthreads();
    const float ia = red[4], ib = red[12];
    float* o = Fsum + (size_t)blockIdx.x * D_DIM;
    for (int i = tid; i < D_DIM; i += 256) o[i] = ps[i] * ia + pt[i] * ib;
}

// concat-convert Fv|Fvs|Fvt -> Xb (bf16), 8/thread
__global__ __launch_bounds__(256)
void convX(const float* __restrict__ Fv, const float* __restrict__ Fvs,
           const float* __restrict__ Fvt, bf* __restrict__ X)
{
    int i = (blockIdx.x * 256 + threadIdx.x) * 8;
    const int n0 = B_ROWS * D_DIM, n1 = n0 + NBANK * D_DIM;
    const float* src;
    int off;
    if (i < n0)      { src = Fv;  off = i; }
    else if (i < n1) { src = Fvs; off = i - n0; }
    else             { src = Fvt; off = i - n1; }
    float4 a = *(const float4*)(src + off);
    float4 b = *(const float4*)(src + off + 4);
    union { bf h[8]; int4 v; } u;
    u.h[0] = __float2bfloat16(a.x); u.h[1] = __float2bfloat16(a.y);
    u.h[2] = __float2bfloat16(a.z); u.h[3] = __float2bfloat16(a.w);
    u.h[4] = __float2bfloat16(b.x); u.h[5] = __float2bfloat16(b.y);
    u.h[6] = __float2bfloat16(b.z); u.h[7] = __float2bfloat16(b.w);
    *(int4*)(X + i) = u.v;
}

// convert W1|W2|Wp -> bf16, 8/thread
__global__ __launch_bounds__(256)
void convW(const float* __restrict__ W1, const float* __restrict__ W2,
           const float* __restrict__ Wp,
           bf* __restrict__ W1b, bf* __restrict__ W2b, bf* __restrict__ Wpb)
{
    int i = (blockIdx.x * 256 + threadIdx.x) * 8;
    const int n1 = P_DIM * D_DIM;           // 131072
    const int n2 = n1 + P_DIM * P_DIM;      // 147456
    const int n3 = n2 + D_DIM * D_DIM;      // 1196032
    if (i >= n3) return;
    const float* src; bf* dst; int off;
    if (i < n1)      { src = W1; dst = W1b; off = i; }
    else if (i < n2) { src = W2; dst = W2b; off = i - n1; }
    else             { src = Wp; dst = Wpb; off = i - n2; }
    float4 a = *(const float4*)(src + off);
    float4 b = *(const float4*)(src + off + 4);
    union { bf h[8]; int4 v; } u;
    u.h[0] = __float2bfloat16(a.x); u.h[1] = __float2bfloat16(a.y);
    u.h[2] = __float2bfloat16(a.z); u.h[3] = __float2bfloat16(a.w);
    u.h[4] = __float2bfloat16(b.x); u.h[5] = __float2bfloat16(b.y);
    u.h[6] = __float2bfloat16(b.z); u.h[7] = __float2bfloat16(b.w);
    *(int4*)(dst + off) = u.v;
}

// W3 (3072x128 fp32, rows 3d+rr) -> transposed bf16 W3qT/W3kT/W3vT [128,1024]
// Txx[p, d] = W3[3d+x, p]
__global__ __launch_bounds__(256)
void convW3T(const float* __restrict__ W3,
             bf* __restrict__ Tq, bf* __restrict__ Tk, bf* __restrict__ Tv)
{
    int gid = blockIdx.x * 256 + threadIdx.x;   // 16384 threads
    int i = gid * 8;                            // elem index into [128][1024]
    if (i >= P_DIM * D_DIM) return;
    int p = i >> 10, d0 = i & 1023;
    union { bf h[8]; int4 v; } uq, uk, uv;
#pragma unroll
    for (int j = 0; j < 8; ++j) {
        const float* r = W3 + (size_t)3 * (d0 + j) * P_DIM + p;
        uq.h[j] = __float2bfloat16(r[0]);
        uk.h[j] = __float2bfloat16(r[P_DIM]);
        uv.h[j] = __float2bfloat16(r[2 * P_DIM]);
    }
    *(int4*)(Tq + i) = uq.v;
    *(int4*)(Tk + i) = uk.v;
    *(int4*)(Tv + i) = uv.v;
}

// v[p] = sum_d b3[3d] * W3[3d+1, p]   (= W3k^T @ b3q), 1 block x 128 threads
__global__ __launch_bounds__(128)
void vveck(const float* __restrict__ W3, const float* __restrict__ b3,
           float* __restrict__ v)
{
    const int p = threadIdx.x;
    float s = 0.f;
    for (int d = 0; d < D_DIM; ++d)
        s = fmaf(b3[3 * d], W3[(size_t)(3 * d + 1) * P_DIM + p], s);
    v[p] = s;
}

// bvp[o] = sum_i Wp[o,i]*b3[3i+2] + bp[o]   (= Wp @ b3v + bp); wave per output
__global__ __launch_bounds__(256)
void bvpk(const float* __restrict__ Wp, const float* __restrict__ b3,
          const float* __restrict__ bp, float* __restrict__ out)
{
    const int wave = threadIdx.x >> 6, lane = threadIdx.x & 63;
    const int o = blockIdx.x * 4 + wave;
    const float* r = Wp + (size_t)o * D_DIM;
    float s = 0.f;
    for (int i = lane; i < D_DIM; i += 64) s = fmaf(r[i], b3[3 * i + 2], s);
    for (int off = 32; off > 0; off >>= 1) s += __shfl_down(s, off, 64);
    if (lane == 0) out[o] = s + bp[o];
}

// beta[n] = h2_bank[n,:] . v   (per-key softmax logit bias), n in [0, 16384)
__global__ __launch_bounds__(256)
void betak(const bf* __restrict__ h2, const float* __restrict__ v,
           float* __restrict__ beta)
{
    __shared__ float vs[P_DIM];
    const int t = threadIdx.x;
    if (t < P_DIM) vs[t] = v[t];
    __syncthreads();
    const int n = blockIdx.x * 256 + t;
    const bf* r = h2 + (size_t)n * P_DIM;
    float s = 0.f;
#pragma unroll
    for (int c = 0; c < P_DIM; c += 8) {
        union { int4 q; bf h[8]; } u;
        u.q = *(const int4*)(r + c);
#pragma unroll
        for (int e = 0; e < 8; ++e) s += __bfloat162float(u.h[e]) * vs[c + e];
    }
    beta[n] = s;
}

// transpose bf16 [16384,128] -> [128,16384], 64-row tiles via LDS
__global__ __launch_bounds__(256)
void transp(const bf* __restrict__ in, bf* __restrict__ out)
{
    __shared__ bf t[64][136];
    const int tid = threadIdx.x;
    const size_t n0 = (size_t)blockIdx.x * 64;
#pragma unroll
    for (int q = 0; q < 4; ++q) {
        int idx = (q * 256 + tid) * 8;       // 0..8191
        int r = idx >> 7, c = idx & 127;
        *(int4*)&t[r][c] = *(const int4*)(in + (n0 + r) * P_DIM + c);
    }
    __syncthreads();
    const int p  = tid >> 1;
    const int nb = (tid & 1) * 32;
#pragma unroll
    for (int q = 0; q < 4; ++q) {
        const int n = nb + q * 8;
        union { int4 v; bf h[8]; } u;
#pragma unroll
        for (int e = 0; e < 8; ++e) u.h[e] = t[n + e][p];
        *(int4*)(out + (size_t)p * (2 * NBANK) + n0 + n) = u.v;
    }
}

// fp32 -> bf16, 8/thread
__global__ __launch_bounds__(256)
void f2b(const float* __restrict__ in, bf* __restrict__ out, int n)
{
    int i = (blockIdx.x * 256 + threadIdx.x) * 8;
    if (i + 8 > n) return;
    float4 a = *(const float4*)(in + i);
    float4 b = *(const float4*)(in + i + 4);
    union { bf h[8]; int4 v; } u;
    u.h[0] = __float2bfloat16(a.x); u.h[1] = __float2bfloat16(a.y);
    u.h[2] = __float2bfloat16(a.z); u.h[3] = __float2bfloat16(a.w);
    u.h[4] = __float2bfloat16(b.x); u.h[5] = __float2bfloat16(b.y);
    u.h[6] = __float2bfloat16(b.z); u.h[7] = __float2bfloat16(b.w);
    *(int4*)(out + i) = u.v;
}

// Ft [1000,1024] fp32 -> [1024,1024] bf16, rows 1000..1023 zero
__global__ __launch_bounds__(256)
void ftpad(const float* __restrict__ Ft, bf* __restrict__ out)
{
    int idx = blockIdx.x * 256 + threadIdx.x;
    int row = idx >> 10, col = idx & 1023;
    float v = (row < C_CLS) ? Ft[(size_t)row * D_DIM + col] : 0.f;
    out[idx] = __float2bfloat16(v);
}

// ---------------------------------------------------------------------------
// Rank-128 attention factorization:
//   S = q@k^T = h2q @ (W3q^T W3k) @ h2k^T + alpha[b] + beta[n] + c
//     alpha,c cancel in softmax (explicit rowsum normalization);
//     beta[n] = h2k[n] . (W3k^T b3q) folded into the exp epilogue.
//   A@V = (A_norm @ h2_bank) @ W3v^T + b3v  (A rows sum to 1), and
//   (..@W3v^T + b3v)@Wp^T + bp = Yhat @ (Wp@W3v)^T + (Wp@b3v + bp)
// => all N/K=1024 attention GEMMs collapse to K=128 / N=128.
// ---------------------------------------------------------------------------
extern "C" void kernel_launch(void* const* d_in, const int* in_sizes, int n_in,
                              void* d_out, int out_size, void* d_ws, size_t ws_size,
                              hipStream_t stream)
{
    (void)in_sizes; (void)n_in; (void)out_size; (void)ws_size;

    const float* Ft  = (const float*)d_in[0];
    const float* Fv  = (const float*)d_in[1];
    const float* Fvs = (const float*)d_in[2];
    const float* Fvt = (const float*)d_in[3];
    const float* W1  = (const float*)d_in[4];
    const float* b1  = (const float*)d_in[5];
    const float* g1  = (const float*)d_in[6];
    const float* be1 = (const float*)d_in[7];
    const float* m1  = (const float*)d_in[8];
    const float* v1  = (const float*)d_in[9];
    const float* W2  = (const float*)d_in[10];
    const float* b2  = (const float*)d_in[11];
    const float* g2  = (const float*)d_in[12];
    const float* be2 = (const float*)d_in[13];
    const float* m2  = (const float*)d_in[14];
    const float* v2  = (const float*)d_in[15];
    const float* W3  = (const float*)d_in[16];
    const float* b3  = (const float*)d_in[17];
    const float* Wp  = (const float*)d_in[18];
    const float* bp  = (const float*)d_in[19];
    const float* ls  = (const float*)d_in[20];

    char* base = (char*)d_ws;
    size_t o = 0;
    auto take = [&](size_t s) { size_t r = o; o += (s + 255) & ~(size_t)255; return r; };

    // persistent (~18 MB)
    bf* qtb   = (bf*)(base + take((size_t)B_ROWS * P_DIM * 2));        // Qtilde
    bf* h2T   = (bf*)(base + take((size_t)P_DIM * 2 * NBANK * 2));     // [128,16384]
    bf* Yhat  = (bf*)(base + take((size_t)2 * B_ROWS * P_DIM * 2));    // [8192,128]
    bf* Wpb   = (bf*)(base + take((size_t)D_DIM * D_DIM * 2));
    bf* Ftb   = (bf*)(base + take((size_t)D_DIM * D_DIM * 2));
    bf* W3qT  = (bf*)(base + take((size_t)P_DIM * D_DIM * 2));
    bf* W3kT  = (bf*)(base + take((size_t)P_DIM * D_DIM * 2));
    bf* W3vT  = (bf*)(base + take((size_t)P_DIM * D_DIM * 2));
    bf* Wqk   = (bf*)(base + take((size_t)P_DIM * P_DIM * 2));         // (W3q^T W3k)^T
    bf* Wpvb  = (bf*)(base + take((size_t)D_DIM * P_DIM * 2));         // Wp@W3v
    bf* W1b   = (bf*)(base + take((size_t)P_DIM * D_DIM * 2));
    bf* W2b   = (bf*)(base + take((size_t)P_DIM * P_DIM * 2));
    bf* h2b   = (bf*)(base + take((size_t)MTOT * P_DIM * 2));          // [20480,128]
    float* vvec = (float*)(base + take(P_DIM * 4));
    float* beta = (float*)(base + take((size_t)2 * NBANK * 4));
    float* bvp  = (float*)(base + take(D_DIM * 4));
    float* rsum = (float*)(base + take(B_ROWS * 4));

    // scratch region (aliased across phases)
    const size_t Dbase = o;
    bf* Sb    = (bf*)(base + Dbase);                                   // 64 MB
    bf* Opart = (bf*)(base + Dbase + (size_t)B_ROWS * NBANK * 2);      // 8 MB
    bf* Xb    = (bf*)(base + Dbase + (size_t)B_ROWS * NBANK * 2
                           + (size_t)AVSPLIT * B_ROWS * P_DIM * 2);    // 40 MB
    bf* h1b   = (bf*)((char*)Xb + (size_t)MTOT * D_DIM * 2);           // 5 MB
    // P4 view aliases Sb (dead by then)
    float* G     = (float*)(base + Dbase);                             // 32 MB
    float* Fsum  = (float*)(base + Dbase + (size_t)2 * B_ROWS * D_DIM * 4);
    bf*    Fsumb = (bf*)(base + Dbase + (size_t)3 * B_ROWS * D_DIM * 4);

    auto gemm = [&](const bf* A, const bf* B, int M, int N, int K, int ldb,
                    int kch, int fx, int fy, int epi, float* Cf, bf* Cb,
                    const float* bias, const float* biasm,
                    const float* bg, const float* bb, const float* bm, const float* bv,
                    const float* addsrc, const float* lsp, int ldc) {
        gemm_bf16<<<dim3(N / 128, M / 128, kch), dim3(256), 0, stream>>>(
            A, B, M, N, K, ldb, kch, fx, fy, epi, Cf, Cb, bias, biasm,
            bg, bb, bm, bv, addsrc, lsp, ldc);
    };

    // P1: conversions + folded weight products
    convX<<<dim3(MTOT * D_DIM / 2048), dim3(256), 0, stream>>>(Fv, Fvs, Fvt, Xb);
    convW<<<dim3(584), dim3(256), 0, stream>>>(W1, W2, Wp, W1b, W2b, Wpb);
    convW3T<<<dim3(64), dim3(256), 0, stream>>>(W3, W3qT, W3kT, W3vT);
    ftpad<<<dim3(D_DIM * D_DIM / 256), dim3(256), 0, stream>>>(Ft, Ftb);
    vveck<<<dim3(1), dim3(128), 0, stream>>>(W3, b3, vvec);
    bvpk<<<dim3(256), dim3(256), 0, stream>>>(Wp, b3, bp, bvp);
    // Wqk[p',p] = sum_d W3k[d,p'] W3q[d,p]  (so A@Wqk^T gives h2q @ (W3q^T W3k))
    gemm(W3kT, W3qT, P_DIM, P_DIM, D_DIM, D_DIM, 1, 1, 8, 5, nullptr, Wqk,
         nullptr, nullptr, nullptr, nullptr, nullptr, nullptr, nullptr, nullptr, 0);
    // Wpv[o,p] = sum_i Wp[o,i] W3v[i,p]
    gemm(Wpb, W3vT, D_DIM, P_DIM, D_DIM, D_DIM, 1, 1, 8, 5, nullptr, Wpvb,
         nullptr, nullptr, nullptr, nullptr, nullptr, nullptr, nullptr, nullptr, 0);

    // P2: batched pre_project -> h2 [20480,128]; Qtilde; beta; h2 transpose
    gemm(Xb, W1b, MTOT, P_DIM, D_DIM, D_DIM, 1, 1, 8, 1, nullptr, h1b,
         b1, nullptr, g1, be1, m1, v1, nullptr, nullptr, 0);
    gemm(h1b, W2b, MTOT, P_DIM, P_DIM, P_DIM, 1, 1, 8, 1, nullptr, h2b,
         b2, nullptr, g2, be2, m2, v2, nullptr, nullptr, 0);
    gemm(h2b, Wqk, B_ROWS, P_DIM, P_DIM, P_DIM, 1, 1, 8, 5, nullptr, qtb,
         nullptr, nullptr, nullptr, nullptr, nullptr, nullptr, nullptr, nullptr, 0);
    betak<<<dim3(2 * NBANK / 256), dim3(256), 0, stream>>>(
        h2b + (size_t)B_ROWS * P_DIM, vvec, beta);
    transp<<<dim3(2 * NBANK / 64), dim3(256), 0, stream>>>(
        h2b + (size_t)B_ROWS * P_DIM, h2T);

    // P3: per side: exp(SCALE*(Qt@h2k^T + beta)) -> rowsum -> split-K A@h2 -> norm
    for (int side = 0; side < 2; ++side) {
        const bf* kb = h2b + (size_t)(B_ROWS + side * NBANK) * P_DIM;
        gemm(qtb, kb, B_ROWS, NBANK, P_DIM, P_DIM, 1, 4, 2, 7, nullptr, Sb,
             beta + (size_t)side * NBANK, nullptr, nullptr, nullptr, nullptr,
             nullptr, nullptr, nullptr, 0);
        rowsum_k<<<dim3(B_ROWS), dim3(256), 0, stream>>>(Sb, rsum);
        gemm(Sb, h2T + (size_t)side * NBANK, B_ROWS, P_DIM, NBANK, 2 * NBANK,
             AVSPLIT, 1, 8, 6, nullptr, Opart, nullptr, nullptr, nullptr, nullptr,
             nullptr, nullptr, nullptr, nullptr, 0);
        reduce_parts<<<dim3(B_ROWS * P_DIM / 2048), dim3(256), 0, stream>>>(
            Opart, (size_t)B_ROWS * P_DIM, AVSPLIT, rsum, 7,
            Yhat + (size_t)side * B_ROWS * P_DIM, B_ROWS * P_DIM);
    }

    // P4: combined post-project (K=128 now) + dual rownorm + logits
    gemm(Yhat, Wpvb, 2 * B_ROWS, D_DIM, P_DIM, P_DIM, 1, 1, 8, 3, G, nullptr,
         bvp, nullptr, nullptr, nullptr, nullptr, nullptr, Fv, nullptr, B_ROWS);
    rownorm2<<<dim3(B_ROWS), dim3(256), 0, stream>>>(G, Fsum);
    f2b<<<dim3(B_ROWS * D_DIM / 2048), dim3(256), 0, stream>>>(
        Fsum, Fsumb, B_ROWS * D_DIM);
    gemm(Fsumb, Ftb, B_ROWS, D_DIM, D_DIM, D_DIM, 1, 1, 8, 4, (float*)d_out, nullptr,
         nullptr, nullptr, nullptr, nullptr, nullptr, nullptr, nullptr, ls, C_CLS);
}

// Round 2
// 543.541 us; speedup vs baseline: 1.5642x; 1.1451x over previous
//
#include <hip/hip_runtime.h>
#include <hip/hip_bf16.h>
#include <math.h>

#define D_DIM   1024
#define P_DIM   128
#define B_ROWS  4096
#define NBANK   8192
#define C_CLS   1000
#define EPS_BN  1e-5f
#define SCALE_S 0.1f
#define MTOT    20480   // 4096 + 8192 + 8192 batched pre_project rows

typedef __bf16 bf16x8 __attribute__((ext_vector_type(8)));
typedef float  f32x4  __attribute__((ext_vector_type(4)));
typedef __hip_bfloat16 bf;

__device__ __forceinline__ void load_lds16(const void* gp, void* lp) {
    __builtin_amdgcn_global_load_lds(
        (__attribute__((address_space(1))) void*)gp,
        (__attribute__((address_space(3))) void*)lp, 16, 0, 0);
}

__device__ __forceinline__ int4 pack8(float4 a, float4 b) {
    union { bf h[8]; int4 v; } u;
    u.h[0] = __float2bfloat16(a.x); u.h[1] = __float2bfloat16(a.y);
    u.h[2] = __float2bfloat16(a.z); u.h[3] = __float2bfloat16(a.w);
    u.h[4] = __float2bfloat16(b.x); u.h[5] = __float2bfloat16(b.y);
    u.h[6] = __float2bfloat16(b.z); u.h[7] = __float2bfloat16(b.w);
    return u.v;
}

// ---------------------------------------------------------------------------
// bf16 MFMA GEMM: C[M,N] = A[M,K] @ B[N,K]^T (row-major bf16), 128x128 tile.
// A row stride = lda; B row stride = ldb. kchunks>1 -> split-K via blockIdx.z.
// epi: 1 +bias,BN,ReLU -> bf16 | 3 fp32 +bias + addsrc[(gm&(ldc-1))*N+gn] |
//      4 fp32 *exp(*lsp), cols<ldc | 5 bf16 (+bias[n], +biasm[m]) |
//      6 bf16 partial at Cb + z*M*N | 7 bf16 exp(SCALE_S*(val + bias[n]))
//        + fused per-row sum atomics into rsump[row (+M if bn0>=ldc)]
// bf16 epis (1,5,6,7) store via per-wave LDS staging -> dwordx4 coalesced.
// ---------------------------------------------------------------------------
__global__ __launch_bounds__(256)
void gemm_bf16(const bf* __restrict__ A, const bf* __restrict__ B,
               int M, int N, int K, int lda, int ldb,
               int kchunks, int fx, int fy, int epi,
               float* __restrict__ Cf, bf* __restrict__ Cb,
               const float* __restrict__ bias, const float* __restrict__ biasm,
               const float* __restrict__ bng, const float* __restrict__ bnb,
               const float* __restrict__ bnm, const float* __restrict__ bnv,
               const float* __restrict__ addsrc, const float* __restrict__ lsp,
               int ldc, float* __restrict__ rsump)
{
    __shared__ __align__(16) short ldsS[8192];   // 16 KB
    short* lsA = ldsS;          // [128][32]
    short* lsB = ldsS + 4096;   // [128][32]

    const int tid  = threadIdx.x;
    const int wave = tid >> 6;
    const int lane = tid & 63;
    const int wm   = wave >> 1;
    const int wn   = wave & 1;
    const int r16  = lane & 15;
    const int quad = lane >> 4;

    // XCD-aware tile remap
    const int gx = gridDim.x, gy = gridDim.y;
    const int l   = blockIdx.y * gx + blockIdx.x;
    const int xcd = l & 7;
    const int i0  = l >> 3;
    const int sx  = gx / fx, sy = gy / fy;
    const int bx  = (xcd % fx) * sx + (i0 % sx);
    const int by  = (xcd / fx) * sy + (i0 / sx);
    const int bm0 = by * 128;
    const int bn0 = bx * 128;

    const int kper = K / kchunks;
    const int kbeg = blockIdx.z * kper;
    const int kend = kbeg + kper;

    f32x4 acc[4][4];
#pragma unroll
    for (int i = 0; i < 4; ++i)
#pragma unroll
        for (int j = 0; j < 4; ++j) acc[i][j] = (f32x4){0.f, 0.f, 0.f, 0.f};

    for (int k0 = kbeg; k0 < kend; k0 += 32) {
#pragma unroll
        for (int i = 0; i < 2; ++i) {
            const int s   = i * 256 + tid;
            const int row = s >> 2;
            const int cc  = (s & 3) * 8;
            const int lofs = (i * 256 + wave * 64) * 16;
            load_lds16(A + (size_t)(bm0 + row) * lda + k0 + cc, (char*)lsA + lofs);
            load_lds16(B + (size_t)(bn0 + row) * ldb + k0 + cc, (char*)lsB + lofs);
        }
        __syncthreads();

        bf16x8 af[4], bfr[4];
#pragma unroll
        for (int i = 0; i < 4; ++i)
            af[i] = *(const bf16x8*)(lsA + (wm * 64 + i * 16 + r16) * 32 + quad * 8);
#pragma unroll
        for (int j = 0; j < 4; ++j)
            bfr[j] = *(const bf16x8*)(lsB + (wn * 64 + j * 16 + r16) * 32 + quad * 8);
#pragma unroll
        for (int i = 0; i < 4; ++i)
#pragma unroll
            for (int j = 0; j < 4; ++j)
                acc[i][j] = __builtin_amdgcn_mfma_f32_16x16x32_bf16(
                    af[i], bfr[j], acc[i][j], 0, 0, 0);
        __syncthreads();
    }
    // after final barrier all LDS fragment reads are complete -> safe to reuse

    if (epi == 3 || epi == 4) {
        const float lsv = (epi == 4) ? expf(*lsp) : 1.0f;
#pragma unroll
        for (int i = 0; i < 4; ++i) {
            const int gmb = bm0 + wm * 64 + i * 16 + quad * 4;
#pragma unroll
            for (int j = 0; j < 4; ++j) {
                const int gn = bn0 + wn * 64 + j * 16 + r16;
#pragma unroll
                for (int r = 0; r < 4; ++r) {
                    const int gm = gmb + r;
                    float val = acc[i][j][r];
                    if (epi == 3) {
                        Cf[(size_t)gm * N + gn] =
                            val + bias[gn] + addsrc[(size_t)(gm & (ldc - 1)) * N + gn];
                    } else {
                        if (gn < ldc) Cf[(size_t)gm * ldc + gn] = val * lsv;
                    }
                }
            }
        }
        return;
    }

    // bf16 LDS-staged store path (epi 1, 5, 6, 7)
    bf* dst = Cb + (epi == 6 ? (size_t)blockIdx.z * M * N : 0);
    bf* my  = (bf*)(ldsS + wave * 2048);   // 4 KB per wave: [32][64] bf16
    float* rsp = (epi == 7 && rsump)
        ? rsump + ((ldc > 0 && bn0 >= ldc) ? M : 0) : nullptr;

#pragma unroll
    for (int half = 0; half < 2; ++half) {
#pragma unroll
        for (int i2 = 0; i2 < 2; ++i2) {
            const int i = half * 2 + i2;
            const int gmb = bm0 + wm * 64 + i * 16 + quad * 4;
            float rsv[4] = {0.f, 0.f, 0.f, 0.f};
#pragma unroll
            for (int j = 0; j < 4; ++j) {
                const int gn = bn0 + wn * 64 + j * 16 + r16;
#pragma unroll
                for (int r = 0; r < 4; ++r) {
                    float val = acc[i][j][r];
                    if (epi == 1) {
                        val += bias[gn];
                        val = (val - bnm[gn]) * rsqrtf(bnv[gn] + EPS_BN) * bng[gn] + bnb[gn];
                        val = fmaxf(val, 0.f);
                    } else if (epi == 7) {
                        val = __expf(SCALE_S * (val + (bias ? bias[gn] : 0.f)));
                        rsv[r] += val;
                    } else {
                        if (bias)  val += bias[gn];
                        if (biasm) val += biasm[gmb + r];
                    }
                    my[(i2 * 16 + quad * 4 + r) * 64 + j * 16 + r16] =
                        __float2bfloat16(val);
                }
            }
            if (rsp) {
                // reduce each row partial across the 16-lane r16 group, then
                // one atomic per row per wave (4 lanes/instr, 64B-coalesced)
#pragma unroll
                for (int r = 0; r < 4; ++r) {
                    float s = rsv[r];
                    s += __shfl_xor(s, 1, 64);
                    s += __shfl_xor(s, 2, 64);
                    s += __shfl_xor(s, 4, 64);
                    s += __shfl_xor(s, 8, 64);
                    if (r16 == 0) atomicAdd(rsp + gmb + r, s);
                }
            }
        }
#pragma unroll
        for (int it = 0; it < 4; ++it) {
            const int chunk = it * 64 + lane;
            const int lrow  = chunk >> 3;
            const int lcol  = (chunk & 7) * 8;
            const int grow  = bm0 + wm * 64 + half * 32 + lrow;
            const int gcol  = bn0 + wn * 64 + lcol;
            int4 v = *(const int4*)(my + lrow * 64 + lcol);
            *(int4*)(dst + (size_t)grow * N + gcol) = v;
        }
    }
}

// ---------------------------------------------------------------------------
// prep mega-kernel: all input-only transforms in ONE dispatch (range-split).
//  r0 convX | r1 convW | r2 convW3T | r3 ftpad | r4 zero rsum |
//  r5 vvec partials (vvecP[16][128], no atomics) | r6 bvp = Wp@b3v + bp
// ---------------------------------------------------------------------------
#define PG0 10240   // convX: MTOT*D/2048
#define PG1 584     // convW: (P*D + P*P + D*D)/2048
#define PG2 64      // convW3T: P*D/2048
#define PG3 512     // ftpad: D*D/2048
#define PG4 8       // zero rsum (8192 floats)
#define PG5 8       // vvecP partials
#define PG6 256     // bvp

__global__ __launch_bounds__(256)
void prep(const float* __restrict__ Fv, const float* __restrict__ Fvs,
          const float* __restrict__ Fvt,
          const float* __restrict__ W1, const float* __restrict__ W2,
          const float* __restrict__ Wp,
          const float* __restrict__ W3, const float* __restrict__ b3,
          const float* __restrict__ bp, const float* __restrict__ Ft,
          bf* __restrict__ Xb, bf* __restrict__ W1b, bf* __restrict__ W2b,
          bf* __restrict__ Wpb,
          bf* __restrict__ Tq, bf* __restrict__ Tk, bf* __restrict__ Tv,
          bf* __restrict__ Ftb,
          float* __restrict__ rsum, float* __restrict__ vvecP,
          float* __restrict__ bvp)
{
    const int tid = threadIdx.x;
    int b = blockIdx.x;
    if (b < PG0) {                       // ---- convX: Fv|Fvs|Fvt -> bf16
        int i = (b * 256 + tid) * 8;
        const int n0 = B_ROWS * D_DIM, n1 = n0 + NBANK * D_DIM;
        const float* src; int off;
        if (i < n0)      { src = Fv;  off = i; }
        else if (i < n1) { src = Fvs; off = i - n0; }
        else             { src = Fvt; off = i - n1; }
        float4 a = *(const float4*)(src + off);
        float4 c = *(const float4*)(src + off + 4);
        *(int4*)(Xb + i) = pack8(a, c);
        return;
    }
    if ((b -= PG0) < PG1) {              // ---- convW: W1|W2|Wp -> bf16
        int i = (b * 256 + tid) * 8;
        const int n1 = P_DIM * D_DIM, n2 = n1 + P_DIM * P_DIM;
        const float* src; bf* dst; int off;
        if (i < n1)      { src = W1; dst = W1b; off = i; }
        else if (i < n2) { src = W2; dst = W2b; off = i - n1; }
        else             { src = Wp; dst = Wpb; off = i - n2; }
        float4 a = *(const float4*)(src + off);
        float4 c = *(const float4*)(src + off + 4);
        *(int4*)(dst + off) = pack8(a, c);
        return;
    }
    if ((b -= PG1) < PG2) {              // ---- convW3T: Txx[p,d] = W3[3d+x,p]
        int i = (b * 256 + tid) * 8;     // [128][1024] elem idx
        int p = i >> 10, d0 = i & 1023;
        union { bf h[8]; int4 v; } uq, uk, uv;
#pragma unroll
        for (int j = 0; j < 8; ++j) {
            const float* r = W3 + (size_t)3 * (d0 + j) * P_DIM + p;
            uq.h[j] = __float2bfloat16(r[0]);
            uk.h[j] = __float2bfloat16(r[P_DIM]);
            uv.h[j] = __float2bfloat16(r[2 * P_DIM]);
        }
        *(int4*)(Tq + i) = uq.v;
        *(int4*)(Tk + i) = uk.v;
        *(int4*)(Tv + i) = uv.v;
        return;
    }
    if ((b -= PG2) < PG3) {              // ---- ftpad: Ft -> [1024,1024] bf16
        int i = (b * 256 + tid) * 8;
        int row = i >> 10, col = i & 1023;
        if (row < C_CLS) {
            float4 a = *(const float4*)(Ft + (size_t)row * D_DIM + col);
            float4 c = *(const float4*)(Ft + (size_t)row * D_DIM + col + 4);
            *(int4*)(Ftb + i) = pack8(a, c);
        } else {
            *(int4*)(Ftb + i) = (int4){0, 0, 0, 0};
        }
        return;
    }
    if ((b -= PG3) < PG4) {              // ---- zero rsum[2*B_ROWS]
        int i = (b * 256 + tid) * 4;
        *(float4*)(rsum + i) = (float4){0.f, 0.f, 0.f, 0.f};
        return;
    }
    if ((b -= PG4) < PG5) {              // ---- vvecP[z][p] partials of W3k^T b3q
        const int p = tid & 127, hf = tid >> 7;
        const int dbase = b * 128 + hf * 64;
        float s = 0.f;
        for (int dd = 0; dd < 64; ++dd) {
            const int d = dbase + dd;
            s = fmaf(b3[3 * d], W3[(size_t)(3 * d + 1) * P_DIM + p], s);
        }
        vvecP[(b * 2 + hf) * P_DIM + p] = s;
        return;
    }
    b -= PG5;                            // ---- bvp[o] = Wp[o,:].b3v + bp[o]
    const int wave = tid >> 6, lane = tid & 63;
    const int o = b * 4 + wave;
    const float* r = Wp + (size_t)o * D_DIM;
    float s = 0.f;
    for (int i = lane; i < D_DIM; i += 64) s = fmaf(r[i], b3[3 * i + 2], s);
    for (int off = 32; off > 0; off >>= 1) s += __shfl_down(s, off, 64);
    if (lane == 0) bvp[o] = s + bp[o];
}

// fused reduce for split-K weight-fold GEMMs: Wqk (8 parts) + Wpv (4 parts)
__global__ __launch_bounds__(256)
void reduceWW(const bf* __restrict__ WqkP, const bf* __restrict__ WpvP,
              bf* __restrict__ Wqk, bf* __restrict__ Wpv)
{
    const int tid = threadIdx.x;
    if (blockIdx.x < 8) {
        int i = (blockIdx.x * 256 + tid) * 8;          // < 16384
        float s[8] = {};
        for (int z = 0; z < 8; ++z) {
            union { int4 v; bf h[8]; } u;
            u.v = *(const int4*)(WqkP + (size_t)z * 16384 + i);
#pragma unroll
            for (int e = 0; e < 8; ++e) s[e] += __bfloat162float(u.h[e]);
        }
        union { bf h[8]; int4 v; } o;
#pragma unroll
        for (int e = 0; e < 8; ++e) o.h[e] = __float2bfloat16(s[e]);
        *(int4*)(Wqk + i) = o.v;
    } else {
        int i = ((blockIdx.x - 8) * 256 + tid) * 8;    // < 131072
        float s[8] = {};
        for (int z = 0; z < 4; ++z) {
            union { int4 v; bf h[8]; } u;
            u.v = *(const int4*)(WpvP + (size_t)z * 131072 + i);
#pragma unroll
            for (int e = 0; e < 8; ++e) s[e] += __bfloat162float(u.h[e]);
        }
        union { bf h[8]; int4 v; } o;
#pragma unroll
        for (int e = 0; e < 8; ++e) o.h[e] = __float2bfloat16(s[e]);
        *(int4*)(Wpv + i) = o.v;
    }
}

// posth2: r0 (64 blocks) beta[n] = h2bank[n,:].vvec | r1 (256) h2 transpose
__global__ __launch_bounds__(256)
void posth2(const bf* __restrict__ h2bank, const float* __restrict__ vvecP,
            float* __restrict__ beta, bf* __restrict__ h2T)
{
    __shared__ float vs[P_DIM];
    __shared__ bf t[64][136];
    const int tid = threadIdx.x;
    if (blockIdx.x < 64) {
        if (tid < P_DIM) {
            float s = 0.f;
#pragma unroll
            for (int z = 0; z < 16; ++z) s += vvecP[z * P_DIM + tid];
            vs[tid] = s;
        }
        __syncthreads();
        const int n = blockIdx.x * 256 + tid;
        const bf* r = h2bank + (size_t)n * P_DIM;
        float s = 0.f;
#pragma unroll
        for (int c = 0; c < P_DIM; c += 8) {
            union { int4 q; bf h[8]; } u;
            u.q = *(const int4*)(r + c);
#pragma unroll
            for (int e = 0; e < 8; ++e) s += __bfloat162float(u.h[e]) * vs[c + e];
        }
        beta[n] = s;
    } else {
        const size_t n0 = (size_t)(blockIdx.x - 64) * 64;
#pragma unroll
        for (int q = 0; q < 4; ++q) {
            int idx = (q * 256 + tid) * 8;       // 0..8191
            int r = idx >> 7, c = idx & 127;
            *(int4*)&t[r][c] = *(const int4*)(h2bank + (n0 + r) * P_DIM + c);
        }
        __syncthreads();
        const int p  = tid >> 1;
        const int nb = (tid & 1) * 32;
#pragma unroll
        for (int q = 0; q < 4; ++q) {
            const int n = nb + q * 8;
            union { int4 v; bf h[8]; } u;
#pragma unroll
            for (int e = 0; e < 8; ++e) u.h[e] = t[n + e][p];
            *(int4*)(h2T + (size_t)p * (2 * NBANK) + n0 + n) = u.v;
        }
    }
}

// reduceY: Yhat[s][b][p] = sum_{z in s*8..s*8+7} parts[z][b][p] / rsum[s*B+b]
__global__ __launch_bounds__(256)
void reduceY(const bf* __restrict__ parts, const float* __restrict__ rsum,
             bf* __restrict__ Yhat)
{
    int j = (blockIdx.x * 256 + threadIdx.x) * 8;      // < 2*B_ROWS*P_DIM
    const int s = j >> 19;                             // B_ROWS*P_DIM = 2^19
    const size_t inner = (size_t)(j & 524287);
    const bf* p = parts + (size_t)s * 8 * 524288 + inner;
    float acc[8] = {};
    for (int z = 0; z < 8; ++z) {
        union { int4 v; bf h[8]; } u;
        u.v = *(const int4*)(p + (size_t)z * 524288);
#pragma unroll
        for (int e = 0; e < 8; ++e) acc[e] += __bfloat162float(u.h[e]);
    }
    const float inv = 1.0f / rsum[j >> 7];
    union { bf h[8]; int4 v; } o;
#pragma unroll
    for (int e = 0; e < 8; ++e) o.h[e] = __float2bfloat16(acc[e] * inv);
    *(int4*)(Yhat + j) = o.v;
}

// dual row L2-normalize + bf16 out: out[b] = bf16(Gs[b]/||Gs[b]|| + Gt[b]/||Gt[b]||)
__global__ __launch_bounds__(256)
void rownorm2b(const float* __restrict__ G, bf* __restrict__ out)
{
    __shared__ float red[16];
    const int tid = threadIdx.x;
    const float* ps = G + (size_t)blockIdx.x * D_DIM;
    const float* pt = ps + (size_t)B_ROWS * D_DIM;
    float4 a = *(const float4*)(ps + tid * 4);
    float4 c = *(const float4*)(pt + tid * 4);
    float sa = a.x * a.x + a.y * a.y + a.z * a.z + a.w * a.w;
    float sb = c.x * c.x + c.y * c.y + c.z * c.z + c.w * c.w;
    for (int s = 32; s > 0; s >>= 1) {
        sa += __shfl_down(sa, s, 64);
        sb += __shfl_down(sb, s, 64);
    }
    if ((tid & 63) == 0) { red[tid >> 6] = sa; red[8 + (tid >> 6)] = sb; }
    __syncthreads();
    if (tid == 0) {
        float ta = 0.f, tb = 0.f;
        for (int w = 0; w < 4; ++w) { ta += red[w]; tb += red[8 + w]; }
        red[4] = rsqrtf(ta); red[12] = rsqrtf(tb);
    }
    __syncthreads();
    const float ia = red[4], ib = red[12];
    union { bf h[4]; int2 v; } o;
    o.h[0] = __float2bfloat16(a.x * ia + c.x * ib);
    o.h[1] = __float2bfloat16(a.y * ia + c.y * ib);
    o.h[2] = __float2bfloat16(a.z * ia + c.z * ib);
    o.h[3] = __float2bfloat16(a.w * ia + c.w * ib);
    *(int2*)(out + (size_t)blockIdx.x * D_DIM + tid * 4) = o.v;
}

// ---------------------------------------------------------------------------
// Rank-128 attention factorization (see R1 notes):
//   S = exp(SCALE*(h2q@Wqk@h2k^T + beta[n]))  [row-const terms cancel in softmax]
//   Y = (A_norm @ h2_bank);  out-proj uses folded Wpv = Wp@W3v, bvp = Wp@b3v+bp.
// This round: dispatch fusion (26->14), vveck parallelized, rowsum fused into
// the exp-GEMM epilogue via atomics, both sides merged into single GEMMs.
// ---------------------------------------------------------------------------
extern "C" void kernel_launch(void* const* d_in, const int* in_sizes, int n_in,
                              void* d_out, int out_size, void* d_ws, size_t ws_size,
                              hipStream_t stream)
{
    (void)in_sizes; (void)n_in; (void)out_size; (void)ws_size;

    const float* Ft  = (const float*)d_in[0];
    const float* Fv  = (const float*)d_in[1];
    const float* Fvs = (const float*)d_in[2];
    const float* Fvt = (const float*)d_in[3];
    const float* W1  = (const float*)d_in[4];
    const float* b1  = (const float*)d_in[5];
    const float* g1  = (const float*)d_in[6];
    const float* be1 = (const float*)d_in[7];
    const float* m1  = (const float*)d_in[8];
    const float* v1  = (const float*)d_in[9];
    const float* W2  = (const float*)d_in[10];
    const float* b2  = (const float*)d_in[11];
    const float* g2  = (const float*)d_in[12];
    const float* be2 = (const float*)d_in[13];
    const float* m2  = (const float*)d_in[14];
    const float* v2  = (const float*)d_in[15];
    const float* W3  = (const float*)d_in[16];
    const float* b3  = (const float*)d_in[17];
    const float* Wp  = (const float*)d_in[18];
    const float* bp  = (const float*)d_in[19];
    const float* ls  = (const float*)d_in[20];

    char* base = (char*)d_ws;
    size_t o = 0;
    auto take = [&](size_t s) { size_t r = o; o += (s + 255) & ~(size_t)255; return r; };

    // persistent (~19 MB)
    bf* qtb   = (bf*)(base + take((size_t)B_ROWS * P_DIM * 2));
    bf* h2T   = (bf*)(base + take((size_t)P_DIM * 2 * NBANK * 2));
    bf* Yhat  = (bf*)(base + take((size_t)2 * B_ROWS * P_DIM * 2));
    bf* Wpb   = (bf*)(base + take((size_t)D_DIM * D_DIM * 2));
    bf* Ftb   = (bf*)(base + take((size_t)D_DIM * D_DIM * 2));
    bf* W3qT  = (bf*)(base + take((size_t)P_DIM * D_DIM * 2));
    bf* W3kT  = (bf*)(base + take((size_t)P_DIM * D_DIM * 2));
    bf* W3vT  = (bf*)(base + take((size_t)P_DIM * D_DIM * 2));
    bf* Wqk   = (bf*)(base + take((size_t)P_DIM * P_DIM * 2));
    bf* Wpvb  = (bf*)(base + take((size_t)D_DIM * P_DIM * 2));
    bf* W1b   = (bf*)(base + take((size_t)P_DIM * D_DIM * 2));
    bf* W2b   = (bf*)(base + take((size_t)P_DIM * P_DIM * 2));
    bf* h2b   = (bf*)(base + take((size_t)MTOT * P_DIM * 2));
    bf* WqkP  = (bf*)(base + take((size_t)8 * P_DIM * P_DIM * 2));
    bf* WpvP  = (bf*)(base + take((size_t)4 * D_DIM * P_DIM * 2));
    float* vvecP = (float*)(base + take((size_t)16 * P_DIM * 4));
    float* beta  = (float*)(base + take((size_t)2 * NBANK * 4));
    float* bvp   = (float*)(base + take(D_DIM * 4));
    float* rsum  = (float*)(base + take((size_t)2 * B_ROWS * 4));

    // scratch region (aliased across phases)
    const size_t Dbase = o;
    bf* Xb    = (bf*)(base + Dbase);                                   // 40 MB
    bf* h1b   = (bf*)(base + Dbase + (size_t)MTOT * D_DIM * 2);        // 5 MB
    bf* Sb    = (bf*)(base + Dbase);                                   // 128 MB
    bf* Opart = (bf*)(base + Dbase + (size_t)B_ROWS * 2 * NBANK * 2);  // 16 MB
    float* G     = (float*)(base + Dbase);                             // 32 MB
    bf*    Fsumb = (bf*)(base + Dbase + (size_t)2 * B_ROWS * D_DIM * 4);

    auto gemm = [&](const bf* A, const bf* B, int M, int N, int K, int lda, int ldb,
                    int kch, int fx, int fy, int epi, float* Cf, bf* Cb,
                    const float* bias, const float* biasm,
                    const float* bg, const float* bb, const float* bm, const float* bv,
                    const float* addsrc, const float* lsp, int ldc, float* rsp) {
        gemm_bf16<<<dim3(N / 128, M / 128, kch), dim3(256), 0, stream>>>(
            A, B, M, N, K, lda, ldb, kch, fx, fy, epi, Cf, Cb, bias, biasm,
            bg, bb, bm, bv, addsrc, lsp, ldc, rsp);
    };

    // 1) prep: all input-only transforms
    prep<<<dim3(PG0 + PG1 + PG2 + PG3 + PG4 + PG5 + PG6), dim3(256), 0, stream>>>(
        Fv, Fvs, Fvt, W1, W2, Wp, W3, b3, bp, Ft,
        Xb, W1b, W2b, Wpb, W3qT, W3kT, W3vT, Ftb, rsum, vvecP, bvp);

    // 2-3) split-K weight folds: Wqk = (W3k^T W3q)^T-form, Wpv = Wp@W3v
    gemm(W3kT, W3qT, P_DIM, P_DIM, D_DIM, D_DIM, D_DIM, 8, 1, 1, 6, nullptr, WqkP,
         nullptr, nullptr, nullptr, nullptr, nullptr, nullptr, nullptr, nullptr, 0, nullptr);
    gemm(Wpb, W3vT, D_DIM, P_DIM, D_DIM, D_DIM, D_DIM, 4, 1, 8, 6, nullptr, WpvP,
         nullptr, nullptr, nullptr, nullptr, nullptr, nullptr, nullptr, nullptr, 0, nullptr);
    // 4) fused reduces
    reduceWW<<<dim3(72), dim3(256), 0, stream>>>(WqkP, WpvP, Wqk, Wpvb);

    // 5-6) batched pre_project -> h2 [20480,128]
    gemm(Xb, W1b, MTOT, P_DIM, D_DIM, D_DIM, D_DIM, 1, 1, 8, 1, nullptr, h1b,
         b1, nullptr, g1, be1, m1, v1, nullptr, nullptr, 0, nullptr);
    gemm(h1b, W2b, MTOT, P_DIM, P_DIM, P_DIM, P_DIM, 1, 1, 8, 1, nullptr, h2b,
         b2, nullptr, g2, be2, m2, v2, nullptr, nullptr, 0, nullptr);
    // 7) Qtilde = h2q @ Wqk
    gemm(h2b, Wqk, B_ROWS, P_DIM, P_DIM, P_DIM, P_DIM, 1, 1, 8, 5, nullptr, qtb,
         nullptr, nullptr, nullptr, nullptr, nullptr, nullptr, nullptr, nullptr, 0, nullptr);
    // 8) beta + h2 transpose
    posth2<<<dim3(320), dim3(256), 0, stream>>>(
        h2b + (size_t)B_ROWS * P_DIM, vvecP, beta, h2T);

    // 9) merged exp-S GEMM over both sides, fused rowsum atomics
    gemm(qtb, h2b + (size_t)B_ROWS * P_DIM, B_ROWS, 2 * NBANK, P_DIM, P_DIM, P_DIM,
         1, 4, 2, 7, nullptr, Sb, beta, nullptr, nullptr, nullptr, nullptr, nullptr,
         nullptr, nullptr, NBANK, rsum);
    // 10) merged split-K A@h2 over both sides (parts 0-7 side0, 8-15 side1)
    gemm(Sb, h2T, B_ROWS, P_DIM, 2 * NBANK, 2 * NBANK, 2 * NBANK, 16, 1, 8, 6,
         nullptr, Opart, nullptr, nullptr, nullptr, nullptr, nullptr, nullptr,
         nullptr, nullptr, 0, nullptr);
    // 11) reduce parts + softmax normalize -> Yhat [2*B_ROWS,128]
    reduceY<<<dim3(2 * B_ROWS * P_DIM / 2048), dim3(256), 0, stream>>>(
        Opart, rsum, Yhat);

    // 12) combined post-project (K=128) + residual
    gemm(Yhat, Wpvb, 2 * B_ROWS, D_DIM, P_DIM, P_DIM, P_DIM, 1, 1, 8, 3, G, nullptr,
         bvp, nullptr, nullptr, nullptr, nullptr, nullptr, Fv, nullptr, B_ROWS, nullptr);
    // 13) dual rownorm -> bf16
    rownorm2b<<<dim3(B_ROWS), dim3(256), 0, stream>>>(G, Fsumb);
    // 14) logits
    gemm(Fsumb, Ftb, B_ROWS, D_DIM, D_DIM, D_DIM, D_DIM, 1, 1, 8, 4, (float*)d_out,
         nullptr, nullptr, nullptr, nullptr, nullptr, nullptr, nullptr, nullptr,
         ls, C_CLS, nullptr);
}

// Round 3
// 509.180 us; speedup vs baseline: 1.6698x; 1.0675x over previous
//
#include <hip/hip_runtime.h>
#include <hip/hip_bf16.h>
#include <math.h>

#define D_DIM   1024
#define P_DIM   128
#define B_ROWS  4096
#define NBANK   8192
#define C_CLS   1000
#define EPS_BN  1e-5f
#define SCALE_S 0.1f
#define MTOT    20480   // 4096 + 8192 + 8192 batched pre_project rows

typedef __bf16 bf16x8 __attribute__((ext_vector_type(8)));
typedef float  f32x4  __attribute__((ext_vector_type(4)));
typedef __hip_bfloat16 bf;

__device__ __forceinline__ void load_lds16(const void* gp, void* lp) {
    __builtin_amdgcn_global_load_lds(
        (__attribute__((address_space(1))) void*)gp,
        (__attribute__((address_space(3))) void*)lp, 16, 0, 0);
}

__device__ __forceinline__ int4 pack8(float4 a, float4 b) {
    union { bf h[8]; int4 v; } u;
    u.h[0] = __float2bfloat16(a.x); u.h[1] = __float2bfloat16(a.y);
    u.h[2] = __float2bfloat16(a.z); u.h[3] = __float2bfloat16(a.w);
    u.h[4] = __float2bfloat16(b.x); u.h[5] = __float2bfloat16(b.y);
    u.h[6] = __float2bfloat16(b.z); u.h[7] = __float2bfloat16(b.w);
    return u.v;
}

// ---------------------------------------------------------------------------
// bf16 MFMA GEMM: C[M,N] = A[M,K] @ B[N,K]^T (row-major bf16), 128x128 tile.
// A row stride = lda; B row stride = ldb. kchunks>1 -> split-K via blockIdx.z.
// epi: 1 +bias,BN,ReLU -> bf16 | 3 fp32 +bias + addsrc[(gm&(ldc-1))*N+gn] |
//      4 fp32 *exp(*lsp), cols<ldc | 5 bf16 (+bias[n], +biasm[m]) |
//      6 bf16 partial at Cb + z*M*N | 7 bf16 exp(SCALE_S*(val + bias[n]))
//        + per-block row sums -> rsumP[bx][bm0+row] (LDS-combined, NO atomics;
//        R2's atomicAdd rowsum was a 217us disaster: ~1024 serialized atomics
//        per cache line at device scope)
// bf16 epis (1,5,6,7) store via per-wave LDS staging -> dwordx4 coalesced.
// ---------------------------------------------------------------------------
__global__ __launch_bounds__(256)
void gemm_bf16(const bf* __restrict__ A, const bf* __restrict__ B,
               int M, int N, int K, int lda, int ldb,
               int kchunks, int fx, int fy, int epi,
               float* __restrict__ Cf, bf* __restrict__ Cb,
               const float* __restrict__ bias, const float* __restrict__ biasm,
               const float* __restrict__ bng, const float* __restrict__ bnb,
               const float* __restrict__ bnm, const float* __restrict__ bnv,
               const float* __restrict__ addsrc, const float* __restrict__ lsp,
               int ldc, float* __restrict__ rsumP)
{
    __shared__ __align__(16) short ldsS[8192];   // 16 KB
    __shared__ float lds_rs[2][128];             // epi-7 row-sum combine
    short* lsA = ldsS;          // [128][32]
    short* lsB = ldsS + 4096;   // [128][32]

    const int tid  = threadIdx.x;
    const int wave = tid >> 6;
    const int lane = tid & 63;
    const int wm   = wave >> 1;
    const int wn   = wave & 1;
    const int r16  = lane & 15;
    const int quad = lane >> 4;

    // XCD-aware tile remap
    const int gx = gridDim.x, gy = gridDim.y;
    const int l   = blockIdx.y * gx + blockIdx.x;
    const int xcd = l & 7;
    const int i0  = l >> 3;
    const int sx  = gx / fx, sy = gy / fy;
    const int bx  = (xcd % fx) * sx + (i0 % sx);
    const int by  = (xcd / fx) * sy + (i0 / sx);
    const int bm0 = by * 128;
    const int bn0 = bx * 128;

    const int kper = K / kchunks;
    const int kbeg = blockIdx.z * kper;
    const int kend = kbeg + kper;

    f32x4 acc[4][4];
#pragma unroll
    for (int i = 0; i < 4; ++i)
#pragma unroll
        for (int j = 0; j < 4; ++j) acc[i][j] = (f32x4){0.f, 0.f, 0.f, 0.f};

    for (int k0 = kbeg; k0 < kend; k0 += 32) {
#pragma unroll
        for (int i = 0; i < 2; ++i) {
            const int s   = i * 256 + tid;
            const int row = s >> 2;
            const int cc  = (s & 3) * 8;
            const int lofs = (i * 256 + wave * 64) * 16;
            load_lds16(A + (size_t)(bm0 + row) * lda + k0 + cc, (char*)lsA + lofs);
            load_lds16(B + (size_t)(bn0 + row) * ldb + k0 + cc, (char*)lsB + lofs);
        }
        __syncthreads();

        bf16x8 af[4], bfr[4];
#pragma unroll
        for (int i = 0; i < 4; ++i)
            af[i] = *(const bf16x8*)(lsA + (wm * 64 + i * 16 + r16) * 32 + quad * 8);
#pragma unroll
        for (int j = 0; j < 4; ++j)
            bfr[j] = *(const bf16x8*)(lsB + (wn * 64 + j * 16 + r16) * 32 + quad * 8);
#pragma unroll
        for (int i = 0; i < 4; ++i)
#pragma unroll
            for (int j = 0; j < 4; ++j)
                acc[i][j] = __builtin_amdgcn_mfma_f32_16x16x32_bf16(
                    af[i], bfr[j], acc[i][j], 0, 0, 0);
        __syncthreads();
    }
    // after final barrier all LDS fragment reads are complete -> safe to reuse

    if (epi == 3 || epi == 4) {
        const float lsv = (epi == 4) ? expf(*lsp) : 1.0f;
#pragma unroll
        for (int i = 0; i < 4; ++i) {
            const int gmb = bm0 + wm * 64 + i * 16 + quad * 4;
#pragma unroll
            for (int j = 0; j < 4; ++j) {
                const int gn = bn0 + wn * 64 + j * 16 + r16;
#pragma unroll
                for (int r = 0; r < 4; ++r) {
                    const int gm = gmb + r;
                    float val = acc[i][j][r];
                    if (epi == 3) {
                        Cf[(size_t)gm * N + gn] =
                            val + bias[gn] + addsrc[(size_t)(gm & (ldc - 1)) * N + gn];
                    } else {
                        if (gn < ldc) Cf[(size_t)gm * ldc + gn] = val * lsv;
                    }
                }
            }
        }
        return;
    }

    // bf16 LDS-staged store path (epi 1, 5, 6, 7)
    bf* dst = Cb + (epi == 6 ? (size_t)blockIdx.z * M * N : 0);
    bf* my  = (bf*)(ldsS + wave * 2048);   // 4 KB per wave: [32][64] bf16
    const bool dorsum = (epi == 7) && (rsumP != nullptr);

#pragma unroll
    for (int half = 0; half < 2; ++half) {
#pragma unroll
        for (int i2 = 0; i2 < 2; ++i2) {
            const int i = half * 2 + i2;
            const int gmb = bm0 + wm * 64 + i * 16 + quad * 4;
            float rsv[4] = {0.f, 0.f, 0.f, 0.f};
#pragma unroll
            for (int j = 0; j < 4; ++j) {
                const int gn = bn0 + wn * 64 + j * 16 + r16;
#pragma unroll
                for (int r = 0; r < 4; ++r) {
                    float val = acc[i][j][r];
                    if (epi == 1) {
                        val += bias[gn];
                        val = (val - bnm[gn]) * rsqrtf(bnv[gn] + EPS_BN) * bng[gn] + bnb[gn];
                        val = fmaxf(val, 0.f);
                    } else if (epi == 7) {
                        val = __expf(SCALE_S * (val + (bias ? bias[gn] : 0.f)));
                        rsv[r] += val;
                    } else {
                        if (bias)  val += bias[gn];
                        if (biasm) val += biasm[gmb + r];
                    }
                    my[(i2 * 16 + quad * 4 + r) * 64 + j * 16 + r16] =
                        __float2bfloat16(val);
                }
            }
            if (dorsum) {
                // reduce each row partial across the 16-lane r16 group,
                // stash per-wave row sums in LDS (wave-exclusive slots)
#pragma unroll
                for (int r = 0; r < 4; ++r) {
                    float s = rsv[r];
                    s += __shfl_xor(s, 1, 64);
                    s += __shfl_xor(s, 2, 64);
                    s += __shfl_xor(s, 4, 64);
                    s += __shfl_xor(s, 8, 64);
                    if (r16 == 0)
                        lds_rs[wn][wm * 64 + i * 16 + quad * 4 + r] = s;
                }
            }
        }
#pragma unroll
        for (int it = 0; it < 4; ++it) {
            const int chunk = it * 64 + lane;
            const int lrow  = chunk >> 3;
            const int lcol  = (chunk & 7) * 8;
            const int grow  = bm0 + wm * 64 + half * 32 + lrow;
            const int gcol  = bn0 + wn * 64 + lcol;
            int4 v = *(const int4*)(my + lrow * 64 + lcol);
            *(int4*)(dst + (size_t)grow * N + gcol) = v;
        }
    }

    if (dorsum) {
        __syncthreads();
        if (tid < 128)
            rsumP[(size_t)bx * M + bm0 + tid] = lds_rs[0][tid] + lds_rs[1][tid];
    }
}

// rsum[s*B+b] = sum_z rsumP[(s*64+z)*B + b]   (32 blocks x 256)
__global__ __launch_bounds__(256)
void rsred(const float* __restrict__ rsumP, float* __restrict__ rsum)
{
    const int gid = blockIdx.x * 256 + threadIdx.x;   // 0..8191
    const int s = gid >> 12, b = gid & 4095;
    const float* p = rsumP + (size_t)(s * 64) * B_ROWS + b;
    float t = 0.f;
#pragma unroll 8
    for (int z = 0; z < 64; ++z) t += p[(size_t)z * B_ROWS];
    rsum[gid] = t;
}

// ---------------------------------------------------------------------------
// prep mega-kernel: all input-only transforms in ONE dispatch (range-split).
//  r0 convX | r1 convW | r2 convW3T | r3 ftpad |
//  r4 vvec partials (vvecP[16][128]) | r5 bvp = Wp@b3v + bp
// ---------------------------------------------------------------------------
#define PG0 10240   // convX: MTOT*D/2048
#define PG1 584     // convW: (P*D + P*P + D*D)/2048
#define PG2 64      // convW3T: P*D/2048
#define PG3 512     // ftpad: D*D/2048
#define PG4 8       // vvecP partials
#define PG5 256     // bvp

__global__ __launch_bounds__(256)
void prep(const float* __restrict__ Fv, const float* __restrict__ Fvs,
          const float* __restrict__ Fvt,
          const float* __restrict__ W1, const float* __restrict__ W2,
          const float* __restrict__ Wp,
          const float* __restrict__ W3, const float* __restrict__ b3,
          const float* __restrict__ bp, const float* __restrict__ Ft,
          bf* __restrict__ Xb, bf* __restrict__ W1b, bf* __restrict__ W2b,
          bf* __restrict__ Wpb,
          bf* __restrict__ Tq, bf* __restrict__ Tk, bf* __restrict__ Tv,
          bf* __restrict__ Ftb,
          float* __restrict__ vvecP, float* __restrict__ bvp)
{
    const int tid = threadIdx.x;
    int b = blockIdx.x;
    if (b < PG0) {                       // ---- convX: Fv|Fvs|Fvt -> bf16
        int i = (b * 256 + tid) * 8;
        const int n0 = B_ROWS * D_DIM, n1 = n0 + NBANK * D_DIM;
        const float* src; int off;
        if (i < n0)      { src = Fv;  off = i; }
        else if (i < n1) { src = Fvs; off = i - n0; }
        else             { src = Fvt; off = i - n1; }
        float4 a = *(const float4*)(src + off);
        float4 c = *(const float4*)(src + off + 4);
        *(int4*)(Xb + i) = pack8(a, c);
        return;
    }
    if ((b -= PG0) < PG1) {              // ---- convW: W1|W2|Wp -> bf16
        int i = (b * 256 + tid) * 8;
        const int n1 = P_DIM * D_DIM, n2 = n1 + P_DIM * P_DIM;
        const float* src; bf* dst; int off;
        if (i < n1)      { src = W1; dst = W1b; off = i; }
        else if (i < n2) { src = W2; dst = W2b; off = i - n1; }
        else             { src = Wp; dst = Wpb; off = i - n2; }
        float4 a = *(const float4*)(src + off);
        float4 c = *(const float4*)(src + off + 4);
        *(int4*)(dst + off) = pack8(a, c);
        return;
    }
    if ((b -= PG1) < PG2) {              // ---- convW3T: Txx[p,d] = W3[3d+x,p]
        int i = (b * 256 + tid) * 8;     // [128][1024] elem idx
        int p = i >> 10, d0 = i & 1023;
        union { bf h[8]; int4 v; } uq, uk, uv;
#pragma unroll
        for (int j = 0; j < 8; ++j) {
            const float* r = W3 + (size_t)3 * (d0 + j) * P_DIM + p;
            uq.h[j] = __float2bfloat16(r[0]);
            uk.h[j] = __float2bfloat16(r[P_DIM]);
            uv.h[j] = __float2bfloat16(r[2 * P_DIM]);
        }
        *(int4*)(Tq + i) = uq.v;
        *(int4*)(Tk + i) = uk.v;
        *(int4*)(Tv + i) = uv.v;
        return;
    }
    if ((b -= PG2) < PG3) {              // ---- ftpad: Ft -> [1024,1024] bf16
        int i = (b * 256 + tid) * 8;
        int row = i >> 10, col = i & 1023;
        if (row < C_CLS) {
            float4 a = *(const float4*)(Ft + (size_t)row * D_DIM + col);
            float4 c = *(const float4*)(Ft + (size_t)row * D_DIM + col + 4);
            *(int4*)(Ftb + i) = pack8(a, c);
        } else {
            *(int4*)(Ftb + i) = (int4){0, 0, 0, 0};
        }
        return;
    }
    if ((b -= PG3) < PG4) {              // ---- vvecP[z][p] partials of W3k^T b3q
        const int p = tid & 127, hf = tid >> 7;
        const int dbase = b * 128 + hf * 64;
        float s = 0.f;
        for (int dd = 0; dd < 64; ++dd) {
            const int d = dbase + dd;
            s = fmaf(b3[3 * d], W3[(size_t)(3 * d + 1) * P_DIM + p], s);
        }
        vvecP[(b * 2 + hf) * P_DIM + p] = s;
        return;
    }
    b -= PG4;                            // ---- bvp[o] = Wp[o,:].b3v + bp[o]
    const int wave = tid >> 6, lane = tid & 63;
    const int o = b * 4 + wave;
    const float* r = Wp + (size_t)o * D_DIM;
    float s = 0.f;
    for (int i = lane; i < D_DIM; i += 64) s = fmaf(r[i], b3[3 * i + 2], s);
    for (int off = 32; off > 0; off >>= 1) s += __shfl_down(s, off, 64);
    if (lane == 0) bvp[o] = s + bp[o];
}

// fused reduce for split-K weight-fold GEMMs: Wqk (8 parts) + Wpv (4 parts)
__global__ __launch_bounds__(256)
void reduceWW(const bf* __restrict__ WqkP, const bf* __restrict__ WpvP,
              bf* __restrict__ Wqk, bf* __restrict__ Wpv)
{
    const int tid = threadIdx.x;
    if (blockIdx.x < 8) {
        int i = (blockIdx.x * 256 + tid) * 8;          // < 16384
        float s[8] = {};
        for (int z = 0; z < 8; ++z) {
            union { int4 v; bf h[8]; } u;
            u.v = *(const int4*)(WqkP + (size_t)z * 16384 + i);
#pragma unroll
            for (int e = 0; e < 8; ++e) s[e] += __bfloat162float(u.h[e]);
        }
        union { bf h[8]; int4 v; } o;
#pragma unroll
        for (int e = 0; e < 8; ++e) o.h[e] = __float2bfloat16(s[e]);
        *(int4*)(Wqk + i) = o.v;
    } else {
        int i = ((blockIdx.x - 8) * 256 + tid) * 8;    // < 131072
        float s[8] = {};
        for (int z = 0; z < 4; ++z) {
            union { int4 v; bf h[8]; } u;
            u.v = *(const int4*)(WpvP + (size_t)z * 131072 + i);
#pragma unroll
            for (int e = 0; e < 8; ++e) s[e] += __bfloat162float(u.h[e]);
        }
        union { bf h[8]; int4 v; } o;
#pragma unroll
        for (int e = 0; e < 8; ++e) o.h[e] = __float2bfloat16(s[e]);
        *(int4*)(Wpv + i) = o.v;
    }
}

// posth2: r0 (64 blocks) beta[n] = h2bank[n,:].vvec | r1 (256) h2 transpose
__global__ __launch_bounds__(256)
void posth2(const bf* __restrict__ h2bank, const float* __restrict__ vvecP,
            float* __restrict__ beta, bf* __restrict__ h2T)
{
    __shared__ float vs[P_DIM];
    __shared__ bf t[64][136];
    const int tid = threadIdx.x;
    if (blockIdx.x < 64) {
        if (tid < P_DIM) {
            float s = 0.f;
#pragma unroll
            for (int z = 0; z < 16; ++z) s += vvecP[z * P_DIM + tid];
            vs[tid] = s;
        }
        __syncthreads();
        const int n = blockIdx.x * 256 + tid;
        const bf* r = h2bank + (size_t)n * P_DIM;
        float s = 0.f;
#pragma unroll
        for (int c = 0; c < P_DIM; c += 8) {
            union { int4 q; bf h[8]; } u;
            u.q = *(const int4*)(r + c);
#pragma unroll
            for (int e = 0; e < 8; ++e) s += __bfloat162float(u.h[e]) * vs[c + e];
        }
        beta[n] = s;
    } else {
        const size_t n0 = (size_t)(blockIdx.x - 64) * 64;
#pragma unroll
        for (int q = 0; q < 4; ++q) {
            int idx = (q * 256 + tid) * 8;       // 0..8191
            int r = idx >> 7, c = idx & 127;
            *(int4*)&t[r][c] = *(const int4*)(h2bank + (n0 + r) * P_DIM + c);
        }
        __syncthreads();
        const int p  = tid >> 1;
        const int nb = (tid & 1) * 32;
#pragma unroll
        for (int q = 0; q < 4; ++q) {
            const int n = nb + q * 8;
            union { int4 v; bf h[8]; } u;
#pragma unroll
            for (int e = 0; e < 8; ++e) u.h[e] = t[n + e][p];
            *(int4*)(h2T + (size_t)p * (2 * NBANK) + n0 + n) = u.v;
        }
    }
}

// reduceY: Yhat[s][b][p] = sum_{z in s*8..s*8+7} parts[z][b][p] / rsum[s*B+b]
__global__ __launch_bounds__(256)
void reduceY(const bf* __restrict__ parts, const float* __restrict__ rsum,
             bf* __restrict__ Yhat)
{
    int j = (blockIdx.x * 256 + threadIdx.x) * 8;      // < 2*B_ROWS*P_DIM
    const int s = j >> 19;                             // B_ROWS*P_DIM = 2^19
    const size_t inner = (size_t)(j & 524287);
    const bf* p = parts + (size_t)s * 8 * 524288 + inner;
    float acc[8] = {};
    for (int z = 0; z < 8; ++z) {
        union { int4 v; bf h[8]; } u;
        u.v = *(const int4*)(p + (size_t)z * 524288);
#pragma unroll
        for (int e = 0; e < 8; ++e) acc[e] += __bfloat162float(u.h[e]);
    }
    const float inv = 1.0f / rsum[j >> 7];
    union { bf h[8]; int4 v; } o;
#pragma unroll
    for (int e = 0; e < 8; ++e) o.h[e] = __float2bfloat16(acc[e] * inv);
    *(int4*)(Yhat + j) = o.v;
}

// dual row L2-normalize + bf16 out: out[b] = bf16(Gs[b]/||Gs[b]|| + Gt[b]/||Gt[b]||)
__global__ __launch_bounds__(256)
void rownorm2b(const float* __restrict__ G, bf* __restrict__ out)
{
    __shared__ float red[16];
    const int tid = threadIdx.x;
    const float* ps = G + (size_t)blockIdx.x * D_DIM;
    const float* pt = ps + (size_t)B_ROWS * D_DIM;
    float4 a = *(const float4*)(ps + tid * 4);
    float4 c = *(const float4*)(pt + tid * 4);
    float sa = a.x * a.x + a.y * a.y + a.z * a.z + a.w * a.w;
    float sb = c.x * c.x + c.y * c.y + c.z * c.z + c.w * c.w;
    for (int s = 32; s > 0; s >>= 1) {
        sa += __shfl_down(sa, s, 64);
        sb += __shfl_down(sb, s, 64);
    }
    if ((tid & 63) == 0) { red[tid >> 6] = sa; red[8 + (tid >> 6)] = sb; }
    __syncthreads();
    if (tid == 0) {
        float ta = 0.f, tb = 0.f;
        for (int w = 0; w < 4; ++w) { ta += red[w]; tb += red[8 + w]; }
        red[4] = rsqrtf(ta); red[12] = rsqrtf(tb);
    }
    __syncthreads();
    const float ia = red[4], ib = red[12];
    union { bf h[4]; int2 v; } o;
    o.h[0] = __float2bfloat16(a.x * ia + c.x * ib);
    o.h[1] = __float2bfloat16(a.y * ia + c.y * ib);
    o.h[2] = __float2bfloat16(a.z * ia + c.z * ib);
    o.h[3] = __float2bfloat16(a.w * ia + c.w * ib);
    *(int2*)(out + (size_t)blockIdx.x * D_DIM + tid * 4) = o.v;
}

// ---------------------------------------------------------------------------
// Rank-128 attention factorization (see R1 notes):
//   S = exp(SCALE*(h2q@Wqk@h2k^T + beta[n]))  [row-const terms cancel in softmax]
//   Y = (A_norm @ h2_bank);  out-proj uses folded Wpv = Wp@W3v, bvp = Wp@b3v+bp.
// R3: rowsum fusion kept but via per-block LDS-combined partials + tiny rsred
// kernel (replaces R2's contended global atomics).
// ---------------------------------------------------------------------------
extern "C" void kernel_launch(void* const* d_in, const int* in_sizes, int n_in,
                              void* d_out, int out_size, void* d_ws, size_t ws_size,
                              hipStream_t stream)
{
    (void)in_sizes; (void)n_in; (void)out_size; (void)ws_size;

    const float* Ft  = (const float*)d_in[0];
    const float* Fv  = (const float*)d_in[1];
    const float* Fvs = (const float*)d_in[2];
    const float* Fvt = (const float*)d_in[3];
    const float* W1  = (const float*)d_in[4];
    const float* b1  = (const float*)d_in[5];
    const float* g1  = (const float*)d_in[6];
    const float* be1 = (const float*)d_in[7];
    const float* m1  = (const float*)d_in[8];
    const float* v1  = (const float*)d_in[9];
    const float* W2  = (const float*)d_in[10];
    const float* b2  = (const float*)d_in[11];
    const float* g2  = (const float*)d_in[12];
    const float* be2 = (const float*)d_in[13];
    const float* m2  = (const float*)d_in[14];
    const float* v2  = (const float*)d_in[15];
    const float* W3  = (const float*)d_in[16];
    const float* b3  = (const float*)d_in[17];
    const float* Wp  = (const float*)d_in[18];
    const float* bp  = (const float*)d_in[19];
    const float* ls  = (const float*)d_in[20];

    char* base = (char*)d_ws;
    size_t o = 0;
    auto take = [&](size_t s) { size_t r = o; o += (s + 255) & ~(size_t)255; return r; };

    // persistent (~21 MB)
    bf* qtb   = (bf*)(base + take((size_t)B_ROWS * P_DIM * 2));
    bf* h2T   = (bf*)(base + take((size_t)P_DIM * 2 * NBANK * 2));
    bf* Yhat  = (bf*)(base + take((size_t)2 * B_ROWS * P_DIM * 2));
    bf* Wpb   = (bf*)(base + take((size_t)D_DIM * D_DIM * 2));
    bf* Ftb   = (bf*)(base + take((size_t)D_DIM * D_DIM * 2));
    bf* W3qT  = (bf*)(base + take((size_t)P_DIM * D_DIM * 2));
    bf* W3kT  = (bf*)(base + take((size_t)P_DIM * D_DIM * 2));
    bf* W3vT  = (bf*)(base + take((size_t)P_DIM * D_DIM * 2));
    bf* Wqk   = (bf*)(base + take((size_t)P_DIM * P_DIM * 2));
    bf* Wpvb  = (bf*)(base + take((size_t)D_DIM * P_DIM * 2));
    bf* W1b   = (bf*)(base + take((size_t)P_DIM * D_DIM * 2));
    bf* W2b   = (bf*)(base + take((size_t)P_DIM * P_DIM * 2));
    bf* h2b   = (bf*)(base + take((size_t)MTOT * P_DIM * 2));
    bf* WqkP  = (bf*)(base + take((size_t)8 * P_DIM * P_DIM * 2));
    bf* WpvP  = (bf*)(base + take((size_t)4 * D_DIM * P_DIM * 2));
    float* vvecP = (float*)(base + take((size_t)16 * P_DIM * 4));
    float* beta  = (float*)(base + take((size_t)2 * NBANK * 4));
    float* bvp   = (float*)(base + take(D_DIM * 4));
    float* rsum  = (float*)(base + take((size_t)2 * B_ROWS * 4));
    float* rsumP = (float*)(base + take((size_t)128 * B_ROWS * 4));   // 2 MB

    // scratch region (aliased across phases)
    const size_t Dbase = o;
    bf* Xb    = (bf*)(base + Dbase);                                   // 40 MB
    bf* h1b   = (bf*)(base + Dbase + (size_t)MTOT * D_DIM * 2);        // 5 MB
    bf* Sb    = (bf*)(base + Dbase);                                   // 128 MB
    bf* Opart = (bf*)(base + Dbase + (size_t)B_ROWS * 2 * NBANK * 2);  // 16 MB
    float* G     = (float*)(base + Dbase);                             // 32 MB
    bf*    Fsumb = (bf*)(base + Dbase + (size_t)2 * B_ROWS * D_DIM * 4);

    auto gemm = [&](const bf* A, const bf* B, int M, int N, int K, int lda, int ldb,
                    int kch, int fx, int fy, int epi, float* Cf, bf* Cb,
                    const float* bias, const float* biasm,
                    const float* bg, const float* bb, const float* bm, const float* bv,
                    const float* addsrc, const float* lsp, int ldc, float* rsp) {
        gemm_bf16<<<dim3(N / 128, M / 128, kch), dim3(256), 0, stream>>>(
            A, B, M, N, K, lda, ldb, kch, fx, fy, epi, Cf, Cb, bias, biasm,
            bg, bb, bm, bv, addsrc, lsp, ldc, rsp);
    };

    // 1) prep: all input-only transforms
    prep<<<dim3(PG0 + PG1 + PG2 + PG3 + PG4 + PG5), dim3(256), 0, stream>>>(
        Fv, Fvs, Fvt, W1, W2, Wp, W3, b3, bp, Ft,
        Xb, W1b, W2b, Wpb, W3qT, W3kT, W3vT, Ftb, vvecP, bvp);

    // 2-3) split-K weight folds: Wqk = (W3k^T W3q)^T-form, Wpv = Wp@W3v
    gemm(W3kT, W3qT, P_DIM, P_DIM, D_DIM, D_DIM, D_DIM, 8, 1, 1, 6, nullptr, WqkP,
         nullptr, nullptr, nullptr, nullptr, nullptr, nullptr, nullptr, nullptr, 0, nullptr);
    gemm(Wpb, W3vT, D_DIM, P_DIM, D_DIM, D_DIM, D_DIM, 4, 1, 8, 6, nullptr, WpvP,
         nullptr, nullptr, nullptr, nullptr, nullptr, nullptr, nullptr, nullptr, 0, nullptr);
    // 4) fused reduces
    reduceWW<<<dim3(72), dim3(256), 0, stream>>>(WqkP, WpvP, Wqk, Wpvb);

    // 5-6) batched pre_project -> h2 [20480,128]
    gemm(Xb, W1b, MTOT, P_DIM, D_DIM, D_DIM, D_DIM, 1, 1, 8, 1, nullptr, h1b,
         b1, nullptr, g1, be1, m1, v1, nullptr, nullptr, 0, nullptr);
    gemm(h1b, W2b, MTOT, P_DIM, P_DIM, P_DIM, P_DIM, 1, 1, 8, 1, nullptr, h2b,
         b2, nullptr, g2, be2, m2, v2, nullptr, nullptr, 0, nullptr);
    // 7) Qtilde = h2q @ Wqk
    gemm(h2b, Wqk, B_ROWS, P_DIM, P_DIM, P_DIM, P_DIM, 1, 1, 8, 5, nullptr, qtb,
         nullptr, nullptr, nullptr, nullptr, nullptr, nullptr, nullptr, nullptr, 0, nullptr);
    // 8) beta + h2 transpose
    posth2<<<dim3(320), dim3(256), 0, stream>>>(
        h2b + (size_t)B_ROWS * P_DIM, vvecP, beta, h2T);

    // 9) merged exp-S GEMM over both sides, per-block rowsum partials (no atomics)
    gemm(qtb, h2b + (size_t)B_ROWS * P_DIM, B_ROWS, 2 * NBANK, P_DIM, P_DIM, P_DIM,
         1, 4, 2, 7, nullptr, Sb, beta, nullptr, nullptr, nullptr, nullptr, nullptr,
         nullptr, nullptr, NBANK, rsumP);
    // 10) fold rsumP[128][4096] -> rsum[2][4096]
    rsred<<<dim3(32), dim3(256), 0, stream>>>(rsumP, rsum);
    // 11) merged split-K A@h2 over both sides (parts 0-7 side0, 8-15 side1)
    gemm(Sb, h2T, B_ROWS, P_DIM, 2 * NBANK, 2 * NBANK, 2 * NBANK, 16, 1, 8, 6,
         nullptr, Opart, nullptr, nullptr, nullptr, nullptr, nullptr, nullptr,
         nullptr, nullptr, 0, nullptr);
    // 12) reduce parts + softmax normalize -> Yhat [2*B_ROWS,128]
    reduceY<<<dim3(2 * B_ROWS * P_DIM / 2048), dim3(256), 0, stream>>>(
        Opart, rsum, Yhat);

    // 13) combined post-project (K=128) + residual
    gemm(Yhat, Wpvb, 2 * B_ROWS, D_DIM, P_DIM, P_DIM, P_DIM, 1, 1, 8, 3, G, nullptr,
         bvp, nullptr, nullptr, nullptr, nullptr, nullptr, Fv, nullptr, B_ROWS, nullptr);
    // 14) dual rownorm -> bf16
    rownorm2b<<<dim3(B_ROWS), dim3(256), 0, stream>>>(G, Fsumb);
    // 15) logits
    gemm(Fsumb, Ftb, B_ROWS, D_DIM, D_DIM, D_DIM, D_DIM, 1, 1, 8, 4, (float*)d_out,
         nullptr, nullptr, nullptr, nullptr, nullptr, nullptr, nullptr, nullptr,
         ls, C_CLS, nullptr);
}

// Round 4
// 396.870 us; speedup vs baseline: 2.1423x; 1.2830x over previous
//
#include <hip/hip_runtime.h>
#include <hip/hip_bf16.h>
#include <math.h>

#define D_DIM   1024
#define P_DIM   128
#define B_ROWS  4096
#define NBANK   8192
#define C_CLS   1000
#define EPS_BN  1e-5f
#define SCALE_S 0.1f
#define MTOT    20480   // 4096 + 8192 + 8192 batched pre_project rows
#define KVSEG   8       // kv segments per side (softmax split)
#define KCH     64      // kv rows per fused chunk
#define CHUNKS  (NBANK / KVSEG / KCH)   // 16

typedef __bf16 bf16x8 __attribute__((ext_vector_type(8)));
typedef float  f32x4  __attribute__((ext_vector_type(4)));
typedef __hip_bfloat16 bf;

__device__ __forceinline__ void load_lds16(const void* gp, void* lp) {
    __builtin_amdgcn_global_load_lds(
        (__attribute__((address_space(1))) void*)gp,
        (__attribute__((address_space(3))) void*)lp, 16, 0, 0);
}

__device__ __forceinline__ int4 pack8(float4 a, float4 b) {
    union { bf h[8]; int4 v; } u;
    u.h[0] = __float2bfloat16(a.x); u.h[1] = __float2bfloat16(a.y);
    u.h[2] = __float2bfloat16(a.z); u.h[3] = __float2bfloat16(a.w);
    u.h[4] = __float2bfloat16(b.x); u.h[5] = __float2bfloat16(b.y);
    u.h[6] = __float2bfloat16(b.z); u.h[7] = __float2bfloat16(b.w);
    return u.v;
}

// ---------------------------------------------------------------------------
// bf16 MFMA GEMM: C[M,N] = A[M,K] @ B[N,K]^T (row-major bf16), 128x128 tile.
// A row stride = lda; B row stride = ldb. kchunks>1 -> split-K via blockIdx.z.
// epi: 1 +bias,BN,ReLU -> bf16 | 3 fp32 +bias + addsrc[(gm&(ldc-1))*N+gn] |
//      4 fp32 *exp(*lsp), cols<ldc | 5 bf16 (+bias[n], +biasm[m]) |
//      6 bf16 partial at Cb + z*M*N
// bf16 epis (1,5,6) store via per-wave LDS staging -> dwordx4 coalesced.
// ---------------------------------------------------------------------------
__global__ __launch_bounds__(256)
void gemm_bf16(const bf* __restrict__ A, const bf* __restrict__ B,
               int M, int N, int K, int lda, int ldb,
               int kchunks, int fx, int fy, int epi,
               float* __restrict__ Cf, bf* __restrict__ Cb,
               const float* __restrict__ bias, const float* __restrict__ biasm,
               const float* __restrict__ bng, const float* __restrict__ bnb,
               const float* __restrict__ bnm, const float* __restrict__ bnv,
               const float* __restrict__ addsrc, const float* __restrict__ lsp,
               int ldc)
{
    __shared__ __align__(16) short ldsS[8192];   // 16 KB
    short* lsA = ldsS;          // [128][32]
    short* lsB = ldsS + 4096;   // [128][32]

    const int tid  = threadIdx.x;
    const int wave = tid >> 6;
    const int lane = tid & 63;
    const int wm   = wave >> 1;
    const int wn   = wave & 1;
    const int r16  = lane & 15;
    const int quad = lane >> 4;

    // XCD-aware tile remap
    const int gx = gridDim.x, gy = gridDim.y;
    const int l   = blockIdx.y * gx + blockIdx.x;
    const int xcd = l & 7;
    const int i0  = l >> 3;
    const int sx  = gx / fx, sy = gy / fy;
    const int bx  = (xcd % fx) * sx + (i0 % sx);
    const int by  = (xcd / fx) * sy + (i0 / sx);
    const int bm0 = by * 128;
    const int bn0 = bx * 128;

    const int kper = K / kchunks;
    const int kbeg = blockIdx.z * kper;
    const int kend = kbeg + kper;

    f32x4 acc[4][4];
#pragma unroll
    for (int i = 0; i < 4; ++i)
#pragma unroll
        for (int j = 0; j < 4; ++j) acc[i][j] = (f32x4){0.f, 0.f, 0.f, 0.f};

    for (int k0 = kbeg; k0 < kend; k0 += 32) {
#pragma unroll
        for (int i = 0; i < 2; ++i) {
            const int s   = i * 256 + tid;
            const int row = s >> 2;
            const int cc  = (s & 3) * 8;
            const int lofs = (i * 256 + wave * 64) * 16;
            load_lds16(A + (size_t)(bm0 + row) * lda + k0 + cc, (char*)lsA + lofs);
            load_lds16(B + (size_t)(bn0 + row) * ldb + k0 + cc, (char*)lsB + lofs);
        }
        __syncthreads();

        bf16x8 af[4], bfr[4];
#pragma unroll
        for (int i = 0; i < 4; ++i)
            af[i] = *(const bf16x8*)(lsA + (wm * 64 + i * 16 + r16) * 32 + quad * 8);
#pragma unroll
        for (int j = 0; j < 4; ++j)
            bfr[j] = *(const bf16x8*)(lsB + (wn * 64 + j * 16 + r16) * 32 + quad * 8);
#pragma unroll
        for (int i = 0; i < 4; ++i)
#pragma unroll
            for (int j = 0; j < 4; ++j)
                acc[i][j] = __builtin_amdgcn_mfma_f32_16x16x32_bf16(
                    af[i], bfr[j], acc[i][j], 0, 0, 0);
        __syncthreads();
    }

    if (epi == 3 || epi == 4) {
        const float lsv = (epi == 4) ? expf(*lsp) : 1.0f;
#pragma unroll
        for (int i = 0; i < 4; ++i) {
            const int gmb = bm0 + wm * 64 + i * 16 + quad * 4;
#pragma unroll
            for (int j = 0; j < 4; ++j) {
                const int gn = bn0 + wn * 64 + j * 16 + r16;
#pragma unroll
                for (int r = 0; r < 4; ++r) {
                    const int gm = gmb + r;
                    float val = acc[i][j][r];
                    if (epi == 3) {
                        Cf[(size_t)gm * N + gn] =
                            val + bias[gn] + addsrc[(size_t)(gm & (ldc - 1)) * N + gn];
                    } else {
                        if (gn < ldc) Cf[(size_t)gm * ldc + gn] = val * lsv;
                    }
                }
            }
        }
        return;
    }

    // bf16 LDS-staged store path (epi 1, 5, 6)
    bf* dst = Cb + (epi == 6 ? (size_t)blockIdx.z * M * N : 0);
    bf* my  = (bf*)(ldsS + wave * 2048);   // 4 KB per wave: [32][64] bf16

#pragma unroll
    for (int half = 0; half < 2; ++half) {
#pragma unroll
        for (int i2 = 0; i2 < 2; ++i2) {
            const int i = half * 2 + i2;
            const int gmb = bm0 + wm * 64 + i * 16 + quad * 4;
#pragma unroll
            for (int j = 0; j < 4; ++j) {
                const int gn = bn0 + wn * 64 + j * 16 + r16;
#pragma unroll
                for (int r = 0; r < 4; ++r) {
                    float val = acc[i][j][r];
                    if (epi == 1) {
                        val += bias[gn];
                        val = (val - bnm[gn]) * rsqrtf(bnv[gn] + EPS_BN) * bng[gn] + bnb[gn];
                        val = fmaxf(val, 0.f);
                    } else {
                        if (bias)  val += bias[gn];
                        if (biasm) val += biasm[gmb + r];
                    }
                    my[(i2 * 16 + quad * 4 + r) * 64 + j * 16 + r16] =
                        __float2bfloat16(val);
                }
            }
        }
#pragma unroll
        for (int it = 0; it < 4; ++it) {
            const int chunk = it * 64 + lane;
            const int lrow  = chunk >> 3;
            const int lcol  = (chunk & 7) * 8;
            const int grow  = bm0 + wm * 64 + half * 32 + lrow;
            const int gcol  = bn0 + wn * 64 + lcol;
            int4 v = *(const int4*)(my + lrow * 64 + lcol);
            *(int4*)(dst + (size_t)grow * N + gcol) = v;
        }
    }
}

// ---------------------------------------------------------------------------
// Fused attention: per block (side, qb, seg) compute over 1024 kv rows:
//   S = exp(SCALE*(qt@h2k^T + beta)) -> (in LDS, never HBM) -> Y += S@V
// K = h2 bank rows; V = same data via h2T (so PV is in native A@B^T form).
// Writes bf16 Y partial [128][128] per (side,qb,seg) + fp32 rowsum partial.
// LDS tiles XOR-swizzled (D=128 row-major = 16/32-way conflict otherwise);
// staged tiles get the swizzle via pre-swizzled GLOBAL source (linear dest),
// the S tile via matching swizzled ds_write/ds_read.
// ---------------------------------------------------------------------------
__global__ __launch_bounds__(256)
void attn_fused(const bf* __restrict__ qt,      // [4096][128]
                const bf* __restrict__ h2bank,  // [16384][128] side-major
                const bf* __restrict__ h2T,     // [128][16384]
                const float* __restrict__ beta, // [16384]
                bf* __restrict__ Ypart,         // [16][4096][128]
                float* __restrict__ rsP)        // [16][4096]
{
    __shared__ __align__(16) short lds[40960];   // 80 KB -> 2 blocks/CU
    short* lsQ = lds;            // [128][128], phys cg = cg ^ (row&15)
    short* lsK = lds + 16384;    // [64][128],  phys cg = cg ^ (row&15)
    short* lsV = lds + 24576;    // [128][64],  phys cg = cg ^ (row&7)
    short* lsS = lds + 32768;    // [128][64],  phys cg = cg ^ (row&7)

    const int tid  = threadIdx.x;
    const int wave = tid >> 6;
    const int lane = tid & 63;
    const int wm   = wave >> 1;
    const int wn   = wave & 1;
    const int r16  = lane & 15;
    const int quad = lane >> 4;

    const int qb   = blockIdx.x >> 4;
    const int side = (blockIdx.x >> 3) & 1;
    const int seg  = blockIdx.x & 7;
    const int part = side * 8 + seg;
    const int nseg0 = seg * (NBANK / KVSEG);
    const bf* kbase = h2bank + (size_t)side * NBANK * P_DIM;
    const int ncol0 = side * NBANK;

    // stage Q tile once (pre-swizzled source)
#pragma unroll
    for (int m = 0; m < 8; ++m) {
        const int s = m * 256 + tid;
        const int row = s >> 4, pcg = s & 15;
        const int lcg = pcg ^ (row & 15);
        load_lds16(qt + (size_t)(qb * 128 + row) * 128 + lcg * 8,
                   (char*)lsQ + (m * 256 + wave * 64) * 16);
    }

    f32x4 sacc[4][2], yacc[4][4];
    float rsacc[4][4];
#pragma unroll
    for (int i = 0; i < 4; ++i) {
#pragma unroll
        for (int j = 0; j < 4; ++j) yacc[i][j] = (f32x4){0.f, 0.f, 0.f, 0.f};
#pragma unroll
        for (int j = 0; j < 2; ++j) sacc[i][j] = (f32x4){0.f, 0.f, 0.f, 0.f};
#pragma unroll
        for (int r = 0; r < 4; ++r) rsacc[i][r] = 0.f;
    }

    for (int c = 0; c < CHUNKS; ++c) {
        const int kv0 = nseg0 + c * KCH;
        __syncthreads();   // prev chunk's LDS reads done -> safe to restage
        // stage K chunk [64][128]
#pragma unroll
        for (int m = 0; m < 4; ++m) {
            const int s = m * 256 + tid;
            const int row = s >> 4, pcg = s & 15;
            const int lcg = pcg ^ (row & 15);
            load_lds16(kbase + (size_t)(kv0 + row) * P_DIM + lcg * 8,
                       (char*)lsK + (m * 256 + wave * 64) * 16);
        }
        // stage V chunk [128][64] from h2T
#pragma unroll
        for (int m = 0; m < 4; ++m) {
            const int s = m * 256 + tid;
            const int row = s >> 3, pcg = s & 7;
            const int lcg = pcg ^ (row & 7);
            load_lds16(h2T + (size_t)row * (2 * NBANK) + ncol0 + kv0 + lcg * 8,
                       (char*)lsV + (m * 256 + wave * 64) * 16);
        }
        __syncthreads();   // staging (and Q on c=0) complete

        // S-GEMM: S[128][64] = qt_tile @ K_chunk^T
#pragma unroll
        for (int ks = 0; ks < 4; ++ks) {
            bf16x8 af[4], bfr[2];
#pragma unroll
            for (int i = 0; i < 4; ++i) {
                const int qr = wm * 64 + i * 16 + r16;
                af[i] = *(const bf16x8*)(lsQ + qr * 128 +
                                         ((ks * 4 + quad) ^ (qr & 15)) * 8);
            }
#pragma unroll
            for (int j = 0; j < 2; ++j) {
                const int kr = wn * 32 + j * 16 + r16;
                bfr[j] = *(const bf16x8*)(lsK + kr * 128 +
                                          ((ks * 4 + quad) ^ (kr & 15)) * 8);
            }
#pragma unroll
            for (int i = 0; i < 4; ++i)
#pragma unroll
                for (int j = 0; j < 2; ++j)
                    sacc[i][j] = __builtin_amdgcn_mfma_f32_16x16x32_bf16(
                        af[i], bfr[j], sacc[i][j], 0, 0, 0);
        }

        // exp epilogue -> lsS (swizzled ds_write), accumulate row partials
#pragma unroll
        for (int j = 0; j < 2; ++j) {
            const int col = wn * 32 + j * 16 + r16;
            const float bv = beta[(size_t)side * NBANK + kv0 + col];
            const int cg = col >> 3, cl = col & 7;
#pragma unroll
            for (int i = 0; i < 4; ++i) {
#pragma unroll
                for (int r = 0; r < 4; ++r) {
                    const int row = wm * 64 + i * 16 + quad * 4 + r;
                    float v = __expf(SCALE_S * (sacc[i][j][r] + bv));
                    rsacc[i][r] += v;
                    ((bf*)lsS)[row * 64 + ((cg ^ (row & 7)) << 3) + cl] =
                        __float2bfloat16(v);
                }
            }
        }
#pragma unroll
        for (int i = 0; i < 4; ++i)
#pragma unroll
            for (int j = 0; j < 2; ++j) sacc[i][j] = (f32x4){0.f, 0.f, 0.f, 0.f};

        __syncthreads();   // lsS visible to all waves

        // PV-GEMM: Y[128][128] += S[128][64] @ V_chunk (via h2T rows)
#pragma unroll
        for (int ks = 0; ks < 2; ++ks) {
            bf16x8 pa[4], pb[4];
#pragma unroll
            for (int i = 0; i < 4; ++i) {
                const int sr = wm * 64 + i * 16 + r16;
                pa[i] = *(const bf16x8*)(lsS + sr * 64 +
                                         ((ks * 4 + quad) ^ (sr & 7)) * 8);
            }
#pragma unroll
            for (int j = 0; j < 4; ++j) {
                const int vr = wn * 64 + j * 16 + r16;
                pb[j] = *(const bf16x8*)(lsV + vr * 64 +
                                         ((ks * 4 + quad) ^ (vr & 7)) * 8);
            }
#pragma unroll
            for (int i = 0; i < 4; ++i)
#pragma unroll
                for (int j = 0; j < 4; ++j)
                    yacc[i][j] = __builtin_amdgcn_mfma_f32_16x16x32_bf16(
                        pa[i], pb[j], yacc[i][j], 0, 0, 0);
        }
    }

    // rowsum partials: r16-group reduce, cross-wave combine in LDS
    __syncthreads();
    float* frs = (float*)lsK;   // [2][128] floats (lsK dead now)
#pragma unroll
    for (int i = 0; i < 4; ++i)
#pragma unroll
        for (int r = 0; r < 4; ++r) {
            float s = rsacc[i][r];
            s += __shfl_xor(s, 1, 64);
            s += __shfl_xor(s, 2, 64);
            s += __shfl_xor(s, 4, 64);
            s += __shfl_xor(s, 8, 64);
            if (r16 == 0) frs[wn * 128 + wm * 64 + i * 16 + quad * 4 + r] = s;
        }
    __syncthreads();
    if (tid < 128)
        rsP[(size_t)part * B_ROWS + qb * 128 + tid] = frs[tid] + frs[128 + tid];
    __syncthreads();

    // Y partial store via per-wave LDS staging (reuse lsK region, 4 KB/wave)
    bf* my  = (bf*)(lds + 16384) + wave * 2048;
    bf* dst = Ypart + (size_t)part * B_ROWS * P_DIM;
#pragma unroll
    for (int half = 0; half < 2; ++half) {
#pragma unroll
        for (int i2 = 0; i2 < 2; ++i2) {
            const int i = half * 2 + i2;
#pragma unroll
            for (int j = 0; j < 4; ++j)
#pragma unroll
                for (int r = 0; r < 4; ++r)
                    my[(i2 * 16 + quad * 4 + r) * 64 + j * 16 + r16] =
                        __float2bfloat16(yacc[i][j][r]);
        }
#pragma unroll
        for (int it = 0; it < 4; ++it) {
            const int chunk = it * 64 + lane;
            const int lrow  = chunk >> 3;
            const int lcol  = (chunk & 7) * 8;
            const int grow  = qb * 128 + wm * 64 + half * 32 + lrow;
            const int gcol  = wn * 64 + lcol;
            int4 v = *(const int4*)(my + lrow * 64 + lcol);
            *(int4*)(dst + (size_t)grow * P_DIM + gcol) = v;
        }
    }
}

// ---------------------------------------------------------------------------
// prep mega-kernel: all input-only transforms in ONE dispatch (range-split).
// ---------------------------------------------------------------------------
#define PG0 10240   // convX
#define PG1 584     // convW
#define PG2 64      // convW3T
#define PG3 512     // ftpad
#define PG4 8       // vvecP partials
#define PG5 256     // bvp

__global__ __launch_bounds__(256)
void prep(const float* __restrict__ Fv, const float* __restrict__ Fvs,
          const float* __restrict__ Fvt,
          const float* __restrict__ W1, const float* __restrict__ W2,
          const float* __restrict__ Wp,
          const float* __restrict__ W3, const float* __restrict__ b3,
          const float* __restrict__ bp, const float* __restrict__ Ft,
          bf* __restrict__ Xb, bf* __restrict__ W1b, bf* __restrict__ W2b,
          bf* __restrict__ Wpb,
          bf* __restrict__ Tq, bf* __restrict__ Tk, bf* __restrict__ Tv,
          bf* __restrict__ Ftb,
          float* __restrict__ vvecP, float* __restrict__ bvp)
{
    const int tid = threadIdx.x;
    int b = blockIdx.x;
    if (b < PG0) {                       // ---- convX: Fv|Fvs|Fvt -> bf16
        int i = (b * 256 + tid) * 8;
        const int n0 = B_ROWS * D_DIM, n1 = n0 + NBANK * D_DIM;
        const float* src; int off;
        if (i < n0)      { src = Fv;  off = i; }
        else if (i < n1) { src = Fvs; off = i - n0; }
        else             { src = Fvt; off = i - n1; }
        float4 a = *(const float4*)(src + off);
        float4 c = *(const float4*)(src + off + 4);
        *(int4*)(Xb + i) = pack8(a, c);
        return;
    }
    if ((b -= PG0) < PG1) {              // ---- convW: W1|W2|Wp -> bf16
        int i = (b * 256 + tid) * 8;
        const int n1 = P_DIM * D_DIM, n2 = n1 + P_DIM * P_DIM;
        const float* src; bf* dst; int off;
        if (i < n1)      { src = W1; dst = W1b; off = i; }
        else if (i < n2) { src = W2; dst = W2b; off = i - n1; }
        else             { src = Wp; dst = Wpb; off = i - n2; }
        float4 a = *(const float4*)(src + off);
        float4 c = *(const float4*)(src + off + 4);
        *(int4*)(dst + off) = pack8(a, c);
        return;
    }
    if ((b -= PG1) < PG2) {              // ---- convW3T: Txx[p,d] = W3[3d+x,p]
        int i = (b * 256 + tid) * 8;
        int p = i >> 10, d0 = i & 1023;
        union { bf h[8]; int4 v; } uq, uk, uv;
#pragma unroll
        for (int j = 0; j < 8; ++j) {
            const float* r = W3 + (size_t)3 * (d0 + j) * P_DIM + p;
            uq.h[j] = __float2bfloat16(r[0]);
            uk.h[j] = __float2bfloat16(r[P_DIM]);
            uv.h[j] = __float2bfloat16(r[2 * P_DIM]);
        }
        *(int4*)(Tq + i) = uq.v;
        *(int4*)(Tk + i) = uk.v;
        *(int4*)(Tv + i) = uv.v;
        return;
    }
    if ((b -= PG2) < PG3) {              // ---- ftpad
        int i = (b * 256 + tid) * 8;
        int row = i >> 10, col = i & 1023;
        if (row < C_CLS) {
            float4 a = *(const float4*)(Ft + (size_t)row * D_DIM + col);
            float4 c = *(const float4*)(Ft + (size_t)row * D_DIM + col + 4);
            *(int4*)(Ftb + i) = pack8(a, c);
        } else {
            *(int4*)(Ftb + i) = (int4){0, 0, 0, 0};
        }
        return;
    }
    if ((b -= PG3) < PG4) {              // ---- vvecP partials of W3k^T b3q
        const int p = tid & 127, hf = tid >> 7;
        const int dbase = b * 128 + hf * 64;
        float s = 0.f;
        for (int dd = 0; dd < 64; ++dd) {
            const int d = dbase + dd;
            s = fmaf(b3[3 * d], W3[(size_t)(3 * d + 1) * P_DIM + p], s);
        }
        vvecP[(b * 2 + hf) * P_DIM + p] = s;
        return;
    }
    b -= PG4;                            // ---- bvp[o] = Wp[o,:].b3v + bp[o]
    const int wave = tid >> 6, lane = tid & 63;
    const int o = b * 4 + wave;
    const float* r = Wp + (size_t)o * D_DIM;
    float s = 0.f;
    for (int i = lane; i < D_DIM; i += 64) s = fmaf(r[i], b3[3 * i + 2], s);
    for (int off = 32; off > 0; off >>= 1) s += __shfl_down(s, off, 64);
    if (lane == 0) bvp[o] = s + bp[o];
}

// fused reduce for split-K weight-fold GEMMs: Wqk (8 parts) + Wpv (4 parts)
__global__ __launch_bounds__(256)
void reduceWW(const bf* __restrict__ WqkP, const bf* __restrict__ WpvP,
              bf* __restrict__ Wqk, bf* __restrict__ Wpv)
{
    const int tid = threadIdx.x;
    if (blockIdx.x < 8) {
        int i = (blockIdx.x * 256 + tid) * 8;
        float s[8] = {};
        for (int z = 0; z < 8; ++z) {
            union { int4 v; bf h[8]; } u;
            u.v = *(const int4*)(WqkP + (size_t)z * 16384 + i);
#pragma unroll
            for (int e = 0; e < 8; ++e) s[e] += __bfloat162float(u.h[e]);
        }
        union { bf h[8]; int4 v; } o;
#pragma unroll
        for (int e = 0; e < 8; ++e) o.h[e] = __float2bfloat16(s[e]);
        *(int4*)(Wqk + i) = o.v;
    } else {
        int i = ((blockIdx.x - 8) * 256 + tid) * 8;
        float s[8] = {};
        for (int z = 0; z < 4; ++z) {
            union { int4 v; bf h[8]; } u;
            u.v = *(const int4*)(WpvP + (size_t)z * 131072 + i);
#pragma unroll
            for (int e = 0; e < 8; ++e) s[e] += __bfloat162float(u.h[e]);
        }
        union { bf h[8]; int4 v; } o;
#pragma unroll
        for (int e = 0; e < 8; ++e) o.h[e] = __float2bfloat16(s[e]);
        *(int4*)(Wpv + i) = o.v;
    }
}

// posth2: r0 (64 blocks) beta[n] = h2bank[n,:].vvec | r1 (256) h2 transpose
__global__ __launch_bounds__(256)
void posth2(const bf* __restrict__ h2bank, const float* __restrict__ vvecP,
            float* __restrict__ beta, bf* __restrict__ h2T)
{
    __shared__ float vs[P_DIM];
    __shared__ bf t[64][136];
    const int tid = threadIdx.x;
    if (blockIdx.x < 64) {
        if (tid < P_DIM) {
            float s = 0.f;
#pragma unroll
            for (int z = 0; z < 16; ++z) s += vvecP[z * P_DIM + tid];
            vs[tid] = s;
        }
        __syncthreads();
        const int n = blockIdx.x * 256 + tid;
        const bf* r = h2bank + (size_t)n * P_DIM;
        float s = 0.f;
#pragma unroll
        for (int c = 0; c < P_DIM; c += 8) {
            union { int4 q; bf h[8]; } u;
            u.q = *(const int4*)(r + c);
#pragma unroll
            for (int e = 0; e < 8; ++e) s += __bfloat162float(u.h[e]) * vs[c + e];
        }
        beta[n] = s;
    } else {
        const size_t n0 = (size_t)(blockIdx.x - 64) * 64;
#pragma unroll
        for (int q = 0; q < 4; ++q) {
            int idx = (q * 256 + tid) * 8;
            int r = idx >> 7, c = idx & 127;
            *(int4*)&t[r][c] = *(const int4*)(h2bank + (n0 + r) * P_DIM + c);
        }
        __syncthreads();
        const int p  = tid >> 1;
        const int nb = (tid & 1) * 32;
#pragma unroll
        for (int q = 0; q < 4; ++q) {
            const int n = nb + q * 8;
            union { int4 v; bf h[8]; } u;
#pragma unroll
            for (int e = 0; e < 8; ++e) u.h[e] = t[n + e][p];
            *(int4*)(h2T + (size_t)p * (2 * NBANK) + n0 + n) = u.v;
        }
    }
}

// reduceY: Yhat[s][b][p] = sum_z parts[s*8+z][b][p] / (sum_g rsP[s*8+g][b])
__global__ __launch_bounds__(256)
void reduceY(const bf* __restrict__ parts, const float* __restrict__ rsP,
             bf* __restrict__ Yhat)
{
    int j = (blockIdx.x * 256 + threadIdx.x) * 8;      // < 2*B_ROWS*P_DIM
    const int s = j >> 19;                             // B_ROWS*P_DIM = 2^19
    const int qrow = (j >> 7) & (B_ROWS - 1);
    float rs = 0.f;
#pragma unroll
    for (int g = 0; g < 8; ++g)
        rs += rsP[(size_t)(s * 8 + g) * B_ROWS + qrow];
    const bf* p = parts + (size_t)s * 8 * 524288 + (size_t)(j & 524287);
    float acc[8] = {};
    for (int z = 0; z < 8; ++z) {
        union { int4 v; bf h[8]; } u;
        u.v = *(const int4*)(p + (size_t)z * 524288);
#pragma unroll
        for (int e = 0; e < 8; ++e) acc[e] += __bfloat162float(u.h[e]);
    }
    const float inv = 1.0f / rs;
    union { bf h[8]; int4 v; } o;
#pragma unroll
    for (int e = 0; e < 8; ++e) o.h[e] = __float2bfloat16(acc[e] * inv);
    *(int4*)(Yhat + j) = o.v;
}

// dual row L2-normalize + bf16 out
__global__ __launch_bounds__(256)
void rownorm2b(const float* __restrict__ G, bf* __restrict__ out)
{
    __shared__ float red[16];
    const int tid = threadIdx.x;
    const float* ps = G + (size_t)blockIdx.x * D_DIM;
    const float* pt = ps + (size_t)B_ROWS * D_DIM;
    float4 a = *(const float4*)(ps + tid * 4);
    float4 c = *(const float4*)(pt + tid * 4);
    float sa = a.x * a.x + a.y * a.y + a.z * a.z + a.w * a.w;
    float sb = c.x * c.x + c.y * c.y + c.z * c.z + c.w * c.w;
    for (int s = 32; s > 0; s >>= 1) {
        sa += __shfl_down(sa, s, 64);
        sb += __shfl_down(sb, s, 64);
    }
    if ((tid & 63) == 0) { red[tid >> 6] = sa; red[8 + (tid >> 6)] = sb; }
    __syncthreads();
    if (tid == 0) {
        float ta = 0.f, tb = 0.f;
        for (int w = 0; w < 4; ++w) { ta += red[w]; tb += red[8 + w]; }
        red[4] = rsqrtf(ta); red[12] = rsqrtf(tb);
    }
    __syncthreads();
    const float ia = red[4], ib = red[12];
    union { bf h[4]; int2 v; } o;
    o.h[0] = __float2bfloat16(a.x * ia + c.x * ib);
    o.h[1] = __float2bfloat16(a.y * ia + c.y * ib);
    o.h[2] = __float2bfloat16(a.z * ia + c.z * ib);
    o.h[3] = __float2bfloat16(a.w * ia + c.w * ib);
    *(int2*)(out + (size_t)blockIdx.x * D_DIM + tid * 4) = o.v;
}

// ---------------------------------------------------------------------------
// Rank-128 attention factorization + flash-fused attention (R4):
//   S = exp(SCALE*(h2q@Wqk@h2k^T + beta[n]))  [row-const terms cancel]
//   fused: S never hits HBM; Y = (A@h2)/rowsum via seg partials.
// ---------------------------------------------------------------------------
extern "C" void kernel_launch(void* const* d_in, const int* in_sizes, int n_in,
                              void* d_out, int out_size, void* d_ws, size_t ws_size,
                              hipStream_t stream)
{
    (void)in_sizes; (void)n_in; (void)out_size; (void)ws_size;

    const float* Ft  = (const float*)d_in[0];
    const float* Fv  = (const float*)d_in[1];
    const float* Fvs = (const float*)d_in[2];
    const float* Fvt = (const float*)d_in[3];
    const float* W1  = (const float*)d_in[4];
    const float* b1  = (const float*)d_in[5];
    const float* g1  = (const float*)d_in[6];
    const float* be1 = (const float*)d_in[7];
    const float* m1  = (const float*)d_in[8];
    const float* v1  = (const float*)d_in[9];
    const float* W2  = (const float*)d_in[10];
    const float* b2  = (const float*)d_in[11];
    const float* g2  = (const float*)d_in[12];
    const float* be2 = (const float*)d_in[13];
    const float* m2  = (const float*)d_in[14];
    const float* v2  = (const float*)d_in[15];
    const float* W3  = (const float*)d_in[16];
    const float* b3  = (const float*)d_in[17];
    const float* Wp  = (const float*)d_in[18];
    const float* bp  = (const float*)d_in[19];
    const float* ls  = (const float*)d_in[20];

    char* base = (char*)d_ws;
    size_t o = 0;
    auto take = [&](size_t s) { size_t r = o; o += (s + 255) & ~(size_t)255; return r; };

    // persistent (~21 MB)
    bf* qtb   = (bf*)(base + take((size_t)B_ROWS * P_DIM * 2));
    bf* h2T   = (bf*)(base + take((size_t)P_DIM * 2 * NBANK * 2));
    bf* Yhat  = (bf*)(base + take((size_t)2 * B_ROWS * P_DIM * 2));
    bf* Wpb   = (bf*)(base + take((size_t)D_DIM * D_DIM * 2));
    bf* Ftb   = (bf*)(base + take((size_t)D_DIM * D_DIM * 2));
    bf* W3qT  = (bf*)(base + take((size_t)P_DIM * D_DIM * 2));
    bf* W3kT  = (bf*)(base + take((size_t)P_DIM * D_DIM * 2));
    bf* W3vT  = (bf*)(base + take((size_t)P_DIM * D_DIM * 2));
    bf* Wqk   = (bf*)(base + take((size_t)P_DIM * P_DIM * 2));
    bf* Wpvb  = (bf*)(base + take((size_t)D_DIM * P_DIM * 2));
    bf* W1b   = (bf*)(base + take((size_t)P_DIM * D_DIM * 2));
    bf* W2b   = (bf*)(base + take((size_t)P_DIM * P_DIM * 2));
    bf* h2b   = (bf*)(base + take((size_t)MTOT * P_DIM * 2));
    bf* WqkP  = (bf*)(base + take((size_t)8 * P_DIM * P_DIM * 2));
    bf* WpvP  = (bf*)(base + take((size_t)4 * D_DIM * P_DIM * 2));
    float* vvecP = (float*)(base + take((size_t)16 * P_DIM * 4));
    float* beta  = (float*)(base + take((size_t)2 * NBANK * 4));
    float* bvp   = (float*)(base + take(D_DIM * 4));
    float* rsP   = (float*)(base + take((size_t)16 * B_ROWS * 4));   // 256 KB

    // scratch region (aliased across phases)
    const size_t Dbase = o;
    bf* Xb    = (bf*)(base + Dbase);                                  // 40 MB
    bf* h1b   = (bf*)(base + Dbase + (size_t)MTOT * D_DIM * 2);       // 5 MB
    bf* Opart = (bf*)(base + Dbase + (size_t)48 * 1024 * 1024);       // 16 MB
    float* G     = (float*)(base + Dbase);                            // 32 MB
    bf*    Fsumb = (bf*)(base + Dbase + (size_t)2 * B_ROWS * D_DIM * 4);

    auto gemm = [&](const bf* A, const bf* B, int M, int N, int K, int lda, int ldb,
                    int kch, int fx, int fy, int epi, float* Cf, bf* Cb,
                    const float* bias, const float* biasm,
                    const float* bg, const float* bb, const float* bm, const float* bv,
                    const float* addsrc, const float* lsp, int ldc) {
        gemm_bf16<<<dim3(N / 128, M / 128, kch), dim3(256), 0, stream>>>(
            A, B, M, N, K, lda, ldb, kch, fx, fy, epi, Cf, Cb, bias, biasm,
            bg, bb, bm, bv, addsrc, lsp, ldc);
    };

    // 1) prep: all input-only transforms
    prep<<<dim3(PG0 + PG1 + PG2 + PG3 + PG4 + PG5), dim3(256), 0, stream>>>(
        Fv, Fvs, Fvt, W1, W2, Wp, W3, b3, bp, Ft,
        Xb, W1b, W2b, Wpb, W3qT, W3kT, W3vT, Ftb, vvecP, bvp);

    // 2-3) split-K weight folds: Wqk, Wpv = Wp@W3v
    gemm(W3kT, W3qT, P_DIM, P_DIM, D_DIM, D_DIM, D_DIM, 8, 1, 1, 6, nullptr, WqkP,
         nullptr, nullptr, nullptr, nullptr, nullptr, nullptr, nullptr, nullptr, 0);
    gemm(Wpb, W3vT, D_DIM, P_DIM, D_DIM, D_DIM, D_DIM, 4, 1, 8, 6, nullptr, WpvP,
         nullptr, nullptr, nullptr, nullptr, nullptr, nullptr, nullptr, nullptr, 0);
    // 4) fused reduces
    reduceWW<<<dim3(72), dim3(256), 0, stream>>>(WqkP, WpvP, Wqk, Wpvb);

    // 5-6) batched pre_project -> h2 [20480,128]
    gemm(Xb, W1b, MTOT, P_DIM, D_DIM, D_DIM, D_DIM, 1, 1, 8, 1, nullptr, h1b,
         b1, nullptr, g1, be1, m1, v1, nullptr, nullptr, 0);
    gemm(h1b, W2b, MTOT, P_DIM, P_DIM, P_DIM, P_DIM, 1, 1, 8, 1, nullptr, h2b,
         b2, nullptr, g2, be2, m2, v2, nullptr, nullptr, 0);
    // 7) Qtilde = h2q @ Wqk
    gemm(h2b, Wqk, B_ROWS, P_DIM, P_DIM, P_DIM, P_DIM, 1, 1, 8, 5, nullptr, qtb,
         nullptr, nullptr, nullptr, nullptr, nullptr, nullptr, nullptr, nullptr, 0);
    // 8) beta + h2 transpose
    posth2<<<dim3(320), dim3(256), 0, stream>>>(
        h2b + (size_t)B_ROWS * P_DIM, vvecP, beta, h2T);

    // 9) fused attention: S in LDS only; Y/rowsum seg partials
    attn_fused<<<dim3(2 * KVSEG * (B_ROWS / 128)), dim3(256), 0, stream>>>(
        qtb, h2b + (size_t)B_ROWS * P_DIM, h2T, beta, Opart, rsP);
    // 10) fold segments + softmax normalize -> Yhat [2*B_ROWS,128]
    reduceY<<<dim3(2 * B_ROWS * P_DIM / 2048), dim3(256), 0, stream>>>(
        Opart, rsP, Yhat);

    // 11) combined post-project (K=128) + residual
    gemm(Yhat, Wpvb, 2 * B_ROWS, D_DIM, P_DIM, P_DIM, P_DIM, 1, 1, 8, 3, G, nullptr,
         bvp, nullptr, nullptr, nullptr, nullptr, nullptr, Fv, nullptr, B_ROWS);
    // 12) dual rownorm -> bf16
    rownorm2b<<<dim3(B_ROWS), dim3(256), 0, stream>>>(G, Fsumb);
    // 13) logits
    gemm(Fsumb, Ftb, B_ROWS, D_DIM, D_DIM, D_DIM, D_DIM, 1, 1, 8, 4, (float*)d_out,
         nullptr, nullptr, nullptr, nullptr, nullptr, nullptr, nullptr, nullptr,
         ls, C_CLS);
}

// Round 5
// 373.702 us; speedup vs baseline: 2.2751x; 1.0620x over previous
//
#include <hip/hip_runtime.h>
#include <hip/hip_bf16.h>
#include <math.h>

#define D_DIM   1024
#define P_DIM   128
#define B_ROWS  4096
#define NBANK   8192
#define C_CLS   1000
#define EPS_BN  1e-5f
#define SCALE_S 0.1f
#define MTOT    20480   // 4096 + 8192 + 8192 batched pre_project rows
#define KVSEG   16      // kv segments per side (softmax split)
#define KCH     64      // kv rows per fused chunk
#define CHUNKS  (NBANK / KVSEG / KCH)   // 8

typedef __bf16 bf16x8 __attribute__((ext_vector_type(8)));
typedef float  f32x4  __attribute__((ext_vector_type(4)));
typedef __hip_bfloat16 bf;

__device__ __forceinline__ void load_lds16(const void* gp, void* lp) {
    __builtin_amdgcn_global_load_lds(
        (__attribute__((address_space(1))) void*)gp,
        (__attribute__((address_space(3))) void*)lp, 16, 0, 0);
}

__device__ __forceinline__ int4 pack8(float4 a, float4 b) {
    union { bf h[8]; int4 v; } u;
    u.h[0] = __float2bfloat16(a.x); u.h[1] = __float2bfloat16(a.y);
    u.h[2] = __float2bfloat16(a.z); u.h[3] = __float2bfloat16(a.w);
    u.h[4] = __float2bfloat16(b.x); u.h[5] = __float2bfloat16(b.y);
    u.h[6] = __float2bfloat16(b.z); u.h[7] = __float2bfloat16(b.w);
    return u.v;
}

// ---------------------------------------------------------------------------
// bf16 MFMA GEMM: C[M,N] = A[M,K] @ B[N,K]^T (row-major bf16), 128x128 tile.
// A row stride = lda; B row stride = ldb. kchunks>1 -> split-K via blockIdx.z.
// epi: 1 +bias,BN,ReLU -> bf16 | 3 fp32 +bias + addsrc[(gm&(ldc-1))*N+gn] |
//      4 fp32 *exp(*lsp), cols<ldc | 5 bf16 (+bias[n], +biasm[m]) |
//      6 bf16 partial at Cb + z*M*N
// bf16 epis (1,5,6) store via per-wave LDS staging -> dwordx4 coalesced.
// ---------------------------------------------------------------------------
__global__ __launch_bounds__(256)
void gemm_bf16(const bf* __restrict__ A, const bf* __restrict__ B,
               int M, int N, int K, int lda, int ldb,
               int kchunks, int fx, int fy, int epi,
               float* __restrict__ Cf, bf* __restrict__ Cb,
               const float* __restrict__ bias, const float* __restrict__ biasm,
               const float* __restrict__ bng, const float* __restrict__ bnb,
               const float* __restrict__ bnm, const float* __restrict__ bnv,
               const float* __restrict__ addsrc, const float* __restrict__ lsp,
               int ldc)
{
    __shared__ __align__(16) short ldsS[8192];   // 16 KB
    short* lsA = ldsS;          // [128][32]
    short* lsB = ldsS + 4096;   // [128][32]

    const int tid  = threadIdx.x;
    const int wave = tid >> 6;
    const int lane = tid & 63;
    const int wm   = wave >> 1;
    const int wn   = wave & 1;
    const int r16  = lane & 15;
    const int quad = lane >> 4;

    // XCD-aware tile remap
    const int gx = gridDim.x, gy = gridDim.y;
    const int l   = blockIdx.y * gx + blockIdx.x;
    const int xcd = l & 7;
    const int i0  = l >> 3;
    const int sx  = gx / fx, sy = gy / fy;
    const int bx  = (xcd % fx) * sx + (i0 % sx);
    const int by  = (xcd / fx) * sy + (i0 / sx);
    const int bm0 = by * 128;
    const int bn0 = bx * 128;

    const int kper = K / kchunks;
    const int kbeg = blockIdx.z * kper;
    const int kend = kbeg + kper;

    f32x4 acc[4][4];
#pragma unroll
    for (int i = 0; i < 4; ++i)
#pragma unroll
        for (int j = 0; j < 4; ++j) acc[i][j] = (f32x4){0.f, 0.f, 0.f, 0.f};

    for (int k0 = kbeg; k0 < kend; k0 += 32) {
#pragma unroll
        for (int i = 0; i < 2; ++i) {
            const int s   = i * 256 + tid;
            const int row = s >> 2;
            const int cc  = (s & 3) * 8;
            const int lofs = (i * 256 + wave * 64) * 16;
            load_lds16(A + (size_t)(bm0 + row) * lda + k0 + cc, (char*)lsA + lofs);
            load_lds16(B + (size_t)(bn0 + row) * ldb + k0 + cc, (char*)lsB + lofs);
        }
        __syncthreads();

        bf16x8 af[4], bfr[4];
#pragma unroll
        for (int i = 0; i < 4; ++i)
            af[i] = *(const bf16x8*)(lsA + (wm * 64 + i * 16 + r16) * 32 + quad * 8);
#pragma unroll
        for (int j = 0; j < 4; ++j)
            bfr[j] = *(const bf16x8*)(lsB + (wn * 64 + j * 16 + r16) * 32 + quad * 8);
#pragma unroll
        for (int i = 0; i < 4; ++i)
#pragma unroll
            for (int j = 0; j < 4; ++j)
                acc[i][j] = __builtin_amdgcn_mfma_f32_16x16x32_bf16(
                    af[i], bfr[j], acc[i][j], 0, 0, 0);
        __syncthreads();
    }

    if (epi == 3 || epi == 4) {
        const float lsv = (epi == 4) ? expf(*lsp) : 1.0f;
#pragma unroll
        for (int i = 0; i < 4; ++i) {
            const int gmb = bm0 + wm * 64 + i * 16 + quad * 4;
#pragma unroll
            for (int j = 0; j < 4; ++j) {
                const int gn = bn0 + wn * 64 + j * 16 + r16;
#pragma unroll
                for (int r = 0; r < 4; ++r) {
                    const int gm = gmb + r;
                    float val = acc[i][j][r];
                    if (epi == 3) {
                        Cf[(size_t)gm * N + gn] =
                            val + bias[gn] + addsrc[(size_t)(gm & (ldc - 1)) * N + gn];
                    } else {
                        if (gn < ldc) Cf[(size_t)gm * ldc + gn] = val * lsv;
                    }
                }
            }
        }
        return;
    }

    // bf16 LDS-staged store path (epi 1, 5, 6)
    bf* dst = Cb + (epi == 6 ? (size_t)blockIdx.z * M * N : 0);
    bf* my  = (bf*)(ldsS + wave * 2048);   // 4 KB per wave: [32][64] bf16

#pragma unroll
    for (int half = 0; half < 2; ++half) {
#pragma unroll
        for (int i2 = 0; i2 < 2; ++i2) {
            const int i = half * 2 + i2;
            const int gmb = bm0 + wm * 64 + i * 16 + quad * 4;
#pragma unroll
            for (int j = 0; j < 4; ++j) {
                const int gn = bn0 + wn * 64 + j * 16 + r16;
#pragma unroll
                for (int r = 0; r < 4; ++r) {
                    float val = acc[i][j][r];
                    if (epi == 1) {
                        val += bias[gn];
                        val = (val - bnm[gn]) * rsqrtf(bnv[gn] + EPS_BN) * bng[gn] + bnb[gn];
                        val = fmaxf(val, 0.f);
                    } else {
                        if (bias)  val += bias[gn];
                        if (biasm) val += biasm[gmb + r];
                    }
                    my[(i2 * 16 + quad * 4 + r) * 64 + j * 16 + r16] =
                        __float2bfloat16(val);
                }
            }
        }
#pragma unroll
        for (int it = 0; it < 4; ++it) {
            const int chunk = it * 64 + lane;
            const int lrow  = chunk >> 3;
            const int lcol  = (chunk & 7) * 8;
            const int grow  = bm0 + wm * 64 + half * 32 + lrow;
            const int gcol  = bn0 + wn * 64 + lcol;
            int4 v = *(const int4*)(my + lrow * 64 + lcol);
            *(int4*)(dst + (size_t)grow * N + gcol) = v;
        }
    }
}

// ---------------------------------------------------------------------------
// Fused attention v2 (8-wave, Q-in-regs, 48 KB LDS -> ~2-3 blocks/CU):
// per block (side, qb, seg) over 512 kv rows (8 chunks of 64):
//   S = exp(SCALE*(qt@h2k^T + beta)) -> LDS only -> Y += S@V
// Each wave owns 16 q-rows: S rows are wave-private, so NO barrier between
// exp-write and PV-read. 2 barriers/chunk total.
// LDS tiles XOR-swizzled; staged tiles swizzle via pre-swizzled GLOBAL source.
// ---------------------------------------------------------------------------
__global__ __launch_bounds__(512)
void attn_fused(const bf* __restrict__ qt,      // [4096][128]
                const bf* __restrict__ h2bank,  // [16384][128] side-major
                const bf* __restrict__ h2T,     // [128][16384]
                const float* __restrict__ beta, // [16384]
                bf* __restrict__ Ypart,         // [32][4096][128]
                float* __restrict__ rsP)        // [32][4096]
{
    __shared__ __align__(16) short lds[24576];   // 48 KB
    short* lsK = lds;            // [64][128],  phys cg = cg ^ (row&15)
    short* lsV = lds + 8192;     // [128][64],  phys cg = cg ^ (row&7)
    short* lsS = lds + 16384;    // [128][64],  phys cg = cg ^ (row&7)

    const int tid  = threadIdx.x;
    const int wave = tid >> 6;
    const int lane = tid & 63;
    const int r16  = lane & 15;
    const int quad = lane >> 4;

    const int qb   = blockIdx.x >> 5;
    const int side = (blockIdx.x >> 4) & 1;
    const int seg  = blockIdx.x & 15;
    const int part = side * KVSEG + seg;
    const int nseg0 = seg * (NBANK / KVSEG);
    const bf* kbase = h2bank + (size_t)side * NBANK * P_DIM;
    const int ncol0 = side * NBANK;

    // Q fragments in registers (wave-private 16 q-rows, loop-invariant)
    const bf* qrow = qt + (size_t)(qb * 128 + wave * 16 + r16) * P_DIM;
    bf16x8 qreg[4];
#pragma unroll
    for (int ks = 0; ks < 4; ++ks)
        qreg[ks] = *(const bf16x8*)(qrow + (ks * 4 + quad) * 8);

    f32x4 yacc[8];
    float rsacc[4] = {0.f, 0.f, 0.f, 0.f};
#pragma unroll
    for (int j = 0; j < 8; ++j) yacc[j] = (f32x4){0.f, 0.f, 0.f, 0.f};

    for (int c = 0; c < CHUNKS; ++c) {
        const int kv0 = nseg0 + c * KCH;
        __syncthreads();   // prev chunk's lsK/lsV reads done -> safe to restage
        // stage K chunk [64][128]
#pragma unroll
        for (int m = 0; m < 2; ++m) {
            const int s = m * 512 + tid;
            const int row = s >> 4, pcg = s & 15;
            const int lcg = pcg ^ (row & 15);
            load_lds16(kbase + (size_t)(kv0 + row) * P_DIM + lcg * 8,
                       (char*)lsK + (m * 512 + wave * 64) * 16);
        }
        // stage V chunk [128][64] from h2T
#pragma unroll
        for (int m = 0; m < 2; ++m) {
            const int s = m * 512 + tid;
            const int row = s >> 3, pcg = s & 7;
            const int lcg = pcg ^ (row & 7);
            load_lds16(h2T + (size_t)row * (2 * NBANK) + ncol0 + kv0 + lcg * 8,
                       (char*)lsV + (m * 512 + wave * 64) * 16);
        }
        __syncthreads();   // staging complete

        // S-tile [16][64] = Q_wave @ K_chunk^T
        f32x4 sacc[4];
#pragma unroll
        for (int j = 0; j < 4; ++j) sacc[j] = (f32x4){0.f, 0.f, 0.f, 0.f};
#pragma unroll
        for (int ks = 0; ks < 4; ++ks) {
            bf16x8 bfr[4];
#pragma unroll
            for (int j = 0; j < 4; ++j) {
                const int kr = j * 16 + r16;
                bfr[j] = *(const bf16x8*)(lsK + kr * 128 +
                                          ((ks * 4 + quad) ^ (kr & 15)) * 8);
            }
#pragma unroll
            for (int j = 0; j < 4; ++j)
                sacc[j] = __builtin_amdgcn_mfma_f32_16x16x32_bf16(
                    qreg[ks], bfr[j], sacc[j], 0, 0, 0);
        }

        // exp -> lsS (wave-private rows; no barrier needed before PV)
#pragma unroll
        for (int j = 0; j < 4; ++j) {
            const int col = j * 16 + r16;
            const float bv = beta[(size_t)side * NBANK + kv0 + col];
            const int cg = col >> 3, cl = col & 7;
#pragma unroll
            for (int r = 0; r < 4; ++r) {
                const int row = wave * 16 + quad * 4 + r;
                float v = __expf(SCALE_S * (sacc[j][r] + bv));
                rsacc[r] += v;
                ((bf*)lsS)[row * 64 + ((cg ^ (row & 7)) << 3) + cl] =
                    __float2bfloat16(v);
            }
        }

        // PV: Y[16][128] += S[16][64] @ V (d-major rows of h2T)
#pragma unroll
        for (int ks = 0; ks < 2; ++ks) {
            const int sr = wave * 16 + r16;
            bf16x8 pa = *(const bf16x8*)(lsS + sr * 64 +
                                         ((ks * 4 + quad) ^ (sr & 7)) * 8);
            bf16x8 pb[8];
#pragma unroll
            for (int j = 0; j < 8; ++j) {
                const int vr = j * 16 + r16;
                pb[j] = *(const bf16x8*)(lsV + vr * 64 +
                                         ((ks * 4 + quad) ^ (vr & 7)) * 8);
            }
#pragma unroll
            for (int j = 0; j < 8; ++j)
                yacc[j] = __builtin_amdgcn_mfma_f32_16x16x32_bf16(
                    pa, pb[j], yacc[j], 0, 0, 0);
        }
    }

    // rowsum partials: reduce across the 16-lane r16 group; rows wave-private
#pragma unroll
    for (int r = 0; r < 4; ++r) {
        float s = rsacc[r];
        s += __shfl_xor(s, 1, 64);
        s += __shfl_xor(s, 2, 64);
        s += __shfl_xor(s, 4, 64);
        s += __shfl_xor(s, 8, 64);
        rsacc[r] = s;
    }
    if (r16 == 0)
        *(float4*)(rsP + (size_t)part * B_ROWS + qb * 128 + wave * 16 + quad * 4) =
            (float4){rsacc[0], rsacc[1], rsacc[2], rsacc[3]};

    // Y partial store via per-wave LDS staging (whole LDS dead after barrier)
    __syncthreads();
    bf* my = (bf*)lds + wave * 2048;   // [16][128] bf16 = 4 KB per wave
#pragma unroll
    for (int j = 0; j < 8; ++j)
#pragma unroll
        for (int r = 0; r < 4; ++r)
            my[(quad * 4 + r) * 128 + j * 16 + r16] =
                __float2bfloat16(yacc[j][r]);
    bf* dst = Ypart + (size_t)part * B_ROWS * P_DIM
                    + (size_t)(qb * 128 + wave * 16) * P_DIM;
#pragma unroll
    for (int it = 0; it < 4; ++it) {
        const int chunk = it * 64 + lane;       // 0..255 int4s
        const int lrow  = chunk >> 4;
        const int lcol  = (chunk & 15) * 8;
        *(int4*)(dst + (size_t)lrow * P_DIM + lcol) =
            *(const int4*)(my + lrow * 128 + lcol);
    }
}

// ---------------------------------------------------------------------------
// prep mega-kernel: all input-only transforms in ONE dispatch (range-split).
// ---------------------------------------------------------------------------
#define PG0 10240   // convX
#define PG1 584     // convW
#define PG2 64      // convW3T
#define PG3 512     // ftpad
#define PG4 8       // vvecP partials
#define PG5 256     // bvp

__global__ __launch_bounds__(256)
void prep(const float* __restrict__ Fv, const float* __restrict__ Fvs,
          const float* __restrict__ Fvt,
          const float* __restrict__ W1, const float* __restrict__ W2,
          const float* __restrict__ Wp,
          const float* __restrict__ W3, const float* __restrict__ b3,
          const float* __restrict__ bp, const float* __restrict__ Ft,
          bf* __restrict__ Xb, bf* __restrict__ W1b, bf* __restrict__ W2b,
          bf* __restrict__ Wpb,
          bf* __restrict__ Tq, bf* __restrict__ Tk, bf* __restrict__ Tv,
          bf* __restrict__ Ftb,
          float* __restrict__ vvecP, float* __restrict__ bvp)
{
    const int tid = threadIdx.x;
    int b = blockIdx.x;
    if (b < PG0) {                       // ---- convX: Fv|Fvs|Fvt -> bf16
        int i = (b * 256 + tid) * 8;
        const int n0 = B_ROWS * D_DIM, n1 = n0 + NBANK * D_DIM;
        const float* src; int off;
        if (i < n0)      { src = Fv;  off = i; }
        else if (i < n1) { src = Fvs; off = i - n0; }
        else             { src = Fvt; off = i - n1; }
        float4 a = *(const float4*)(src + off);
        float4 c = *(const float4*)(src + off + 4);
        *(int4*)(Xb + i) = pack8(a, c);
        return;
    }
    if ((b -= PG0) < PG1) {              // ---- convW: W1|W2|Wp -> bf16
        int i = (b * 256 + tid) * 8;
        const int n1 = P_DIM * D_DIM, n2 = n1 + P_DIM * P_DIM;
        const float* src; bf* dst; int off;
        if (i < n1)      { src = W1; dst = W1b; off = i; }
        else if (i < n2) { src = W2; dst = W2b; off = i - n1; }
        else             { src = Wp; dst = Wpb; off = i - n2; }
        float4 a = *(const float4*)(src + off);
        float4 c = *(const float4*)(src + off + 4);
        *(int4*)(dst + off) = pack8(a, c);
        return;
    }
    if ((b -= PG1) < PG2) {              // ---- convW3T: Txx[p,d] = W3[3d+x,p]
        int i = (b * 256 + tid) * 8;
        int p = i >> 10, d0 = i & 1023;
        union { bf h[8]; int4 v; } uq, uk, uv;
#pragma unroll
        for (int j = 0; j < 8; ++j) {
            const float* r = W3 + (size_t)3 * (d0 + j) * P_DIM + p;
            uq.h[j] = __float2bfloat16(r[0]);
            uk.h[j] = __float2bfloat16(r[P_DIM]);
            uv.h[j] = __float2bfloat16(r[2 * P_DIM]);
        }
        *(int4*)(Tq + i) = uq.v;
        *(int4*)(Tk + i) = uk.v;
        *(int4*)(Tv + i) = uv.v;
        return;
    }
    if ((b -= PG2) < PG3) {              // ---- ftpad
        int i = (b * 256 + tid) * 8;
        int row = i >> 10, col = i & 1023;
        if (row < C_CLS) {
            float4 a = *(const float4*)(Ft + (size_t)row * D_DIM + col);
            float4 c = *(const float4*)(Ft + (size_t)row * D_DIM + col + 4);
            *(int4*)(Ftb + i) = pack8(a, c);
        } else {
            *(int4*)(Ftb + i) = (int4){0, 0, 0, 0};
        }
        return;
    }
    if ((b -= PG3) < PG4) {              // ---- vvecP partials of W3k^T b3q
        const int p = tid & 127, hf = tid >> 7;
        const int dbase = b * 128 + hf * 64;
        float s = 0.f;
        for (int dd = 0; dd < 64; ++dd) {
            const int d = dbase + dd;
            s = fmaf(b3[3 * d], W3[(size_t)(3 * d + 1) * P_DIM + p], s);
        }
        vvecP[(b * 2 + hf) * P_DIM + p] = s;
        return;
    }
    b -= PG4;                            // ---- bvp[o] = Wp[o,:].b3v + bp[o]
    const int wave = tid >> 6, lane = tid & 63;
    const int o = b * 4 + wave;
    const float* r = Wp + (size_t)o * D_DIM;
    float s = 0.f;
    for (int i = lane; i < D_DIM; i += 64) s = fmaf(r[i], b3[3 * i + 2], s);
    for (int off = 32; off > 0; off >>= 1) s += __shfl_down(s, off, 64);
    if (lane == 0) bvp[o] = s + bp[o];
}

// fused reduce for split-K weight-fold GEMMs: Wqk (8 parts) + Wpv (4 parts)
__global__ __launch_bounds__(256)
void reduceWW(const bf* __restrict__ WqkP, const bf* __restrict__ WpvP,
              bf* __restrict__ Wqk, bf* __restrict__ Wpv)
{
    const int tid = threadIdx.x;
    if (blockIdx.x < 8) {
        int i = (blockIdx.x * 256 + tid) * 8;
        float s[8] = {};
        for (int z = 0; z < 8; ++z) {
            union { int4 v; bf h[8]; } u;
            u.v = *(const int4*)(WqkP + (size_t)z * 16384 + i);
#pragma unroll
            for (int e = 0; e < 8; ++e) s[e] += __bfloat162float(u.h[e]);
        }
        union { bf h[8]; int4 v; } o;
#pragma unroll
        for (int e = 0; e < 8; ++e) o.h[e] = __float2bfloat16(s[e]);
        *(int4*)(Wqk + i) = o.v;
    } else {
        int i = ((blockIdx.x - 8) * 256 + tid) * 8;
        float s[8] = {};
        for (int z = 0; z < 4; ++z) {
            union { int4 v; bf h[8]; } u;
            u.v = *(const int4*)(WpvP + (size_t)z * 131072 + i);
#pragma unroll
            for (int e = 0; e < 8; ++e) s[e] += __bfloat162float(u.h[e]);
        }
        union { bf h[8]; int4 v; } o;
#pragma unroll
        for (int e = 0; e < 8; ++e) o.h[e] = __float2bfloat16(s[e]);
        *(int4*)(Wpv + i) = o.v;
    }
}

// posth2: r0 (64 blocks) beta[n] = h2bank[n,:].vvec | r1 (256) h2 transpose
__global__ __launch_bounds__(256)
void posth2(const bf* __restrict__ h2bank, const float* __restrict__ vvecP,
            float* __restrict__ beta, bf* __restrict__ h2T)
{
    __shared__ float vs[P_DIM];
    __shared__ bf t[64][136];
    const int tid = threadIdx.x;
    if (blockIdx.x < 64) {
        if (tid < P_DIM) {
            float s = 0.f;
#pragma unroll
            for (int z = 0; z < 16; ++z) s += vvecP[z * P_DIM + tid];
            vs[tid] = s;
        }
        __syncthreads();
        const int n = blockIdx.x * 256 + tid;
        const bf* r = h2bank + (size_t)n * P_DIM;
        float s = 0.f;
#pragma unroll
        for (int c = 0; c < P_DIM; c += 8) {
            union { int4 q; bf h[8]; } u;
            u.q = *(const int4*)(r + c);
#pragma unroll
            for (int e = 0; e < 8; ++e) s += __bfloat162float(u.h[e]) * vs[c + e];
        }
        beta[n] = s;
    } else {
        const size_t n0 = (size_t)(blockIdx.x - 64) * 64;
#pragma unroll
        for (int q = 0; q < 4; ++q) {
            int idx = (q * 256 + tid) * 8;
            int r = idx >> 7, c = idx & 127;
            *(int4*)&t[r][c] = *(const int4*)(h2bank + (n0 + r) * P_DIM + c);
        }
        __syncthreads();
        const int p  = tid >> 1;
        const int nb = (tid & 1) * 32;
#pragma unroll
        for (int q = 0; q < 4; ++q) {
            const int n = nb + q * 8;
            union { int4 v; bf h[8]; } u;
#pragma unroll
            for (int e = 0; e < 8; ++e) u.h[e] = t[n + e][p];
            *(int4*)(h2T + (size_t)p * (2 * NBANK) + n0 + n) = u.v;
        }
    }
}

// reduceY: Yhat[s][b][p] = sum_z parts[s*16+z][b][p] / (sum_g rsP[s*16+g][b])
__global__ __launch_bounds__(256)
void reduceY(const bf* __restrict__ parts, const float* __restrict__ rsP,
             bf* __restrict__ Yhat)
{
    int j = (blockIdx.x * 256 + threadIdx.x) * 8;      // < 2*B_ROWS*P_DIM
    const int s = j >> 19;                             // B_ROWS*P_DIM = 2^19
    const int qrow = (j >> 7) & (B_ROWS - 1);
    float rs = 0.f;
#pragma unroll
    for (int g = 0; g < KVSEG; ++g)
        rs += rsP[(size_t)(s * KVSEG + g) * B_ROWS + qrow];
    const bf* p = parts + (size_t)s * KVSEG * 524288 + (size_t)(j & 524287);
    float acc[8] = {};
    for (int z = 0; z < KVSEG; ++z) {
        union { int4 v; bf h[8]; } u;
        u.v = *(const int4*)(p + (size_t)z * 524288);
#pragma unroll
        for (int e = 0; e < 8; ++e) acc[e] += __bfloat162float(u.h[e]);
    }
    const float inv = 1.0f / rs;
    union { bf h[8]; int4 v; } o;
#pragma unroll
    for (int e = 0; e < 8; ++e) o.h[e] = __float2bfloat16(acc[e] * inv);
    *(int4*)(Yhat + j) = o.v;
}

// dual row L2-normalize + bf16 out
__global__ __launch_bounds__(256)
void rownorm2b(const float* __restrict__ G, bf* __restrict__ out)
{
    __shared__ float red[16];
    const int tid = threadIdx.x;
    const float* ps = G + (size_t)blockIdx.x * D_DIM;
    const float* pt = ps + (size_t)B_ROWS * D_DIM;
    float4 a = *(const float4*)(ps + tid * 4);
    float4 c = *(const float4*)(pt + tid * 4);
    float sa = a.x * a.x + a.y * a.y + a.z * a.z + a.w * a.w;
    float sb = c.x * c.x + c.y * c.y + c.z * c.z + c.w * c.w;
    for (int s = 32; s > 0; s >>= 1) {
        sa += __shfl_down(sa, s, 64);
        sb += __shfl_down(sb, s, 64);
    }
    if ((tid & 63) == 0) { red[tid >> 6] = sa; red[8 + (tid >> 6)] = sb; }
    __syncthreads();
    if (tid == 0) {
        float ta = 0.f, tb = 0.f;
        for (int w = 0; w < 4; ++w) { ta += red[w]; tb += red[8 + w]; }
        red[4] = rsqrtf(ta); red[12] = rsqrtf(tb);
    }
    __syncthreads();
    const float ia = red[4], ib = red[12];
    union { bf h[4]; int2 v; } o;
    o.h[0] = __float2bfloat16(a.x * ia + c.x * ib);
    o.h[1] = __float2bfloat16(a.y * ia + c.y * ib);
    o.h[2] = __float2bfloat16(a.z * ia + c.z * ib);
    o.h[3] = __float2bfloat16(a.w * ia + c.w * ib);
    *(int2*)(out + (size_t)blockIdx.x * D_DIM + tid * 4) = o.v;
}

// ---------------------------------------------------------------------------
// Rank-128 attention factorization + flash-fused attention (R5):
//   S = exp(SCALE*(h2q@Wqk@h2k^T + beta[n]))  [row-const terms cancel]
//   fused: S never hits HBM; Y = (A@h2)/rowsum via seg partials.
// R5: attn_fused restructured for occupancy (8 waves, Q in regs, 48 KB LDS).
// ---------------------------------------------------------------------------
extern "C" void kernel_launch(void* const* d_in, const int* in_sizes, int n_in,
                              void* d_out, int out_size, void* d_ws, size_t ws_size,
                              hipStream_t stream)
{
    (void)in_sizes; (void)n_in; (void)out_size; (void)ws_size;

    const float* Ft  = (const float*)d_in[0];
    const float* Fv  = (const float*)d_in[1];
    const float* Fvs = (const float*)d_in[2];
    const float* Fvt = (const float*)d_in[3];
    const float* W1  = (const float*)d_in[4];
    const float* b1  = (const float*)d_in[5];
    const float* g1  = (const float*)d_in[6];
    const float* be1 = (const float*)d_in[7];
    const float* m1  = (const float*)d_in[8];
    const float* v1  = (const float*)d_in[9];
    const float* W2  = (const float*)d_in[10];
    const float* b2  = (const float*)d_in[11];
    const float* g2  = (const float*)d_in[12];
    const float* be2 = (const float*)d_in[13];
    const float* m2  = (const float*)d_in[14];
    const float* v2  = (const float*)d_in[15];
    const float* W3  = (const float*)d_in[16];
    const float* b3  = (const float*)d_in[17];
    const float* Wp  = (const float*)d_in[18];
    const float* bp  = (const float*)d_in[19];
    const float* ls  = (const float*)d_in[20];

    char* base = (char*)d_ws;
    size_t o = 0;
    auto take = [&](size_t s) { size_t r = o; o += (s + 255) & ~(size_t)255; return r; };

    // persistent (~22 MB)
    bf* qtb   = (bf*)(base + take((size_t)B_ROWS * P_DIM * 2));
    bf* h2T   = (bf*)(base + take((size_t)P_DIM * 2 * NBANK * 2));
    bf* Yhat  = (bf*)(base + take((size_t)2 * B_ROWS * P_DIM * 2));
    bf* Wpb   = (bf*)(base + take((size_t)D_DIM * D_DIM * 2));
    bf* Ftb   = (bf*)(base + take((size_t)D_DIM * D_DIM * 2));
    bf* W3qT  = (bf*)(base + take((size_t)P_DIM * D_DIM * 2));
    bf* W3kT  = (bf*)(base + take((size_t)P_DIM * D_DIM * 2));
    bf* W3vT  = (bf*)(base + take((size_t)P_DIM * D_DIM * 2));
    bf* Wqk   = (bf*)(base + take((size_t)P_DIM * P_DIM * 2));
    bf* Wpvb  = (bf*)(base + take((size_t)D_DIM * P_DIM * 2));
    bf* W1b   = (bf*)(base + take((size_t)P_DIM * D_DIM * 2));
    bf* W2b   = (bf*)(base + take((size_t)P_DIM * P_DIM * 2));
    bf* h2b   = (bf*)(base + take((size_t)MTOT * P_DIM * 2));
    bf* WqkP  = (bf*)(base + take((size_t)8 * P_DIM * P_DIM * 2));
    bf* WpvP  = (bf*)(base + take((size_t)4 * D_DIM * P_DIM * 2));
    float* vvecP = (float*)(base + take((size_t)16 * P_DIM * 4));
    float* beta  = (float*)(base + take((size_t)2 * NBANK * 4));
    float* bvp   = (float*)(base + take(D_DIM * 4));
    float* rsP   = (float*)(base + take((size_t)2 * KVSEG * B_ROWS * 4)); // 512 KB

    // scratch region (aliased across phases)
    const size_t Dbase = o;
    bf* Xb    = (bf*)(base + Dbase);                                  // 40 MB
    bf* h1b   = (bf*)(base + Dbase + (size_t)MTOT * D_DIM * 2);       // 5 MB
    bf* Opart = (bf*)(base + Dbase + (size_t)48 * 1024 * 1024);       // 32 MB
    float* G     = (float*)(base + Dbase);                            // 32 MB
    bf*    Fsumb = (bf*)(base + Dbase + (size_t)2 * B_ROWS * D_DIM * 4);

    auto gemm = [&](const bf* A, const bf* B, int M, int N, int K, int lda, int ldb,
                    int kch, int fx, int fy, int epi, float* Cf, bf* Cb,
                    const float* bias, const float* biasm,
                    const float* bg, const float* bb, const float* bm, const float* bv,
                    const float* addsrc, const float* lsp, int ldc) {
        gemm_bf16<<<dim3(N / 128, M / 128, kch), dim3(256), 0, stream>>>(
            A, B, M, N, K, lda, ldb, kch, fx, fy, epi, Cf, Cb, bias, biasm,
            bg, bb, bm, bv, addsrc, lsp, ldc);
    };

    // 1) prep: all input-only transforms
    prep<<<dim3(PG0 + PG1 + PG2 + PG3 + PG4 + PG5), dim3(256), 0, stream>>>(
        Fv, Fvs, Fvt, W1, W2, Wp, W3, b3, bp, Ft,
        Xb, W1b, W2b, Wpb, W3qT, W3kT, W3vT, Ftb, vvecP, bvp);

    // 2-3) split-K weight folds: Wqk, Wpv = Wp@W3v
    gemm(W3kT, W3qT, P_DIM, P_DIM, D_DIM, D_DIM, D_DIM, 8, 1, 1, 6, nullptr, WqkP,
         nullptr, nullptr, nullptr, nullptr, nullptr, nullptr, nullptr, nullptr, 0);
    gemm(Wpb, W3vT, D_DIM, P_DIM, D_DIM, D_DIM, D_DIM, 4, 1, 8, 6, nullptr, WpvP,
         nullptr, nullptr, nullptr, nullptr, nullptr, nullptr, nullptr, nullptr, 0);
    // 4) fused reduces
    reduceWW<<<dim3(72), dim3(256), 0, stream>>>(WqkP, WpvP, Wqk, Wpvb);

    // 5-6) batched pre_project -> h2 [20480,128]
    gemm(Xb, W1b, MTOT, P_DIM, D_DIM, D_DIM, D_DIM, 1, 1, 8, 1, nullptr, h1b,
         b1, nullptr, g1, be1, m1, v1, nullptr, nullptr, 0);
    gemm(h1b, W2b, MTOT, P_DIM, P_DIM, P_DIM, P_DIM, 1, 1, 8, 1, nullptr, h2b,
         b2, nullptr, g2, be2, m2, v2, nullptr, nullptr, 0);
    // 7) Qtilde = h2q @ Wqk
    gemm(h2b, Wqk, B_ROWS, P_DIM, P_DIM, P_DIM, P_DIM, 1, 1, 8, 5, nullptr, qtb,
         nullptr, nullptr, nullptr, nullptr, nullptr, nullptr, nullptr, nullptr, 0);
    // 8) beta + h2 transpose
    posth2<<<dim3(320), dim3(256), 0, stream>>>(
        h2b + (size_t)B_ROWS * P_DIM, vvecP, beta, h2T);

    // 9) fused attention: S in LDS only; Y/rowsum seg partials
    attn_fused<<<dim3(2 * KVSEG * (B_ROWS / 128)), dim3(512), 0, stream>>>(
        qtb, h2b + (size_t)B_ROWS * P_DIM, h2T, beta, Opart, rsP);
    // 10) fold segments + softmax normalize -> Yhat [2*B_ROWS,128]
    reduceY<<<dim3(2 * B_ROWS * P_DIM / 2048), dim3(256), 0, stream>>>(
        Opart, rsP, Yhat);

    // 11) combined post-project (K=128) + residual
    gemm(Yhat, Wpvb, 2 * B_ROWS, D_DIM, P_DIM, P_DIM, P_DIM, 1, 1, 8, 3, G, nullptr,
         bvp, nullptr, nullptr, nullptr, nullptr, nullptr, Fv, nullptr, B_ROWS);
    // 12) dual rownorm -> bf16
    rownorm2b<<<dim3(B_ROWS), dim3(256), 0, stream>>>(G, Fsumb);
    // 13) logits
    gemm(Fsumb, Ftb, B_ROWS, D_DIM, D_DIM, D_DIM, D_DIM, 1, 1, 8, 4, (float*)d_out,
         nullptr, nullptr, nullptr, nullptr, nullptr, nullptr, nullptr, nullptr,
         ls, C_CLS);
}

// Round 6
// 348.482 us; speedup vs baseline: 2.4398x; 1.0724x over previous
//
#include <hip/hip_runtime.h>
#include <hip/hip_bf16.h>
#include <math.h>

#define D_DIM   1024
#define P_DIM   128
#define B_ROWS  4096
#define NBANK   8192
#define C_CLS   1000
#define EPS_BN  1e-5f
#define SCALE_S 0.1f
#define MTOT    20480   // 4096 + 8192 + 8192 batched pre_project rows
#define KVSEG   16      // kv segments per side (softmax split)
#define KCH     64      // kv rows per fused chunk
#define CHUNKS  (NBANK / KVSEG / KCH)   // 8

typedef __bf16 bf16x8 __attribute__((ext_vector_type(8)));
typedef float  f32x4  __attribute__((ext_vector_type(4)));
typedef __hip_bfloat16 bf;

__device__ __forceinline__ void load_lds16(const void* gp, void* lp) {
    __builtin_amdgcn_global_load_lds(
        (__attribute__((address_space(1))) void*)gp,
        (__attribute__((address_space(3))) void*)lp, 16, 0, 0);
}

__device__ __forceinline__ int4 pack8(float4 a, float4 b) {
    union { bf h[8]; int4 v; } u;
    u.h[0] = __float2bfloat16(a.x); u.h[1] = __float2bfloat16(a.y);
    u.h[2] = __float2bfloat16(a.z); u.h[3] = __float2bfloat16(a.w);
    u.h[4] = __float2bfloat16(b.x); u.h[5] = __float2bfloat16(b.y);
    u.h[6] = __float2bfloat16(b.z); u.h[7] = __float2bfloat16(b.w);
    return u.v;
}

// ---------------------------------------------------------------------------
// bf16 MFMA GEMM: C[M,N] = A[M,K] @ B[N,K]^T (row-major bf16), 128x128 tile.
// A row stride = lda; B row stride = ldb. kchunks>1 -> split-K via blockIdx.z.
// epi: 1 +bias,BN,ReLU -> bf16 | 3 fp32 +bias + addsrc[(gm&(ldc-1))*N+gn] |
//      4 fp32 *exp(*lsp), cols<ldc | 5 bf16 (+bias[n], +biasm[m]) |
//      6 bf16 partial at Cb + z*M*N | 8 fp32 plain partial at Cf + z*M*N
// bf16 epis (1,5,6) store via per-wave LDS staging -> dwordx4 coalesced.
// ---------------------------------------------------------------------------
__global__ __launch_bounds__(256)
void gemm_bf16(const bf* __restrict__ A, const bf* __restrict__ B,
               int M, int N, int K, int lda, int ldb,
               int kchunks, int fx, int fy, int epi,
               float* __restrict__ Cf, bf* __restrict__ Cb,
               const float* __restrict__ bias, const float* __restrict__ biasm,
               const float* __restrict__ bng, const float* __restrict__ bnb,
               const float* __restrict__ bnm, const float* __restrict__ bnv,
               const float* __restrict__ addsrc, const float* __restrict__ lsp,
               int ldc)
{
    __shared__ __align__(16) short ldsS[8192];   // 16 KB
    short* lsA = ldsS;          // [128][32]
    short* lsB = ldsS + 4096;   // [128][32]

    const int tid  = threadIdx.x;
    const int wave = tid >> 6;
    const int lane = tid & 63;
    const int wm   = wave >> 1;
    const int wn   = wave & 1;
    const int r16  = lane & 15;
    const int quad = lane >> 4;

    // XCD-aware tile remap
    const int gx = gridDim.x, gy = gridDim.y;
    const int l   = blockIdx.y * gx + blockIdx.x;
    const int xcd = l & 7;
    const int i0  = l >> 3;
    const int sx  = gx / fx, sy = gy / fy;
    const int bx  = (xcd % fx) * sx + (i0 % sx);
    const int by  = (xcd / fx) * sy + (i0 / sx);
    const int bm0 = by * 128;
    const int bn0 = bx * 128;

    const int kper = K / kchunks;
    const int kbeg = blockIdx.z * kper;
    const int kend = kbeg + kper;

    f32x4 acc[4][4];
#pragma unroll
    for (int i = 0; i < 4; ++i)
#pragma unroll
        for (int j = 0; j < 4; ++j) acc[i][j] = (f32x4){0.f, 0.f, 0.f, 0.f};

    for (int k0 = kbeg; k0 < kend; k0 += 32) {
#pragma unroll
        for (int i = 0; i < 2; ++i) {
            const int s   = i * 256 + tid;
            const int row = s >> 2;
            const int cc  = (s & 3) * 8;
            const int lofs = (i * 256 + wave * 64) * 16;
            load_lds16(A + (size_t)(bm0 + row) * lda + k0 + cc, (char*)lsA + lofs);
            load_lds16(B + (size_t)(bn0 + row) * ldb + k0 + cc, (char*)lsB + lofs);
        }
        __syncthreads();

        bf16x8 af[4], bfr[4];
#pragma unroll
        for (int i = 0; i < 4; ++i)
            af[i] = *(const bf16x8*)(lsA + (wm * 64 + i * 16 + r16) * 32 + quad * 8);
#pragma unroll
        for (int j = 0; j < 4; ++j)
            bfr[j] = *(const bf16x8*)(lsB + (wn * 64 + j * 16 + r16) * 32 + quad * 8);
#pragma unroll
        for (int i = 0; i < 4; ++i)
#pragma unroll
            for (int j = 0; j < 4; ++j)
                acc[i][j] = __builtin_amdgcn_mfma_f32_16x16x32_bf16(
                    af[i], bfr[j], acc[i][j], 0, 0, 0);
        __syncthreads();
    }

    if (epi == 8) {
        float* dst = Cf + (size_t)blockIdx.z * M * N;
#pragma unroll
        for (int i = 0; i < 4; ++i) {
            const int gmb = bm0 + wm * 64 + i * 16 + quad * 4;
#pragma unroll
            for (int j = 0; j < 4; ++j) {
                const int gn = bn0 + wn * 64 + j * 16 + r16;
#pragma unroll
                for (int r = 0; r < 4; ++r)
                    dst[(size_t)(gmb + r) * N + gn] = acc[i][j][r];
            }
        }
        return;
    }

    if (epi == 3 || epi == 4) {
        const float lsv = (epi == 4) ? expf(*lsp) : 1.0f;
#pragma unroll
        for (int i = 0; i < 4; ++i) {
            const int gmb = bm0 + wm * 64 + i * 16 + quad * 4;
#pragma unroll
            for (int j = 0; j < 4; ++j) {
                const int gn = bn0 + wn * 64 + j * 16 + r16;
#pragma unroll
                for (int r = 0; r < 4; ++r) {
                    const int gm = gmb + r;
                    float val = acc[i][j][r];
                    if (epi == 3) {
                        Cf[(size_t)gm * N + gn] =
                            val + bias[gn] + addsrc[(size_t)(gm & (ldc - 1)) * N + gn];
                    } else {
                        if (gn < ldc) Cf[(size_t)gm * ldc + gn] = val * lsv;
                    }
                }
            }
        }
        return;
    }

    // bf16 LDS-staged store path (epi 1, 5, 6)
    bf* dst = Cb + (epi == 6 ? (size_t)blockIdx.z * M * N : 0);
    bf* my  = (bf*)(ldsS + wave * 2048);   // 4 KB per wave: [32][64] bf16

#pragma unroll
    for (int half = 0; half < 2; ++half) {
#pragma unroll
        for (int i2 = 0; i2 < 2; ++i2) {
            const int i = half * 2 + i2;
            const int gmb = bm0 + wm * 64 + i * 16 + quad * 4;
#pragma unroll
            for (int j = 0; j < 4; ++j) {
                const int gn = bn0 + wn * 64 + j * 16 + r16;
#pragma unroll
                for (int r = 0; r < 4; ++r) {
                    float val = acc[i][j][r];
                    if (epi == 1) {
                        val += bias[gn];
                        val = (val - bnm[gn]) * rsqrtf(bnv[gn] + EPS_BN) * bng[gn] + bnb[gn];
                        val = fmaxf(val, 0.f);
                    } else {
                        if (bias)  val += bias[gn];
                        if (biasm) val += biasm[gmb + r];
                    }
                    my[(i2 * 16 + quad * 4 + r) * 64 + j * 16 + r16] =
                        __float2bfloat16(val);
                }
            }
        }
#pragma unroll
        for (int it = 0; it < 4; ++it) {
            const int chunk = it * 64 + lane;
            const int lrow  = chunk >> 3;
            const int lcol  = (chunk & 7) * 8;
            const int grow  = bm0 + wm * 64 + half * 32 + lrow;
            const int gcol  = bn0 + wn * 64 + lcol;
            int4 v = *(const int4*)(my + lrow * 64 + lcol);
            *(int4*)(dst + (size_t)grow * N + gcol) = v;
        }
    }
}

// ---------------------------------------------------------------------------
// h2fuse: per 128-row tile of the 20480-row batch:
//   h1 = relu(A1*(Hp0+Hp1)+C1)          (split-K partial sum + folded BN1)
//   h2 = relu(A2*(h1@W2^T)+C2) -> h2b   (MFMA, W2 staged in LDS)
//   if rows<4096: qt = h2@Wqk^T -> qtb  (MFMA, Wqk staged into dead W2 slot)
// Replaces GEMM2 + Qtilde dispatches and the h1b HBM round-trip.
// LDS swizzle: phys cg = cg ^ (row&15) (same scheme as attn_fused tiles).
// ---------------------------------------------------------------------------
__global__ __launch_bounds__(256)
void h2fuse(const float* __restrict__ Hp,     // [2][MTOT][128] fp32 partials
            const bf* __restrict__ W2b,       // [128][128]
            const bf* __restrict__ Wqk,       // [128][128]
            const float* __restrict__ bnA,    // A1|C1|A2|C2 (4x128)
            bf* __restrict__ h2b, bf* __restrict__ qtb)
{
    __shared__ __align__(16) short lsH[16384];   // [128][128] swizzled
    __shared__ __align__(16) short lsW[16384];   // [128][128] swizzled
    __shared__ float sA1[128], sC1[128], sA2[128], sC2[128];

    const int tid  = threadIdx.x;
    const int wave = tid >> 6;
    const int lane = tid & 63;
    const int r16  = lane & 15;
    const int quad = lane >> 4;
    const int wm   = wave >> 1;
    const int wn   = wave & 1;
    const int r0   = blockIdx.x * 128;
    const bool isq = (r0 < B_ROWS);

    // stage W2 (pre-swizzled global source -> linear LDS dest)
#pragma unroll
    for (int m = 0; m < 8; ++m) {
        const int s = m * 256 + tid;
        const int row = s >> 4, pcg = s & 15;
        load_lds16(W2b + row * 128 + (pcg ^ (row & 15)) * 8,
                   (char*)lsW + (m * 256 + wave * 64) * 16);
    }
    if (tid < 128) {
        sA1[tid] = bnA[tid];       sC1[tid] = bnA[128 + tid];
        sA2[tid] = bnA[256 + tid]; sC2[tid] = bnA[384 + tid];
    }
    __syncthreads();

    // h1 tile -> lsH (swizzled bf16)
#pragma unroll
    for (int m = 0; m < 16; ++m) {
        const int s = m * 256 + tid;
        const int row = s >> 5;
        const int col = (s & 31) * 4;
        const float* p0 = Hp + (size_t)(r0 + row) * 128 + col;
        float4 x0 = *(const float4*)p0;
        float4 x1 = *(const float4*)(p0 + (size_t)MTOT * 128);
        union { bf h[4]; int2 v; } u;
        u.h[0] = __float2bfloat16(fmaxf(fmaf(x0.x + x1.x, sA1[col],     sC1[col]),     0.f));
        u.h[1] = __float2bfloat16(fmaxf(fmaf(x0.y + x1.y, sA1[col + 1], sC1[col + 1]), 0.f));
        u.h[2] = __float2bfloat16(fmaxf(fmaf(x0.z + x1.z, sA1[col + 2], sC1[col + 2]), 0.f));
        u.h[3] = __float2bfloat16(fmaxf(fmaf(x0.w + x1.w, sA1[col + 3], sC1[col + 3]), 0.f));
        const int cg = col >> 3;
        *(int2*)((bf*)lsH + row * 128 + ((cg ^ (row & 15)) << 3) + (col & 7)) = u.v;
    }
    __syncthreads();   // lsH + lsW ready (barrier drains global_load_lds)

    // pass 1: acc = h1 @ W2^T
    f32x4 acc[4][4];
#pragma unroll
    for (int i = 0; i < 4; ++i)
#pragma unroll
        for (int j = 0; j < 4; ++j) acc[i][j] = (f32x4){0.f, 0.f, 0.f, 0.f};
#pragma unroll
    for (int ks = 0; ks < 4; ++ks) {
        bf16x8 af[4], bfr[4];
#pragma unroll
        for (int i = 0; i < 4; ++i) {
            const int row = wm * 64 + i * 16 + r16;
            af[i] = *(const bf16x8*)(lsH + row * 128 + ((ks * 4 + quad) ^ (row & 15)) * 8);
        }
#pragma unroll
        for (int j = 0; j < 4; ++j) {
            const int row = wn * 64 + j * 16 + r16;
            bfr[j] = *(const bf16x8*)(lsW + row * 128 + ((ks * 4 + quad) ^ (row & 15)) * 8);
        }
#pragma unroll
        for (int i = 0; i < 4; ++i)
#pragma unroll
            for (int j = 0; j < 4; ++j)
                acc[i][j] = __builtin_amdgcn_mfma_f32_16x16x32_bf16(
                    af[i], bfr[j], acc[i][j], 0, 0, 0);
    }
    __syncthreads();   // pass-1 LDS reads complete

    if (isq) {
        // stage Wqk into lsW (dead after pass 1)
#pragma unroll
        for (int m = 0; m < 8; ++m) {
            const int s = m * 256 + tid;
            const int row = s >> 4, pcg = s & 15;
            load_lds16(Wqk + row * 128 + (pcg ^ (row & 15)) * 8,
                       (char*)lsW + (m * 256 + wave * 64) * 16);
        }
    }

    // epilogue: h2 = relu(A2*acc+C2) -> lsH (swizzled, overwrites h1)
#pragma unroll
    for (int i = 0; i < 4; ++i) {
#pragma unroll
        for (int j = 0; j < 4; ++j) {
            const int gn = wn * 64 + j * 16 + r16;
            const int cg = gn >> 3, cl = gn & 7;
            const float a2 = sA2[gn], c2 = sC2[gn];
#pragma unroll
            for (int r = 0; r < 4; ++r) {
                const int row = wm * 64 + i * 16 + quad * 4 + r;
                float v = fmaxf(fmaf(acc[i][j][r], a2, c2), 0.f);
                ((bf*)lsH)[row * 128 + ((cg ^ (row & 15)) << 3) + cl] =
                    __float2bfloat16(v);
            }
        }
    }
    __syncthreads();   // lsH(h2) visible; Wqk staging drained

    // h2 global store (unswizzling coalesced read)
#pragma unroll
    for (int m = 0; m < 8; ++m) {
        const int s = m * 256 + tid;
        const int row = s >> 4, cg = s & 15;
        *(int4*)(h2b + (size_t)(r0 + row) * 128 + cg * 8) =
            *(const int4*)(lsH + row * 128 + ((cg ^ (row & 15)) << 3));
    }

    if (!isq) return;

    // pass 2: qt = h2 @ Wqk^T
    f32x4 acc2[4][4];
#pragma unroll
    for (int i = 0; i < 4; ++i)
#pragma unroll
        for (int j = 0; j < 4; ++j) acc2[i][j] = (f32x4){0.f, 0.f, 0.f, 0.f};
#pragma unroll
    for (int ks = 0; ks < 4; ++ks) {
        bf16x8 af[4], bfr[4];
#pragma unroll
        for (int i = 0; i < 4; ++i) {
            const int row = wm * 64 + i * 16 + r16;
            af[i] = *(const bf16x8*)(lsH + row * 128 + ((ks * 4 + quad) ^ (row & 15)) * 8);
        }
#pragma unroll
        for (int j = 0; j < 4; ++j) {
            const int row = wn * 64 + j * 16 + r16;
            bfr[j] = *(const bf16x8*)(lsW + row * 128 + ((ks * 4 + quad) ^ (row & 15)) * 8);
        }
#pragma unroll
        for (int i = 0; i < 4; ++i)
#pragma unroll
            for (int j = 0; j < 4; ++j)
                acc2[i][j] = __builtin_amdgcn_mfma_f32_16x16x32_bf16(
                    af[i], bfr[j], acc2[i][j], 0, 0, 0);
    }
    __syncthreads();   // lsW (Wqk) reads complete before my-region overwrite

    // qt store via per-wave LDS staging (lsW dead)
    bf* my  = (bf*)lsW + wave * 2048;   // [32][64] per wave
    bf* dst = qtb + (size_t)r0 * 128;
#pragma unroll
    for (int half = 0; half < 2; ++half) {
#pragma unroll
        for (int i2 = 0; i2 < 2; ++i2) {
            const int i = half * 2 + i2;
#pragma unroll
            for (int j = 0; j < 4; ++j)
#pragma unroll
                for (int r = 0; r < 4; ++r)
                    my[(i2 * 16 + quad * 4 + r) * 64 + j * 16 + r16] =
                        __float2bfloat16(acc2[i][j][r]);
        }
#pragma unroll
        for (int it = 0; it < 4; ++it) {
            const int chunk = it * 64 + lane;
            const int lrow  = chunk >> 3;
            const int lcol  = (chunk & 7) * 8;
            const int grow  = wm * 64 + half * 32 + lrow;
            const int gcol  = wn * 64 + lcol;
            int4 v = *(const int4*)(my + lrow * 64 + lcol);
            *(int4*)(dst + (size_t)grow * 128 + gcol) = v;
        }
    }
}

// ---------------------------------------------------------------------------
// Fused attention v2 (8-wave, Q-in-regs, 48 KB LDS): unchanged from R5.
// ---------------------------------------------------------------------------
__global__ __launch_bounds__(512)
void attn_fused(const bf* __restrict__ qt,      // [4096][128]
                const bf* __restrict__ h2bank,  // [16384][128] side-major
                const bf* __restrict__ h2T,     // [128][16384]
                const float* __restrict__ beta, // [16384]
                bf* __restrict__ Ypart,         // [32][4096][128]
                float* __restrict__ rsP)        // [32][4096]
{
    __shared__ __align__(16) short lds[24576];   // 48 KB
    short* lsK = lds;            // [64][128],  phys cg = cg ^ (row&15)
    short* lsV = lds + 8192;     // [128][64],  phys cg = cg ^ (row&7)
    short* lsS = lds + 16384;    // [128][64],  phys cg = cg ^ (row&7)

    const int tid  = threadIdx.x;
    const int wave = tid >> 6;
    const int lane = tid & 63;
    const int r16  = lane & 15;
    const int quad = lane >> 4;

    const int qb   = blockIdx.x >> 5;
    const int side = (blockIdx.x >> 4) & 1;
    const int seg  = blockIdx.x & 15;
    const int part = side * KVSEG + seg;
    const int nseg0 = seg * (NBANK / KVSEG);
    const bf* kbase = h2bank + (size_t)side * NBANK * P_DIM;
    const int ncol0 = side * NBANK;

    const bf* qrow = qt + (size_t)(qb * 128 + wave * 16 + r16) * P_DIM;
    bf16x8 qreg[4];
#pragma unroll
    for (int ks = 0; ks < 4; ++ks)
        qreg[ks] = *(const bf16x8*)(qrow + (ks * 4 + quad) * 8);

    f32x4 yacc[8];
    float rsacc[4] = {0.f, 0.f, 0.f, 0.f};
#pragma unroll
    for (int j = 0; j < 8; ++j) yacc[j] = (f32x4){0.f, 0.f, 0.f, 0.f};

    for (int c = 0; c < CHUNKS; ++c) {
        const int kv0 = nseg0 + c * KCH;
        __syncthreads();
#pragma unroll
        for (int m = 0; m < 2; ++m) {
            const int s = m * 512 + tid;
            const int row = s >> 4, pcg = s & 15;
            const int lcg = pcg ^ (row & 15);
            load_lds16(kbase + (size_t)(kv0 + row) * P_DIM + lcg * 8,
                       (char*)lsK + (m * 512 + wave * 64) * 16);
        }
#pragma unroll
        for (int m = 0; m < 2; ++m) {
            const int s = m * 512 + tid;
            const int row = s >> 3, pcg = s & 7;
            const int lcg = pcg ^ (row & 7);
            load_lds16(h2T + (size_t)row * (2 * NBANK) + ncol0 + kv0 + lcg * 8,
                       (char*)lsV + (m * 512 + wave * 64) * 16);
        }
        __syncthreads();

        f32x4 sacc[4];
#pragma unroll
        for (int j = 0; j < 4; ++j) sacc[j] = (f32x4){0.f, 0.f, 0.f, 0.f};
#pragma unroll
        for (int ks = 0; ks < 4; ++ks) {
            bf16x8 bfr[4];
#pragma unroll
            for (int j = 0; j < 4; ++j) {
                const int kr = j * 16 + r16;
                bfr[j] = *(const bf16x8*)(lsK + kr * 128 +
                                          ((ks * 4 + quad) ^ (kr & 15)) * 8);
            }
#pragma unroll
            for (int j = 0; j < 4; ++j)
                sacc[j] = __builtin_amdgcn_mfma_f32_16x16x32_bf16(
                    qreg[ks], bfr[j], sacc[j], 0, 0, 0);
        }

#pragma unroll
        for (int j = 0; j < 4; ++j) {
            const int col = j * 16 + r16;
            const float bv = beta[(size_t)side * NBANK + kv0 + col];
            const int cg = col >> 3, cl = col & 7;
#pragma unroll
            for (int r = 0; r < 4; ++r) {
                const int row = wave * 16 + quad * 4 + r;
                float v = __expf(SCALE_S * (sacc[j][r] + bv));
                rsacc[r] += v;
                ((bf*)lsS)[row * 64 + ((cg ^ (row & 7)) << 3) + cl] =
                    __float2bfloat16(v);
            }
        }

#pragma unroll
        for (int ks = 0; ks < 2; ++ks) {
            const int sr = wave * 16 + r16;
            bf16x8 pa = *(const bf16x8*)(lsS + sr * 64 +
                                         ((ks * 4 + quad) ^ (sr & 7)) * 8);
            bf16x8 pb[8];
#pragma unroll
            for (int j = 0; j < 8; ++j) {
                const int vr = j * 16 + r16;
                pb[j] = *(const bf16x8*)(lsV + vr * 64 +
                                         ((ks * 4 + quad) ^ (vr & 7)) * 8);
            }
#pragma unroll
            for (int j = 0; j < 8; ++j)
                yacc[j] = __builtin_amdgcn_mfma_f32_16x16x32_bf16(
                    pa, pb[j], yacc[j], 0, 0, 0);
        }
    }

#pragma unroll
    for (int r = 0; r < 4; ++r) {
        float s = rsacc[r];
        s += __shfl_xor(s, 1, 64);
        s += __shfl_xor(s, 2, 64);
        s += __shfl_xor(s, 4, 64);
        s += __shfl_xor(s, 8, 64);
        rsacc[r] = s;
    }
    if (r16 == 0)
        *(float4*)(rsP + (size_t)part * B_ROWS + qb * 128 + wave * 16 + quad * 4) =
            (float4){rsacc[0], rsacc[1], rsacc[2], rsacc[3]};

    __syncthreads();
    bf* my = (bf*)lds + wave * 2048;   // [16][128] bf16 = 4 KB per wave
#pragma unroll
    for (int j = 0; j < 8; ++j)
#pragma unroll
        for (int r = 0; r < 4; ++r)
            my[(quad * 4 + r) * 128 + j * 16 + r16] =
                __float2bfloat16(yacc[j][r]);
    bf* dst = Ypart + (size_t)part * B_ROWS * P_DIM
                    + (size_t)(qb * 128 + wave * 16) * P_DIM;
#pragma unroll
    for (int it = 0; it < 4; ++it) {
        const int chunk = it * 64 + lane;       // 0..255 int4s
        const int lrow  = chunk >> 4;
        const int lcol  = (chunk & 15) * 8;
        *(int4*)(dst + (size_t)lrow * P_DIM + lcol) =
            *(const int4*)(my + lrow * 128 + lcol);
    }
}

// ---------------------------------------------------------------------------
// prep mega-kernel: all input-only transforms in ONE dispatch (range-split).
// ---------------------------------------------------------------------------
#define PG0 10240   // convX
#define PG1 584     // convW
#define PG2 64      // convW3T
#define PG3 512     // ftpad
#define PG4 8       // vvecP partials
#define PG5 256     // bvp
#define PG6 1       // folded BN coefficients A1|C1|A2|C2

__global__ __launch_bounds__(256)
void prep(const float* __restrict__ Fv, const float* __restrict__ Fvs,
          const float* __restrict__ Fvt,
          const float* __restrict__ W1, const float* __restrict__ W2,
          const float* __restrict__ Wp,
          const float* __restrict__ W3, const float* __restrict__ b3,
          const float* __restrict__ bp, const float* __restrict__ Ft,
          const float* __restrict__ b1, const float* __restrict__ g1,
          const float* __restrict__ be1, const float* __restrict__ m1,
          const float* __restrict__ v1,
          const float* __restrict__ b2, const float* __restrict__ g2,
          const float* __restrict__ be2, const float* __restrict__ m2,
          const float* __restrict__ v2,
          bf* __restrict__ Xb, bf* __restrict__ W1b, bf* __restrict__ W2b,
          bf* __restrict__ Wpb,
          bf* __restrict__ Tq, bf* __restrict__ Tk, bf* __restrict__ Tv,
          bf* __restrict__ Ftb,
          float* __restrict__ vvecP, float* __restrict__ bvp,
          float* __restrict__ bnA)
{
    const int tid = threadIdx.x;
    int b = blockIdx.x;
    if (b < PG0) {                       // ---- convX: Fv|Fvs|Fvt -> bf16
        int i = (b * 256 + tid) * 8;
        const int n0 = B_ROWS * D_DIM, n1 = n0 + NBANK * D_DIM;
        const float* src; int off;
        if (i < n0)      { src = Fv;  off = i; }
        else if (i < n1) { src = Fvs; off = i - n0; }
        else             { src = Fvt; off = i - n1; }
        float4 a = *(const float4*)(src + off);
        float4 c = *(const float4*)(src + off + 4);
        *(int4*)(Xb + i) = pack8(a, c);
        return;
    }
    if ((b -= PG0) < PG1) {              // ---- convW: W1|W2|Wp -> bf16
        int i = (b * 256 + tid) * 8;
        const int n1 = P_DIM * D_DIM, n2 = n1 + P_DIM * P_DIM;
        const float* src; bf* dst; int off;
        if (i < n1)      { src = W1; dst = W1b; off = i; }
        else if (i < n2) { src = W2; dst = W2b; off = i - n1; }
        else             { src = Wp; dst = Wpb; off = i - n2; }
        float4 a = *(const float4*)(src + off);
        float4 c = *(const float4*)(src + off + 4);
        *(int4*)(dst + off) = pack8(a, c);
        return;
    }
    if ((b -= PG1) < PG2) {              // ---- convW3T: Txx[p,d] = W3[3d+x,p]
        int i = (b * 256 + tid) * 8;
        int p = i >> 10, d0 = i & 1023;
        union { bf h[8]; int4 v; } uq, uk, uv;
#pragma unroll
        for (int j = 0; j < 8; ++j) {
            const float* r = W3 + (size_t)3 * (d0 + j) * P_DIM + p;
            uq.h[j] = __float2bfloat16(r[0]);
            uk.h[j] = __float2bfloat16(r[P_DIM]);
            uv.h[j] = __float2bfloat16(r[2 * P_DIM]);
        }
        *(int4*)(Tq + i) = uq.v;
        *(int4*)(Tk + i) = uk.v;
        *(int4*)(Tv + i) = uv.v;
        return;
    }
    if ((b -= PG2) < PG3) {              // ---- ftpad
        int i = (b * 256 + tid) * 8;
        int row = i >> 10, col = i & 1023;
        if (row < C_CLS) {
            float4 a = *(const float4*)(Ft + (size_t)row * D_DIM + col);
            float4 c = *(const float4*)(Ft + (size_t)row * D_DIM + col + 4);
            *(int4*)(Ftb + i) = pack8(a, c);
        } else {
            *(int4*)(Ftb + i) = (int4){0, 0, 0, 0};
        }
        return;
    }
    if ((b -= PG3) < PG4) {              // ---- vvecP partials of W3k^T b3q
        const int p = tid & 127, hf = tid >> 7;
        const int dbase = b * 128 + hf * 64;
        float s = 0.f;
        for (int dd = 0; dd < 64; ++dd) {
            const int d = dbase + dd;
            s = fmaf(b3[3 * d], W3[(size_t)(3 * d + 1) * P_DIM + p], s);
        }
        vvecP[(b * 2 + hf) * P_DIM + p] = s;
        return;
    }
    if ((b -= PG4) < PG5) {              // ---- bvp[o] = Wp[o,:].b3v + bp[o]
        const int wave = tid >> 6, lane = tid & 63;
        const int o = b * 4 + wave;
        const float* r = Wp + (size_t)o * D_DIM;
        float s = 0.f;
        for (int i = lane; i < D_DIM; i += 64) s = fmaf(r[i], b3[3 * i + 2], s);
        for (int off = 32; off > 0; off >>= 1) s += __shfl_down(s, off, 64);
        if (lane == 0) bvp[o] = s + bp[o];
        return;
    }
    // ---- folded BN coefficients
    if (tid < 128) {
        float a1 = g1[tid] * rsqrtf(v1[tid] + EPS_BN);
        bnA[tid]       = a1;
        bnA[128 + tid] = (b1[tid] - m1[tid]) * a1 + be1[tid];
        float a2 = g2[tid] * rsqrtf(v2[tid] + EPS_BN);
        bnA[256 + tid] = a2;
        bnA[384 + tid] = (b2[tid] - m2[tid]) * a2 + be2[tid];
    }
}

// fused reduce for split-K weight-fold GEMMs: Wqk (8 parts) + Wpv (4 parts)
__global__ __launch_bounds__(256)
void reduceWW(const bf* __restrict__ WqkP, const bf* __restrict__ WpvP,
              bf* __restrict__ Wqk, bf* __restrict__ Wpv)
{
    const int tid = threadIdx.x;
    if (blockIdx.x < 8) {
        int i = (blockIdx.x * 256 + tid) * 8;
        float s[8] = {};
        for (int z = 0; z < 8; ++z) {
            union { int4 v; bf h[8]; } u;
            u.v = *(const int4*)(WqkP + (size_t)z * 16384 + i);
#pragma unroll
            for (int e = 0; e < 8; ++e) s[e] += __bfloat162float(u.h[e]);
        }
        union { bf h[8]; int4 v; } o;
#pragma unroll
        for (int e = 0; e < 8; ++e) o.h[e] = __float2bfloat16(s[e]);
        *(int4*)(Wqk + i) = o.v;
    } else {
        int i = ((blockIdx.x - 8) * 256 + tid) * 8;
        float s[8] = {};
        for (int z = 0; z < 4; ++z) {
            union { int4 v; bf h[8]; } u;
            u.v = *(const int4*)(WpvP + (size_t)z * 131072 + i);
#pragma unroll
            for (int e = 0; e < 8; ++e) s[e] += __bfloat162float(u.h[e]);
        }
        union { bf h[8]; int4 v; } o;
#pragma unroll
        for (int e = 0; e < 8; ++e) o.h[e] = __float2bfloat16(s[e]);
        *(int4*)(Wpv + i) = o.v;
    }
}

// posth2: r0 (64 blocks) beta[n] = h2bank[n,:].vvec | r1 (256) h2 transpose
__global__ __launch_bounds__(256)
void posth2(const bf* __restrict__ h2bank, const float* __restrict__ vvecP,
            float* __restrict__ beta, bf* __restrict__ h2T)
{
    __shared__ float vs[P_DIM];
    __shared__ bf t[64][136];
    const int tid = threadIdx.x;
    if (blockIdx.x < 64) {
        if (tid < P_DIM) {
            float s = 0.f;
#pragma unroll
            for (int z = 0; z < 16; ++z) s += vvecP[z * P_DIM + tid];
            vs[tid] = s;
        }
        __syncthreads();
        const int n = blockIdx.x * 256 + tid;
        const bf* r = h2bank + (size_t)n * P_DIM;
        float s = 0.f;
#pragma unroll
        for (int c = 0; c < P_DIM; c += 8) {
            union { int4 q; bf h[8]; } u;
            u.q = *(const int4*)(r + c);
#pragma unroll
            for (int e = 0; e < 8; ++e) s += __bfloat162float(u.h[e]) * vs[c + e];
        }
        beta[n] = s;
    } else {
        const size_t n0 = (size_t)(blockIdx.x - 64) * 64;
#pragma unroll
        for (int q = 0; q < 4; ++q) {
            int idx = (q * 256 + tid) * 8;
            int r = idx >> 7, c = idx & 127;
            *(int4*)&t[r][c] = *(const int4*)(h2bank + (n0 + r) * P_DIM + c);
        }
        __syncthreads();
        const int p  = tid >> 1;
        const int nb = (tid & 1) * 32;
#pragma unroll
        for (int q = 0; q < 4; ++q) {
            const int n = nb + q * 8;
            union { int4 v; bf h[8]; } u;
#pragma unroll
            for (int e = 0; e < 8; ++e) u.h[e] = t[n + e][p];
            *(int4*)(h2T + (size_t)p * (2 * NBANK) + n0 + n) = u.v;
        }
    }
}

// reduceY: Yhat[s][b][p] = sum_z parts[s*16+z][b][p] / (sum_g rsP[s*16+g][b])
__global__ __launch_bounds__(256)
void reduceY(const bf* __restrict__ parts, const float* __restrict__ rsP,
             bf* __restrict__ Yhat)
{
    int j = (blockIdx.x * 256 + threadIdx.x) * 8;      // < 2*B_ROWS*P_DIM
    const int s = j >> 19;                             // B_ROWS*P_DIM = 2^19
    const int qrow = (j >> 7) & (B_ROWS - 1);
    float rs = 0.f;
#pragma unroll
    for (int g = 0; g < KVSEG; ++g)
        rs += rsP[(size_t)(s * KVSEG + g) * B_ROWS + qrow];
    const bf* p = parts + (size_t)s * KVSEG * 524288 + (size_t)(j & 524287);
    float acc[8] = {};
    for (int z = 0; z < KVSEG; ++z) {
        union { int4 v; bf h[8]; } u;
        u.v = *(const int4*)(p + (size_t)z * 524288);
#pragma unroll
        for (int e = 0; e < 8; ++e) acc[e] += __bfloat162float(u.h[e]);
    }
    const float inv = 1.0f / rs;
    union { bf h[8]; int4 v; } o;
#pragma unroll
    for (int e = 0; e < 8; ++e) o.h[e] = __float2bfloat16(acc[e] * inv);
    *(int4*)(Yhat + j) = o.v;
}

// dual row L2-normalize + bf16 out
__global__ __launch_bounds__(256)
void rownorm2b(const float* __restrict__ G, bf* __restrict__ out)
{
    __shared__ float red[16];
    const int tid = threadIdx.x;
    const float* ps = G + (size_t)blockIdx.x * D_DIM;
    const float* pt = ps + (size_t)B_ROWS * D_DIM;
    float4 a = *(const float4*)(ps + tid * 4);
    float4 c = *(const float4*)(pt + tid * 4);
    float sa = a.x * a.x + a.y * a.y + a.z * a.z + a.w * a.w;
    float sb = c.x * c.x + c.y * c.y + c.z * c.z + c.w * c.w;
    for (int s = 32; s > 0; s >>= 1) {
        sa += __shfl_down(sa, s, 64);
        sb += __shfl_down(sb, s, 64);
    }
    if ((tid & 63) == 0) { red[tid >> 6] = sa; red[8 + (tid >> 6)] = sb; }
    __syncthreads();
    if (tid == 0) {
        float ta = 0.f, tb = 0.f;
        for (int w = 0; w < 4; ++w) { ta += red[w]; tb += red[8 + w]; }
        red[4] = rsqrtf(ta); red[12] = rsqrtf(tb);
    }
    __syncthreads();
    const float ia = red[4], ib = red[12];
    union { bf h[4]; int2 v; } o;
    o.h[0] = __float2bfloat16(a.x * ia + c.x * ib);
    o.h[1] = __float2bfloat16(a.y * ia + c.y * ib);
    o.h[2] = __float2bfloat16(a.z * ia + c.z * ib);
    o.h[3] = __float2bfloat16(a.w * ia + c.w * ib);
    *(int2*)(out + (size_t)blockIdx.x * D_DIM + tid * 4) = o.v;
}

// ---------------------------------------------------------------------------
// Rank-128 attention factorization + flash-fused attention (R6):
//   R6: GEMM1 split-K (fp32 partials) + h2fuse (h1->h2->Qtilde in one kernel),
//   eliminating the 58us low-occupancy GEMM1 and the GEMM2/Qtilde dispatches.
// ---------------------------------------------------------------------------
extern "C" void kernel_launch(void* const* d_in, const int* in_sizes, int n_in,
                              void* d_out, int out_size, void* d_ws, size_t ws_size,
                              hipStream_t stream)
{
    (void)in_sizes; (void)n_in; (void)out_size; (void)ws_size;

    const float* Ft  = (const float*)d_in[0];
    const float* Fv  = (const float*)d_in[1];
    const float* Fvs = (const float*)d_in[2];
    const float* Fvt = (const float*)d_in[3];
    const float* W1  = (const float*)d_in[4];
    const float* b1  = (const float*)d_in[5];
    const float* g1  = (const float*)d_in[6];
    const float* be1 = (const float*)d_in[7];
    const float* m1  = (const float*)d_in[8];
    const float* v1  = (const float*)d_in[9];
    const float* W2  = (const float*)d_in[10];
    const float* b2  = (const float*)d_in[11];
    const float* g2  = (const float*)d_in[12];
    const float* be2 = (const float*)d_in[13];
    const float* m2  = (const float*)d_in[14];
    const float* v2  = (const float*)d_in[15];
    const float* W3  = (const float*)d_in[16];
    const float* b3  = (const float*)d_in[17];
    const float* Wp  = (const float*)d_in[18];
    const float* bp  = (const float*)d_in[19];
    const float* ls  = (const float*)d_in[20];

    char* base = (char*)d_ws;
    size_t o = 0;
    auto take = [&](size_t s) { size_t r = o; o += (s + 255) & ~(size_t)255; return r; };

    // persistent (~22 MB)
    bf* qtb   = (bf*)(base + take((size_t)B_ROWS * P_DIM * 2));
    bf* h2T   = (bf*)(base + take((size_t)P_DIM * 2 * NBANK * 2));
    bf* Yhat  = (bf*)(base + take((size_t)2 * B_ROWS * P_DIM * 2));
    bf* Wpb   = (bf*)(base + take((size_t)D_DIM * D_DIM * 2));
    bf* Ftb   = (bf*)(base + take((size_t)D_DIM * D_DIM * 2));
    bf* W3qT  = (bf*)(base + take((size_t)P_DIM * D_DIM * 2));
    bf* W3kT  = (bf*)(base + take((size_t)P_DIM * D_DIM * 2));
    bf* W3vT  = (bf*)(base + take((size_t)P_DIM * D_DIM * 2));
    bf* Wqk   = (bf*)(base + take((size_t)P_DIM * P_DIM * 2));
    bf* Wpvb  = (bf*)(base + take((size_t)D_DIM * P_DIM * 2));
    bf* W1b   = (bf*)(base + take((size_t)P_DIM * D_DIM * 2));
    bf* W2b   = (bf*)(base + take((size_t)P_DIM * P_DIM * 2));
    bf* h2b   = (bf*)(base + take((size_t)MTOT * P_DIM * 2));
    bf* WqkP  = (bf*)(base + take((size_t)8 * P_DIM * P_DIM * 2));
    bf* WpvP  = (bf*)(base + take((size_t)4 * D_DIM * P_DIM * 2));
    float* vvecP = (float*)(base + take((size_t)16 * P_DIM * 4));
    float* beta  = (float*)(base + take((size_t)2 * NBANK * 4));
    float* bvp   = (float*)(base + take(D_DIM * 4));
    float* bnA   = (float*)(base + take(4 * P_DIM * 4));
    float* rsP   = (float*)(base + take((size_t)2 * KVSEG * B_ROWS * 4)); // 512 KB

    // scratch region (aliased across phases)
    const size_t Dbase = o;
    bf*    Xb    = (bf*)(base + Dbase);                                  // 40 MB
    float* Hp    = (float*)(base + Dbase + (size_t)MTOT * D_DIM * 2);    // 20 MB
    bf*    Opart = (bf*)(base + Dbase + (size_t)64 * 1024 * 1024);       // 32 MB
    float* G     = (float*)(base + Dbase);                               // 32 MB
    bf*    Fsumb = (bf*)(base + Dbase + (size_t)2 * B_ROWS * D_DIM * 4); // 8 MB

    auto gemm = [&](const bf* A, const bf* B, int M, int N, int K, int lda, int ldb,
                    int kch, int fx, int fy, int epi, float* Cf, bf* Cb,
                    const float* bias, const float* biasm,
                    const float* bg, const float* bb, const float* bm, const float* bv,
                    const float* addsrc, const float* lsp, int ldc) {
        gemm_bf16<<<dim3(N / 128, M / 128, kch), dim3(256), 0, stream>>>(
            A, B, M, N, K, lda, ldb, kch, fx, fy, epi, Cf, Cb, bias, biasm,
            bg, bb, bm, bv, addsrc, lsp, ldc);
    };

    // 1) prep: all input-only transforms + folded BN coefficients
    prep<<<dim3(PG0 + PG1 + PG2 + PG3 + PG4 + PG5 + PG6), dim3(256), 0, stream>>>(
        Fv, Fvs, Fvt, W1, W2, Wp, W3, b3, bp, Ft,
        b1, g1, be1, m1, v1, b2, g2, be2, m2, v2,
        Xb, W1b, W2b, Wpb, W3qT, W3kT, W3vT, Ftb, vvecP, bvp, bnA);

    // 2-3) split-K weight folds: Wqk, Wpv = Wp@W3v
    gemm(W3kT, W3qT, P_DIM, P_DIM, D_DIM, D_DIM, D_DIM, 8, 1, 1, 6, nullptr, WqkP,
         nullptr, nullptr, nullptr, nullptr, nullptr, nullptr, nullptr, nullptr, 0);
    gemm(Wpb, W3vT, D_DIM, P_DIM, D_DIM, D_DIM, D_DIM, 4, 1, 8, 6, nullptr, WpvP,
         nullptr, nullptr, nullptr, nullptr, nullptr, nullptr, nullptr, nullptr, 0);
    // 4) fused reduces
    reduceWW<<<dim3(72), dim3(256), 0, stream>>>(WqkP, WpvP, Wqk, Wpvb);

    // 5) pre_project GEMM1, split-K fp32 partials (epi 8)
    gemm(Xb, W1b, MTOT, P_DIM, D_DIM, D_DIM, D_DIM, 2, 1, 8, 8, Hp, nullptr,
         nullptr, nullptr, nullptr, nullptr, nullptr, nullptr, nullptr, nullptr, 0);
    // 6) h2fuse: partial-sum + BN1/ReLU + GEMM2 + BN2/ReLU + Qtilde
    h2fuse<<<dim3(MTOT / 128), dim3(256), 0, stream>>>(
        Hp, W2b, Wqk, bnA, h2b, qtb);
    // 7) beta + h2 transpose
    posth2<<<dim3(320), dim3(256), 0, stream>>>(
        h2b + (size_t)B_ROWS * P_DIM, vvecP, beta, h2T);

    // 8) fused attention: S in LDS only; Y/rowsum seg partials
    attn_fused<<<dim3(2 * KVSEG * (B_ROWS / 128)), dim3(512), 0, stream>>>(
        qtb, h2b + (size_t)B_ROWS * P_DIM, h2T, beta, Opart, rsP);
    // 9) fold segments + softmax normalize -> Yhat [2*B_ROWS,128]
    reduceY<<<dim3(2 * B_ROWS * P_DIM / 2048), dim3(256), 0, stream>>>(
        Opart, rsP, Yhat);

    // 10) combined post-project (K=128) + residual
    gemm(Yhat, Wpvb, 2 * B_ROWS, D_DIM, P_DIM, P_DIM, P_DIM, 1, 1, 8, 3, G, nullptr,
         bvp, nullptr, nullptr, nullptr, nullptr, nullptr, Fv, nullptr, B_ROWS);
    // 11) dual rownorm -> bf16
    rownorm2b<<<dim3(B_ROWS), dim3(256), 0, stream>>>(G, Fsumb);
    // 12) logits
    gemm(Fsumb, Ftb, B_ROWS, D_DIM, D_DIM, D_DIM, D_DIM, 1, 1, 8, 4, (float*)d_out,
         nullptr, nullptr, nullptr, nullptr, nullptr, nullptr, nullptr, nullptr,
         ls, C_CLS);
}